// Round 1
// baseline (485.682 us; speedup 1.0000x reference)
//
#include <hip/hip_runtime.h>
#include <math.h>

// GlobalTransformer: B=2, T=16, N=256 (S=4096), H=64, NHEAD=4, dh=16, L=2
// fp32 end-to-end. edge_index (d_in[1]) is unused by the reference.

namespace {
constexpr int T_ = 16, N_ = 256, S_ = 4096, H_ = 64;
constexpr int UNITS_PER_BH = 72;   // sum over tq of ceil((tq+1)/2)

// workspace layout (float offsets); total 12,058,624 floats = 48.2 MB
constexpr size_t OFF_X    = 0;         // [B*S][64]
constexpr size_t OFF_QKV  = 524288;    // [B*S][192]
constexpr size_t OFF_ATTN = 2097152;   // [B*S][64]
constexpr size_t OFF_PM   = 2621440;   // [bh][tq][kt][n]
constexpr size_t OFF_PL   = 3145728;   // [bh][tq][kt][n]
constexpr size_t OFF_PACC = 3670016;   // [bh][tq][kt][d][n]

__device__ inline float wave_sum(float v) {
#pragma unroll
  for (int off = 32; off > 0; off >>= 1) v += __shfl_xor(v, off, 64);
  return v;
}

// -------- input projection + sinusoidal time PE --------
__global__ void k_init_x(const float* __restrict__ x_seq, const float* __restrict__ Wi,
                         const float* __restrict__ bi, float* __restrict__ X) {
  int gid = blockIdx.x * 256 + threadIdx.x;   // over B*S*H = 524288
  int h = gid & 63;
  int row = gid >> 6;                         // b*S + t*256 + n
  int t = (row >> 8) & 15;
  int i2 = h & ~1;
  float div = __expf((float)i2 * (-0.14391156831212787f));  // -ln(10000)/64
  float arg = (float)t * div;
  float pe = (h & 1) ? cosf(arg) : sinf(arg);
  X[gid] = x_seq[row] * Wi[h] + bi[h] + pe;
}

// -------- qkv = X @ Wqkv + b : wave-uniform X broadcast, coalesced W --------
__global__ void k_qkv(const float* __restrict__ X, const float* __restrict__ W,
                      const float* __restrict__ b, float* __restrict__ QKV) {
  int row = blockIdx.x;          // 0..8191
  int c = threadIdx.x;           // 0..191
  const float* xr = X + (size_t)row * 64;
  float acc = b[c];
#pragma unroll 8
  for (int k = 0; k < 64; ++k) acc = fmaf(xr[k], W[k * 192 + c], acc);
  QKV[(size_t)row * 192 + c] = acc;
}

// -------- attention partials: block=(b,h,tq,chunk of 2 kts), wave = one kt,
// lane holds 2 queries; K/V rows via wave-uniform (L1-broadcast) loads --------
__global__ __launch_bounds__(256, 2) void k_attn(const float* __restrict__ QKV,
    float* __restrict__ PM, float* __restrict__ PL, float* __restrict__ PACC) {
  int bh = blockIdx.x / UNITS_PER_BH;
  int unit = blockIdx.x % UNITS_PER_BH;
  int b = bh >> 2, h = bh & 3;
  int tq = 0;
  while (unit >= (tq / 2 + 1)) { unit -= tq / 2 + 1; ++tq; }
  int chunk = unit;
  int w = threadIdx.x >> 6, lane = threadIdx.x & 63;
  int kt = chunk * 2 + (w >> 1);
  if (kt > tq) return;
  int half = w & 1;

  float q[2][16], acc[2][16], m[2], l[2];
#pragma unroll
  for (int qi = 0; qi < 2; ++qi) {
    int n = half * 128 + qi * 64 + lane;
    const float* qp = QKV + ((size_t)(b * S_ + tq * N_ + n)) * 192 + h * 16;
#pragma unroll
    for (int d4 = 0; d4 < 4; ++d4) {
      float4 v = *(const float4*)(qp + 4 * d4);
      q[qi][4 * d4 + 0] = v.x * 0.25f;  // fold 1/sqrt(dh)
      q[qi][4 * d4 + 1] = v.y * 0.25f;
      q[qi][4 * d4 + 2] = v.z * 0.25f;
      q[qi][4 * d4 + 3] = v.w * 0.25f;
    }
    m[qi] = -INFINITY; l[qi] = 0.f;
#pragma unroll
    for (int d = 0; d < 16; ++d) acc[qi][d] = 0.f;
  }

  const float* kb = QKV + ((size_t)(b * S_ + kt * N_)) * 192 + 64 + h * 16;
#pragma unroll 2
  for (int j = 0; j < 256; ++j) {
    const float* kp = kb + j * 192;
    float kk[16], vv[16];
#pragma unroll
    for (int d4 = 0; d4 < 4; ++d4) {
      float4 k4 = *(const float4*)(kp + 4 * d4);          // key row (uniform addr)
      kk[4 * d4 + 0] = k4.x; kk[4 * d4 + 1] = k4.y;
      kk[4 * d4 + 2] = k4.z; kk[4 * d4 + 3] = k4.w;
      float4 v4 = *(const float4*)(kp + 64 + 4 * d4);     // value row
      vv[4 * d4 + 0] = v4.x; vv[4 * d4 + 1] = v4.y;
      vv[4 * d4 + 2] = v4.z; vv[4 * d4 + 3] = v4.w;
    }
#pragma unroll
    for (int qi = 0; qi < 2; ++qi) {
      float s = 0.f;
#pragma unroll
      for (int d = 0; d < 16; ++d) s = fmaf(q[qi][d], kk[d], s);
      if (s <= m[qi]) {                 // common path: no rescale
        float p = __expf(s - m[qi]);
        l[qi] += p;
#pragma unroll
        for (int d = 0; d < 16; ++d) acc[qi][d] = fmaf(p, vv[d], acc[qi][d]);
      } else {                          // rare: new max, rescale state
        float sc = __expf(m[qi] - s);   // exp(-inf)=0 handles first key
        m[qi] = s;
        l[qi] = fmaf(l[qi], sc, 1.f);
#pragma unroll
        for (int d = 0; d < 16; ++d) acc[qi][d] = fmaf(acc[qi][d], sc, vv[d]);
      }
    }
  }

  int slot = (bh * T_ + tq) * 16 + kt;
#pragma unroll
  for (int qi = 0; qi < 2; ++qi) {
    int n = half * 128 + qi * 64 + lane;
    PM[(size_t)slot * 256 + n] = m[qi];
    PL[(size_t)slot * 256 + n] = l[qi];
#pragma unroll
    for (int d = 0; d < 16; ++d)
      PACC[((size_t)slot * 16 + d) * 256 + n] = acc[qi][d];
  }
}

// -------- merge per-kt partials -> O in [B,S,64] (head-interleaved) --------
__global__ void k_combine(const float* __restrict__ PM, const float* __restrict__ PL,
                          const float* __restrict__ PACC, float* __restrict__ ATTN) {
  int id = blockIdx.x * 256 + threadIdx.x;  // 32768 queries
  int n = id & 255, tq = (id >> 8) & 15, bh = id >> 12;
  int nk = tq + 1;
  int sb = (bh * T_ + tq) * 16;
  float M = -INFINITY;
  for (int kt = 0; kt < nk; ++kt) M = fmaxf(M, PM[(size_t)(sb + kt) * 256 + n]);
  float L = 0.f, acc[16];
#pragma unroll
  for (int d = 0; d < 16; ++d) acc[d] = 0.f;
  for (int kt = 0; kt < nk; ++kt) {
    float wgt = __expf(PM[(size_t)(sb + kt) * 256 + n] - M);
    L = fmaf(PL[(size_t)(sb + kt) * 256 + n], wgt, L);
#pragma unroll
    for (int d = 0; d < 16; ++d)
      acc[d] = fmaf(PACC[((size_t)(sb + kt) * 16 + d) * 256 + n], wgt, acc[d]);
  }
  float inv = 1.f / L;
  int b = bh >> 2, h = bh & 3;
  float* op = ATTN + ((size_t)(b * S_ + tq * N_ + n)) * 64 + h * 16;
#pragma unroll
  for (int d4 = 0; d4 < 4; ++d4) {
    float4 o;
    o.x = acc[4 * d4 + 0] * inv; o.y = acc[4 * d4 + 1] * inv;
    o.z = acc[4 * d4 + 2] * inv; o.w = acc[4 * d4 + 3] * inv;
    *(float4*)(op + 4 * d4) = o;
  }
}

// -------- o @ Wo + bo + residual, LayerNorm1 (wave per row, in-place X) ----
__global__ void k_proj_ln1(const float* __restrict__ O, const float* __restrict__ Wo,
                           const float* __restrict__ bo, const float* __restrict__ g,
                           const float* __restrict__ be, float* __restrict__ X) {
  int row = blockIdx.x * 4 + (threadIdx.x >> 6);
  int c = threadIdx.x & 63;
  const float* orow = O + (size_t)row * 64;
  float a = bo[c];
#pragma unroll 8
  for (int k = 0; k < 64; ++k) a = fmaf(orow[k], Wo[k * 64 + c], a);
  float val = a + X[(size_t)row * 64 + c];
  float mean = wave_sum(val) * (1.f / 64.f);
  float dv = val - mean;
  float var = wave_sum(dv * dv) * (1.f / 64.f);
  X[(size_t)row * 64 + c] = dv * rsqrtf(var + 1e-5f) * g[c] + be[c];
}

// -------- FFN (64->256 relu ->64) + residual + LayerNorm2, 8 rows/block ----
__global__ __launch_bounds__(256) void k_ffn_ln2(const float* __restrict__ W1,
    const float* __restrict__ b1, const float* __restrict__ W2, const float* __restrict__ b2,
    const float* __restrict__ g, const float* __restrict__ be, float* __restrict__ X) {
  __shared__ float xs[8][64];
  __shared__ float hs[8][256];
  int tid = threadIdx.x;
  size_t base = (size_t)blockIdx.x * 8 * 64;
#pragma unroll
  for (int i = 0; i < 2; ++i) {
    int idx = tid + 256 * i;
    xs[idx >> 6][idx & 63] = X[base + idx];
  }
  __syncthreads();
  float am[8];
#pragma unroll
  for (int r = 0; r < 8; ++r) am[r] = b1[tid];
#pragma unroll 4
  for (int k = 0; k < 64; ++k) {
    float w1 = W1[k * 256 + tid];
#pragma unroll
    for (int r = 0; r < 8; ++r) am[r] = fmaf(xs[r][k], w1, am[r]);
  }
#pragma unroll
  for (int r = 0; r < 8; ++r) hs[r][tid] = fmaxf(am[r], 0.f);
  __syncthreads();
  int c = tid & 63, grp = tid >> 6;
  float a0 = b2[c], a1 = b2[c];
#pragma unroll 4
  for (int k = 0; k < 256; ++k) {
    float w2 = W2[k * 64 + c];
    a0 = fmaf(hs[grp][k], w2, a0);
    a1 = fmaf(hs[grp + 4][k], w2, a1);
  }
  {
    float val = a0 + xs[grp][c];
    float mean = wave_sum(val) * (1.f / 64.f);
    float dv = val - mean;
    float var = wave_sum(dv * dv) * (1.f / 64.f);
    X[base + grp * 64 + c] = dv * rsqrtf(var + 1e-5f) * g[c] + be[c];
  }
  {
    float val = a1 + xs[grp + 4][c];
    float mean = wave_sum(val) * (1.f / 64.f);
    float dv = val - mean;
    float var = wave_sum(dv * dv) * (1.f / 64.f);
    X[base + (grp + 4) * 64 + c] = dv * rsqrtf(var + 1e-5f) * g[c] + be[c];
  }
}

// -------- decoder head on last timestep: 64->32->16->1, wave per (b,n) -----
__global__ void k_head(const float* __restrict__ X, const float* __restrict__ dW1,
    const float* __restrict__ db1, const float* __restrict__ dW2, const float* __restrict__ db2,
    const float* __restrict__ dW3, const float* __restrict__ db3, float* __restrict__ out) {
  __shared__ float h1s[4][32];
  __shared__ float h2s[4][16];
  int grp = threadIdx.x >> 6, lane = threadIdx.x & 63;
  int idx = blockIdx.x * 4 + grp;      // 0..511  (b*256+n)
  int b = idx >> 8, n = idx & 255;
  const float* row = X + ((size_t)(b * S_ + 15 * N_ + n)) * 64;
  if (lane < 32) {
    float a = db1[lane];
#pragma unroll 8
    for (int k = 0; k < 64; ++k) a = fmaf(row[k], dW1[k * 32 + lane], a);
    h1s[grp][lane] = fmaxf(a, 0.f);
  }
  __syncthreads();
  if (lane < 16) {
    float a = db2[lane];
#pragma unroll
    for (int k = 0; k < 32; ++k) a = fmaf(h1s[grp][k], dW2[k * 16 + lane], a);
    h2s[grp][lane] = fmaxf(a, 0.f);
  }
  __syncthreads();
  if (lane == 0) {
    float a = db3[0];
#pragma unroll
    for (int k = 0; k < 16; ++k) a = fmaf(h2s[grp][k], dW3[k], a);
    out[idx] = a;
  }
}

}  // namespace

extern "C" void kernel_launch(void* const* d_in, const int* in_sizes, int n_in,
                              void* d_out, int out_size, void* d_ws, size_t ws_size,
                              hipStream_t stream) {
  const float* x_seq = (const float*)d_in[0];
  // d_in[1] = edge_index (unused by reference)
  const float* Wi   = (const float*)d_in[2];
  const float* bi   = (const float*)d_in[3];
  const float* Wqkv = (const float*)d_in[4];
  const float* bqkv = (const float*)d_in[5];
  const float* Wo   = (const float*)d_in[6];
  const float* bo   = (const float*)d_in[7];
  const float* ln1g = (const float*)d_in[8];
  const float* ln1b = (const float*)d_in[9];
  const float* W1   = (const float*)d_in[10];
  const float* b1   = (const float*)d_in[11];
  const float* W2   = (const float*)d_in[12];
  const float* b2   = (const float*)d_in[13];
  const float* ln2g = (const float*)d_in[14];
  const float* ln2b = (const float*)d_in[15];
  const float* dW1  = (const float*)d_in[16];
  const float* db1  = (const float*)d_in[17];
  const float* dW2  = (const float*)d_in[18];
  const float* db2  = (const float*)d_in[19];
  const float* dW3  = (const float*)d_in[20];
  const float* db3  = (const float*)d_in[21];

  float* ws   = (float*)d_ws;  // needs >= 48.3 MB
  float* X    = ws + OFF_X;
  float* QKV  = ws + OFF_QKV;
  float* ATTN = ws + OFF_ATTN;
  float* PM   = ws + OFF_PM;
  float* PL   = ws + OFF_PL;
  float* PACC = ws + OFF_PACC;

  k_init_x<<<2048, 256, 0, stream>>>(x_seq, Wi, bi, X);
  for (int l = 0; l < 2; ++l) {
    k_qkv<<<8192, 192, 0, stream>>>(X, Wqkv + l * 64 * 192, bqkv + l * 192, QKV);
    k_attn<<<8 * UNITS_PER_BH, 256, 0, stream>>>(QKV, PM, PL, PACC);
    k_combine<<<128, 256, 0, stream>>>(PM, PL, PACC, ATTN);
    k_proj_ln1<<<2048, 256, 0, stream>>>(ATTN, Wo + l * 4096, bo + l * 64,
                                         ln1g + l * 64, ln1b + l * 64, X);
    k_ffn_ln2<<<1024, 256, 0, stream>>>(W1 + l * 64 * 256, b1 + l * 256,
                                        W2 + l * 256 * 64, b2 + l * 64,
                                        ln2g + l * 64, ln2b + l * 64, X);
  }
  k_head<<<128, 256, 0, stream>>>(X, dW1, db1, dW2, db2, dW3, db3, (float*)d_out);
}

// Round 2
// 385.279 us; speedup vs baseline: 1.2606x; 1.2606x over previous
//
#include <hip/hip_runtime.h>
#include <math.h>

// GlobalTransformer: B=2, T=16, N=256 (S=4096), H=64, NHEAD=4, dh=16, L=2
// fp32 end-to-end. edge_index (d_in[1]) is unused by the reference.

namespace {
constexpr int T_ = 16, N_ = 256, S_ = 4096, H_ = 64;
constexpr int PAIRS = 136;           // valid (tq,kt) pairs per bh: sum(tq+1)
constexpr int UNITS_PER_BH = PAIRS * 4;  // x2 keyhalf x2 qhalf = 544 waves/bh

// workspace layout (float offsets); total 12,648,448 floats = 50.6 MB
constexpr size_t OFF_X    = 0;         // [B*S][64]
constexpr size_t OFF_QKV  = 524288;    // [B*S][192]
constexpr size_t OFF_ATTN = 2097152;   // [B*S][64]
constexpr size_t OFF_PM   = 2621440;   // [2176 slots][256]
constexpr size_t OFF_PL   = 3178496;   // [2176 slots][256]
constexpr size_t OFF_PACC = 3735552;   // [2176 slots][16][256]

__device__ inline float wave_sum(float v) {
#pragma unroll
  for (int off = 32; off > 0; off >>= 1) v += __shfl_xor(v, off, 64);
  return v;
}

// -------- input projection + sinusoidal time PE --------
__global__ void k_init_x(const float* __restrict__ x_seq, const float* __restrict__ Wi,
                         const float* __restrict__ bi, float* __restrict__ X) {
  int gid = blockIdx.x * 256 + threadIdx.x;   // over B*S*H = 524288
  int h = gid & 63;
  int row = gid >> 6;                         // b*S + t*256 + n
  int t = (row >> 8) & 15;
  int i2 = h & ~1;
  float div = __expf((float)i2 * (-0.14391156831212787f));  // -ln(10000)/64
  float arg = (float)t * div;
  float pe = (h & 1) ? cosf(arg) : sinf(arg);
  X[gid] = x_seq[row] * Wi[h] + bi[h] + pe;
}

// -------- qkv = X @ Wqkv + b : wave-uniform X broadcast, coalesced W --------
__global__ void k_qkv(const float* __restrict__ X, const float* __restrict__ W,
                      const float* __restrict__ b, float* __restrict__ QKV) {
  int row = blockIdx.x;          // 0..8191
  int c = threadIdx.x;           // 0..191
  const float* xr = X + (size_t)row * 64;
  float acc = b[c];
#pragma unroll 8
  for (int k = 0; k < 64; ++k) acc = fmaf(xr[k], W[k * 192 + c], acc);
  QKV[(size_t)row * 192 + c] = acc;
}

// -------- attention partials ------------------------------------------------
// wave = (bh, (tq,kt) pair, keyhalf, qhalf): 128 keys x 128 queries (2/lane).
// 4352 equal waves, no early exits -> ~4.25 waves/SIMD for latency hiding.
__global__ __launch_bounds__(256, 4) void k_attn(const float* __restrict__ QKV,
    float* __restrict__ PM, float* __restrict__ PL, float* __restrict__ PACC) {
  int gunit = blockIdx.x * 4 + (threadIdx.x >> 6);
  int lane = threadIdx.x & 63;
  int bh = gunit / UNITS_PER_BH;
  int u  = gunit % UNITS_PER_BH;
  int pair = u >> 2, keyhalf = (u >> 1) & 1, qhalf = u & 1;
  int b = bh >> 2, h = bh & 3;
  int tq = 0, p = pair;
  while (p >= tq + 1) { p -= tq + 1; ++tq; }
  int kt = p;

  float q[2][16], acc[2][16], m[2], l[2];
#pragma unroll
  for (int qi = 0; qi < 2; ++qi) {
    int n = qhalf * 128 + qi * 64 + lane;
    const float* qp = QKV + ((size_t)(b * S_ + tq * N_ + n)) * 192 + h * 16;
#pragma unroll
    for (int d4 = 0; d4 < 4; ++d4) {
      float4 v = *(const float4*)(qp + 4 * d4);
      q[qi][4 * d4 + 0] = v.x * 0.25f;  // fold 1/sqrt(dh)
      q[qi][4 * d4 + 1] = v.y * 0.25f;
      q[qi][4 * d4 + 2] = v.z * 0.25f;
      q[qi][4 * d4 + 3] = v.w * 0.25f;
    }
    m[qi] = -INFINITY; l[qi] = 0.f;
#pragma unroll
    for (int d = 0; d < 16; ++d) acc[qi][d] = 0.f;
  }

  // wave-uniform K/V base; readfirstlane lets the compiler use scalar loads
  int kbase = (b * S_ + kt * N_ + keyhalf * 128) * 192 + 64 + h * 16;
  kbase = __builtin_amdgcn_readfirstlane(kbase);
  const float* kb = QKV + kbase;

#pragma unroll 2
  for (int j = 0; j < 128; ++j) {
    const float* kp = kb + j * 192;
    float kk[16], vv[16];
#pragma unroll
    for (int d4 = 0; d4 < 4; ++d4) {
      float4 k4 = *(const float4*)(kp + 4 * d4);          // key row (uniform)
      kk[4 * d4 + 0] = k4.x; kk[4 * d4 + 1] = k4.y;
      kk[4 * d4 + 2] = k4.z; kk[4 * d4 + 3] = k4.w;
      float4 v4 = *(const float4*)(kp + 64 + 4 * d4);     // value row
      vv[4 * d4 + 0] = v4.x; vv[4 * d4 + 1] = v4.y;
      vv[4 * d4 + 2] = v4.z; vv[4 * d4 + 3] = v4.w;
    }
#pragma unroll
    for (int qi = 0; qi < 2; ++qi) {
      float s0 = 0.f, s1 = 0.f, s2 = 0.f, s3 = 0.f;   // 4 chains for ILP
#pragma unroll
      for (int d = 0; d < 4; ++d) {
        s0 = fmaf(q[qi][d],      kk[d],      s0);
        s1 = fmaf(q[qi][d + 4],  kk[d + 4],  s1);
        s2 = fmaf(q[qi][d + 8],  kk[d + 8],  s2);
        s3 = fmaf(q[qi][d + 12], kk[d + 12], s3);
      }
      float s = (s0 + s1) + (s2 + s3);
      if (s <= m[qi]) {                 // common path: no rescale
        float pw = __expf(s - m[qi]);
        l[qi] += pw;
#pragma unroll
        for (int d = 0; d < 16; ++d) acc[qi][d] = fmaf(pw, vv[d], acc[qi][d]);
      } else {                          // rare: new max, rescale state
        float sc = __expf(m[qi] - s);   // exp(-inf)=0 handles first key
        m[qi] = s;
        l[qi] = fmaf(l[qi], sc, 1.f);
#pragma unroll
        for (int d = 0; d < 16; ++d) acc[qi][d] = fmaf(acc[qi][d], sc, vv[d]);
      }
    }
  }

  int slot = (bh * PAIRS + pair) * 2 + keyhalf;
#pragma unroll
  for (int qi = 0; qi < 2; ++qi) {
    int n = qhalf * 128 + qi * 64 + lane;
    PM[(size_t)slot * 256 + n] = m[qi];
    PL[(size_t)slot * 256 + n] = l[qi];
#pragma unroll
    for (int d = 0; d < 16; ++d)
      PACC[((size_t)slot * 16 + d) * 256 + n] = acc[qi][d];
  }
}

// -------- merge partials -> O in [B,S,64] (head-interleaved) --------
__global__ void k_combine(const float* __restrict__ PM, const float* __restrict__ PL,
                          const float* __restrict__ PACC, float* __restrict__ ATTN) {
  int id = blockIdx.x * 256 + threadIdx.x;  // 32768 queries
  int n = id & 255, tq = (id >> 8) & 15, bh = id >> 12;
  int ns = 2 * (tq + 1);
  int sb = (bh * PAIRS + tq * (tq + 1) / 2) * 2;   // contiguous slot range
  float M = -INFINITY;
  for (int s = 0; s < ns; ++s) M = fmaxf(M, PM[(size_t)(sb + s) * 256 + n]);
  float L = 0.f, acc[16];
#pragma unroll
  for (int d = 0; d < 16; ++d) acc[d] = 0.f;
  for (int s = 0; s < ns; ++s) {
    float wgt = __expf(PM[(size_t)(sb + s) * 256 + n] - M);
    L = fmaf(PL[(size_t)(sb + s) * 256 + n], wgt, L);
#pragma unroll
    for (int d = 0; d < 16; ++d)
      acc[d] = fmaf(PACC[((size_t)(sb + s) * 16 + d) * 256 + n], wgt, acc[d]);
  }
  float inv = 1.f / L;
  int b = bh >> 2, h = bh & 3;
  float* op = ATTN + ((size_t)(b * S_ + tq * N_ + n)) * 64 + h * 16;
#pragma unroll
  for (int d4 = 0; d4 < 4; ++d4) {
    float4 o;
    o.x = acc[4 * d4 + 0] * inv; o.y = acc[4 * d4 + 1] * inv;
    o.z = acc[4 * d4 + 2] * inv; o.w = acc[4 * d4 + 3] * inv;
    *(float4*)(op + 4 * d4) = o;
  }
}

// -------- o @ Wo + bo + residual, LayerNorm1 (wave per row, in-place X) ----
__global__ void k_proj_ln1(const float* __restrict__ O, const float* __restrict__ Wo,
                           const float* __restrict__ bo, const float* __restrict__ g,
                           const float* __restrict__ be, float* __restrict__ X) {
  int row = blockIdx.x * 4 + (threadIdx.x >> 6);
  int c = threadIdx.x & 63;
  const float* orow = O + (size_t)row * 64;
  float a = bo[c];
#pragma unroll 8
  for (int k = 0; k < 64; ++k) a = fmaf(orow[k], Wo[k * 64 + c], a);
  float val = a + X[(size_t)row * 64 + c];
  float mean = wave_sum(val) * (1.f / 64.f);
  float dv = val - mean;
  float var = wave_sum(dv * dv) * (1.f / 64.f);
  X[(size_t)row * 64 + c] = dv * rsqrtf(var + 1e-5f) * g[c] + be[c];
}

// -------- FFN (64->256 relu ->64) + residual + LayerNorm2, 8 rows/block ----
__global__ __launch_bounds__(256) void k_ffn_ln2(const float* __restrict__ W1,
    const float* __restrict__ b1, const float* __restrict__ W2, const float* __restrict__ b2,
    const float* __restrict__ g, const float* __restrict__ be, float* __restrict__ X) {
  __shared__ float xs[8][64];
  __shared__ float hs[8][256];
  int tid = threadIdx.x;
  size_t base = (size_t)blockIdx.x * 8 * 64;
#pragma unroll
  for (int i = 0; i < 2; ++i) {
    int idx = tid + 256 * i;
    xs[idx >> 6][idx & 63] = X[base + idx];
  }
  __syncthreads();
  float am[8];
#pragma unroll
  for (int r = 0; r < 8; ++r) am[r] = b1[tid];
#pragma unroll 4
  for (int k = 0; k < 64; ++k) {
    float w1 = W1[k * 256 + tid];
#pragma unroll
    for (int r = 0; r < 8; ++r) am[r] = fmaf(xs[r][k], w1, am[r]);
  }
#pragma unroll
  for (int r = 0; r < 8; ++r) hs[r][tid] = fmaxf(am[r], 0.f);
  __syncthreads();
  int c = tid & 63, grp = tid >> 6;
  float a0 = b2[c], a1 = b2[c];
#pragma unroll 4
  for (int k = 0; k < 256; ++k) {
    float w2 = W2[k * 64 + c];
    a0 = fmaf(hs[grp][k], w2, a0);
    a1 = fmaf(hs[grp + 4][k], w2, a1);
  }
  {
    float val = a0 + xs[grp][c];
    float mean = wave_sum(val) * (1.f / 64.f);
    float dv = val - mean;
    float var = wave_sum(dv * dv) * (1.f / 64.f);
    X[base + grp * 64 + c] = dv * rsqrtf(var + 1e-5f) * g[c] + be[c];
  }
  {
    float val = a1 + xs[grp + 4][c];
    float mean = wave_sum(val) * (1.f / 64.f);
    float dv = val - mean;
    float var = wave_sum(dv * dv) * (1.f / 64.f);
    X[base + (grp + 4) * 64 + c] = dv * rsqrtf(var + 1e-5f) * g[c] + be[c];
  }
}

// -------- decoder head on last timestep: 64->32->16->1, wave per (b,n) -----
__global__ void k_head(const float* __restrict__ X, const float* __restrict__ dW1,
    const float* __restrict__ db1, const float* __restrict__ dW2, const float* __restrict__ db2,
    const float* __restrict__ dW3, const float* __restrict__ db3, float* __restrict__ out) {
  __shared__ float h1s[4][32];
  __shared__ float h2s[4][16];
  int grp = threadIdx.x >> 6, lane = threadIdx.x & 63;
  int idx = blockIdx.x * 4 + grp;      // 0..511  (b*256+n)
  int b = idx >> 8, n = idx & 255;
  const float* row = X + ((size_t)(b * S_ + 15 * N_ + n)) * 64;
  if (lane < 32) {
    float a = db1[lane];
#pragma unroll 8
    for (int k = 0; k < 64; ++k) a = fmaf(row[k], dW1[k * 32 + lane], a);
    h1s[grp][lane] = fmaxf(a, 0.f);
  }
  __syncthreads();
  if (lane < 16) {
    float a = db2[lane];
#pragma unroll
    for (int k = 0; k < 32; ++k) a = fmaf(h1s[grp][k], dW2[k * 16 + lane], a);
    h2s[grp][lane] = fmaxf(a, 0.f);
  }
  __syncthreads();
  if (lane == 0) {
    float a = db3[0];
#pragma unroll
    for (int k = 0; k < 16; ++k) a = fmaf(h2s[grp][k], dW3[k], a);
    out[idx] = a;
  }
}

}  // namespace

extern "C" void kernel_launch(void* const* d_in, const int* in_sizes, int n_in,
                              void* d_out, int out_size, void* d_ws, size_t ws_size,
                              hipStream_t stream) {
  const float* x_seq = (const float*)d_in[0];
  // d_in[1] = edge_index (unused by reference)
  const float* Wi   = (const float*)d_in[2];
  const float* bi   = (const float*)d_in[3];
  const float* Wqkv = (const float*)d_in[4];
  const float* bqkv = (const float*)d_in[5];
  const float* Wo   = (const float*)d_in[6];
  const float* bo   = (const float*)d_in[7];
  const float* ln1g = (const float*)d_in[8];
  const float* ln1b = (const float*)d_in[9];
  const float* W1   = (const float*)d_in[10];
  const float* b1   = (const float*)d_in[11];
  const float* W2   = (const float*)d_in[12];
  const float* b2   = (const float*)d_in[13];
  const float* ln2g = (const float*)d_in[14];
  const float* ln2b = (const float*)d_in[15];
  const float* dW1  = (const float*)d_in[16];
  const float* db1  = (const float*)d_in[17];
  const float* dW2  = (const float*)d_in[18];
  const float* db2  = (const float*)d_in[19];
  const float* dW3  = (const float*)d_in[20];
  const float* db3  = (const float*)d_in[21];

  float* ws   = (float*)d_ws;  // needs >= 50.6 MB
  float* X    = ws + OFF_X;
  float* QKV  = ws + OFF_QKV;
  float* ATTN = ws + OFF_ATTN;
  float* PM   = ws + OFF_PM;
  float* PL   = ws + OFF_PL;
  float* PACC = ws + OFF_PACC;

  k_init_x<<<2048, 256, 0, stream>>>(x_seq, Wi, bi, X);
  for (int l = 0; l < 2; ++l) {
    k_qkv<<<8192, 192, 0, stream>>>(X, Wqkv + l * 64 * 192, bqkv + l * 192, QKV);
    k_attn<<<8 * UNITS_PER_BH / 4, 256, 0, stream>>>(QKV, PM, PL, PACC);
    k_combine<<<128, 256, 0, stream>>>(PM, PL, PACC, ATTN);
    k_proj_ln1<<<2048, 256, 0, stream>>>(ATTN, Wo + l * 4096, bo + l * 64,
                                         ln1g + l * 64, ln1b + l * 64, X);
    k_ffn_ln2<<<1024, 256, 0, stream>>>(W1 + l * 64 * 256, b1 + l * 256,
                                        W2 + l * 256 * 64, b2 + l * 64,
                                        ln2g + l * 64, ln2b + l * 64, X);
  }
  k_head<<<128, 256, 0, stream>>>(X, dW1, db1, dW2, db2, dW3, db3, (float*)d_out);
}

// Round 4
// 214.685 us; speedup vs baseline: 2.2623x; 1.7946x over previous
//
#include <hip/hip_runtime.h>
#include <math.h>

// GlobalTransformer: B=2, T=16, N=256 (S=4096), H=64, NHEAD=4, dh=16, L=2
// fp32 everywhere except attention MFMA operands (bf16; Q/K hi-lo split).
// Round 4: all lane-exchange via __shfl_xor, all bf16 packing via explicit
// bit ops — no inline-asm semantics assumptions left in the routing chain.

namespace {
constexpr int T_ = 16, N_ = 256, S_ = 4096;
constexpr int PAIRS = 136;   // valid (tq,kt) pairs per bh

// workspace layout (float offsets); total 7,634,944 floats = 30.5 MB
constexpr size_t OFF_X    = 0;         // [B*S][64]
constexpr size_t OFF_QKV  = 524288;    // [B*S][192]
constexpr size_t OFF_ATTN = 2097152;   // [B*S][64]
constexpr size_t OFF_PM   = 2621440;   // [1088 slots][256]  (log2-space max)
constexpr size_t OFF_PL   = 2899968;   // [1088 slots][256]
constexpr size_t OFF_PACC = 3178496;   // [1088 slots][16][256]

typedef float  f32x16 __attribute__((ext_vector_type(16)));
typedef short  short8 __attribute__((ext_vector_type(8)));

__device__ inline float wave_sum(float v) {
#pragma unroll
  for (int off = 32; off > 0; off >>= 1) v += __shfl_xor(v, off, 64);
  return v;
}

// round-to-nearest-even f32 -> bf16 (bits in low 16)
__device__ inline unsigned bf16_rne(float f) {
  unsigned u = __float_as_uint(f);
  return (u + 0x7FFFu + ((u >> 16) & 1u)) >> 16;
}
__device__ inline unsigned pack2(float a, float b) {   // low<-a, high<-b
  return bf16_rne(a) | (bf16_rne(b) << 16);
}
__device__ inline f32x16 zero16() {
  f32x16 z;
#pragma unroll
  for (int i = 0; i < 16; ++i) z[i] = 0.f;
  return z;
}
// split 8 fp32 -> bf16 hi (truncated) + bf16 lo (RNE of exact residual)
__device__ inline void split8(const float f[8], short8& h8, short8& l8) {
#pragma unroll
  for (int i = 0; i < 8; ++i) {
    unsigned ht = __float_as_uint(f[i]) & 0xFFFF0000u;   // truncate to bf16
    h8[i] = (short)(ht >> 16);
    float r = f[i] - __uint_as_float(ht);                // exact in f32
    l8[i] = (short)bf16_rne(r);
  }
}

// -------- input projection + sinusoidal time PE --------
__global__ void k_init_x(const float* __restrict__ x_seq, const float* __restrict__ Wi,
                         const float* __restrict__ bi, float* __restrict__ X) {
  int gid = blockIdx.x * 256 + threadIdx.x;   // over B*S*H = 524288
  int h = gid & 63;
  int row = gid >> 6;                         // b*S + t*256 + n
  int t = (row >> 8) & 15;
  int i2 = h & ~1;
  float div = __expf((float)i2 * (-0.14391156831212787f));  // -ln(10000)/64
  float arg = (float)t * div;
  float pe = (h & 1) ? cosf(arg) : sinf(arg);
  X[gid] = x_seq[row] * Wi[h] + bi[h] + pe;
}

// -------- qkv = X @ Wqkv + b --------
__global__ void k_qkv(const float* __restrict__ X, const float* __restrict__ W,
                      const float* __restrict__ b, float* __restrict__ QKV) {
  int row = blockIdx.x;          // 0..8191
  int c = threadIdx.x;           // 0..191
  const float* xr = X + (size_t)row * 64;
  float acc = b[c];
#pragma unroll 8
  for (int k = 0; k < 64; ++k) acc = fmaf(xr[k], W[k * 192 + c], acc);
  QKV[(size_t)row * 192 + c] = acc;
}

// -------- MFMA flash attention partials -------------------------------------
// block = (bh, (tq,kt)); 4 waves; wave w owns q-rows [64w,64w+64).
// Swapped QK^T: S^T = mfma(K, Q) -> lane owns one q-col; softmax per-lane.
// PV as O^T = V^T * P^T (V^T staged bf16 in LDS; P^T assembled via shfl_xor).
// Layout facts used (both guide-measured): A/B fragment k = 8*(lane>>5)+elem
// (ascending); C/D: col=lane&31, row=(reg&3)+8*(reg>>2)+4*(lane>>5).
__global__ __launch_bounds__(256, 2) void k_attn(const float* __restrict__ QKV,
    float* __restrict__ PM, float* __restrict__ PL, float* __restrict__ PACC) {
  __shared__ short VT[32][264];   // [d: 16 valid + 16 zeroed][256 keys + pad]

  int blk = blockIdx.x;
  int bh = blk / PAIRS, pair = blk % PAIRS;
  int b = bh >> 2, h = bh & 3;
  int tq = 0, p = pair;
  while (p >= tq + 1) { p -= tq + 1; ++tq; }
  int kt = p;

  int tid = threadIdx.x, w = tid >> 6, lane = tid & 63;
  int l31 = lane & 31, hi = lane >> 5;
  const size_t qkvbase = (size_t)b * S_ * 192;

  // ---- zero d-rows 16..31 (read as A rows by lanes 16..31, discarded) ----
  for (int i = tid; i < 16 * 264; i += 256) (&VT[16][0])[i] = 0;

  // ---- stage V^T (bf16) : thread t handles key-row t, all 16 d ----
  {
    const float* vr = QKV + qkvbase + (size_t)(kt * N_ + tid) * 192 + 128 + h * 16;
#pragma unroll
    for (int i = 0; i < 4; ++i) {
      float4 t4 = *(const float4*)(vr + 4 * i);
      VT[4 * i + 0][tid] = (short)bf16_rne(t4.x);
      VT[4 * i + 1][tid] = (short)bf16_rne(t4.y);
      VT[4 * i + 2][tid] = (short)bf16_rne(t4.z);
      VT[4 * i + 3][tid] = (short)bf16_rne(t4.w);
    }
  }
  __syncthreads();

  // ---- Q fragments (scaled by log2e/4), hi/lo split ----
  const float cscale = 0.36067376022224085f;  // (1/sqrt(16)) * log2(e)
  short8 Qh[2], Ql[2];
#pragma unroll
  for (int qs = 0; qs < 2; ++qs) {
    int qloc = w * 64 + qs * 32 + l31;
    const float* qp = QKV + qkvbase + (size_t)(tq * N_ + qloc) * 192 + h * 16 + 8 * hi;
    float qf[8];
    float4 a4 = *(const float4*)(qp), b4 = *(const float4*)(qp + 4);
    qf[0] = a4.x * cscale; qf[1] = a4.y * cscale; qf[2] = a4.z * cscale; qf[3] = a4.w * cscale;
    qf[4] = b4.x * cscale; qf[5] = b4.y * cscale; qf[6] = b4.z * cscale; qf[7] = b4.w * cscale;
    split8(qf, Qh[qs], Ql[qs]);
  }

  f32x16 O0 = zero16(), O1 = zero16();
  float m[2] = {-INFINITY, -INFINITY}, lsum[2] = {0.f, 0.f};

  for (int ks = 0; ks < 8; ++ks) {
    // K fragment (row = l31 within subtile, dh-half = hi), hi/lo split
    short8 Kh, Kl;
    {
      const float* kp = QKV + qkvbase +
          (size_t)(kt * N_ + ks * 32 + l31) * 192 + 64 + h * 16 + 8 * hi;
      float kf[8];
      float4 a4 = *(const float4*)(kp), b4 = *(const float4*)(kp + 4);
      kf[0] = a4.x; kf[1] = a4.y; kf[2] = a4.z; kf[3] = a4.w;
      kf[4] = b4.x; kf[5] = b4.y; kf[6] = b4.z; kf[7] = b4.w;
      split8(kf, Kh, Kl);
    }
    // V^T fragments: MFMA k = 8*hi+e  <->  key = ks*32 + (8*hi+e) [+16 for Vb]
    int kco = ks * 32 + 8 * hi;
    short8 Va = *(const short8*)(&VT[l31][kco]);
    short8 Vb = *(const short8*)(&VT[l31][kco + 16]);

#pragma unroll
    for (int qs = 0; qs < 2; ++qs) {
      // S^T[32k x 32q] = K * Q^T  (split: Kh*Qh + Kl*Qh + Kh*Ql)
      f32x16 S = zero16();
      S = __builtin_amdgcn_mfma_f32_32x32x16_bf16(Kh, Qh[qs], S, 0, 0, 0);
      S = __builtin_amdgcn_mfma_f32_32x32x16_bf16(Kl, Qh[qs], S, 0, 0, 0);
      S = __builtin_amdgcn_mfma_f32_32x32x16_bf16(Kh, Ql[qs], S, 0, 0, 0);
      // reg r holds subtile-key (r&3)+8*(r>>2)+4*hi for q-col l31

      // per-lane (one q) softmax over the 32 k of this subtile
      float pm = S[0];
#pragma unroll
      for (int r = 1; r < 16; ++r) pm = fmaxf(pm, S[r]);
      pm = fmaxf(pm, __shfl_xor(pm, 32, 64));
      float mq = m[qs];
      if (__any(pm > mq)) {              // wave-uniform rescale
        float mn = fmaxf(mq, pm);
        float al = __builtin_amdgcn_exp2f(mq - mn);  // exp2(-inf)=0 first time
        m[qs] = mn; mq = mn;
        lsum[qs] *= al;
        if (qs == 0) {
#pragma unroll
          for (int r = 0; r < 16; ++r) O0[r] *= al;
        } else {
#pragma unroll
          for (int r = 0; r < 16; ++r) O1[r] *= al;
        }
      }
      float pr[16], ps = 0.f;
#pragma unroll
      for (int r = 0; r < 16; ++r) {
        pr[r] = __builtin_amdgcn_exp2f(S[r] - mq);
        ps += pr[r];
      }
      lsum[qs] += ps + __shfl_xor(ps, 32, 64);

      // ---- assemble P^T B-fragments: elem e must be key 8*hi+e (+16 for P1).
      // word keys (hi=0 / hi=1):
      unsigned w01 = pack2(pr[0],  pr[1]);   // (0,1)   / (4,5)
      unsigned w23 = pack2(pr[2],  pr[3]);   // (2,3)   / (6,7)
      unsigned w45 = pack2(pr[4],  pr[5]);   // (8,9)   / (12,13)
      unsigned w67 = pack2(pr[6],  pr[7]);   // (10,11) / (14,15)
      unsigned w89 = pack2(pr[8],  pr[9]);   // (16,17) / (20,21)
      unsigned wab = pack2(pr[10], pr[11]);  // (18,19) / (22,23)
      unsigned wcd = pack2(pr[12], pr[13]);  // (24,25) / (28,29)
      unsigned wef = pack2(pr[14], pr[15]);  // (26,27) / (30,31)
      unsigned e01 = __shfl_xor(w01, 32, 64), e23 = __shfl_xor(w23, 32, 64);
      unsigned e45 = __shfl_xor(w45, 32, 64), e67 = __shfl_xor(w67, 32, 64);
      unsigned e89 = __shfl_xor(w89, 32, 64), eab = __shfl_xor(wab, 32, 64);
      unsigned ecd = __shfl_xor(wcd, 32, 64), eef = __shfl_xor(wef, 32, 64);
      union { short8 s; unsigned u[4]; } P0, P1;
      P0.u[0] = hi ? e45 : w01;  // hi=0: keys 0..7 ; hi=1: keys 8..15
      P0.u[1] = hi ? e67 : w23;
      P0.u[2] = hi ? w45 : e01;
      P0.u[3] = hi ? w67 : e23;
      P1.u[0] = hi ? ecd : w89;  // hi=0: keys 16..23 ; hi=1: keys 24..31
      P1.u[1] = hi ? eef : wab;
      P1.u[2] = hi ? wcd : e89;
      P1.u[3] = hi ? wef : eab;

      if (qs == 0) {
        O0 = __builtin_amdgcn_mfma_f32_32x32x16_bf16(Va, P0.s, O0, 0, 0, 0);
        O0 = __builtin_amdgcn_mfma_f32_32x32x16_bf16(Vb, P1.s, O0, 0, 0, 0);
      } else {
        O1 = __builtin_amdgcn_mfma_f32_32x32x16_bf16(Va, P0.s, O1, 0, 0, 0);
        O1 = __builtin_amdgcn_mfma_f32_32x32x16_bf16(Vb, P1.s, O1, 0, 0, 0);
      }
    }
  }

  // ---- epilogue: write partials (m,l in log2 space; O^T rows d=0..15) ----
  int slot = blk;   // bh*PAIRS + pair
#pragma unroll
  for (int qs = 0; qs < 2; ++qs) {
    int qloc = w * 64 + qs * 32 + l31;
    if (lane < 32) {
      PM[(size_t)slot * 256 + qloc] = m[qs];
      PL[(size_t)slot * 256 + qloc] = lsum[qs];
    }
#pragma unroll
    for (int r = 0; r < 8; ++r) {
      int d = (r & 3) + 8 * (r >> 2) + 4 * hi;
      float val = (qs == 0) ? O0[r] : O1[r];
      PACC[((size_t)slot * 16 + d) * 256 + qloc] = val;
    }
  }
}

// -------- merge partials -> O in [B,S,64] (head-interleaved) --------
__global__ void k_combine(const float* __restrict__ PM, const float* __restrict__ PL,
                          const float* __restrict__ PACC, float* __restrict__ ATTN) {
  int id = blockIdx.x * 256 + threadIdx.x;  // 32768 queries
  int n = id & 255, tq = (id >> 8) & 15, bh = id >> 12;
  int ns = tq + 1;
  int sb = bh * PAIRS + tq * (tq + 1) / 2;   // contiguous kt slots
  float M = -INFINITY;
  for (int s = 0; s < ns; ++s) M = fmaxf(M, PM[(size_t)(sb + s) * 256 + n]);
  float L = 0.f, acc[16];
#pragma unroll
  for (int d = 0; d < 16; ++d) acc[d] = 0.f;
  for (int s = 0; s < ns; ++s) {
    float wgt = __builtin_amdgcn_exp2f(PM[(size_t)(sb + s) * 256 + n] - M);
    L = fmaf(PL[(size_t)(sb + s) * 256 + n], wgt, L);
#pragma unroll
    for (int d = 0; d < 16; ++d)
      acc[d] = fmaf(PACC[((size_t)(sb + s) * 16 + d) * 256 + n], wgt, acc[d]);
  }
  float inv = 1.f / L;
  int b = bh >> 2, h = bh & 3;
  float* op = ATTN + ((size_t)(b * S_ + tq * N_ + n)) * 64 + h * 16;
#pragma unroll
  for (int d4 = 0; d4 < 4; ++d4) {
    float4 o;
    o.x = acc[4 * d4 + 0] * inv; o.y = acc[4 * d4 + 1] * inv;
    o.z = acc[4 * d4 + 2] * inv; o.w = acc[4 * d4 + 3] * inv;
    *(float4*)(op + 4 * d4) = o;
  }
}

// -------- o @ Wo + bo + residual, LayerNorm1 (wave per row, in-place X) ----
__global__ void k_proj_ln1(const float* __restrict__ O, const float* __restrict__ Wo,
                           const float* __restrict__ bo, const float* __restrict__ g,
                           const float* __restrict__ be, float* __restrict__ X) {
  int row = blockIdx.x * 4 + (threadIdx.x >> 6);
  int c = threadIdx.x & 63;
  const float* orow = O + (size_t)row * 64;
  float a = bo[c];
#pragma unroll 8
  for (int k = 0; k < 64; ++k) a = fmaf(orow[k], Wo[k * 64 + c], a);
  float val = a + X[(size_t)row * 64 + c];
  float mean = wave_sum(val) * (1.f / 64.f);
  float dv = val - mean;
  float var = wave_sum(dv * dv) * (1.f / 64.f);
  X[(size_t)row * 64 + c] = dv * rsqrtf(var + 1e-5f) * g[c] + be[c];
}

// -------- FFN (64->256 relu ->64) + residual + LayerNorm2, 8 rows/block ----
__global__ __launch_bounds__(256) void k_ffn_ln2(const float* __restrict__ W1,
    const float* __restrict__ b1, const float* __restrict__ W2, const float* __restrict__ b2,
    const float* __restrict__ g, const float* __restrict__ be, float* __restrict__ X) {
  __shared__ float xs[8][64];
  __shared__ float hs[8][256];
  int tid = threadIdx.x;
  size_t base = (size_t)blockIdx.x * 8 * 64;
#pragma unroll
  for (int i = 0; i < 2; ++i) {
    int idx = tid + 256 * i;
    xs[idx >> 6][idx & 63] = X[base + idx];
  }
  __syncthreads();
  float am[8];
#pragma unroll
  for (int r = 0; r < 8; ++r) am[r] = b1[tid];
#pragma unroll 4
  for (int k = 0; k < 64; ++k) {
    float w1 = W1[k * 256 + tid];
#pragma unroll
    for (int r = 0; r < 8; ++r) am[r] = fmaf(xs[r][k], w1, am[r]);
  }
#pragma unroll
  for (int r = 0; r < 8; ++r) hs[r][tid] = fmaxf(am[r], 0.f);
  __syncthreads();
  int c = tid & 63, grp = tid >> 6;
  float a0 = b2[c], a1 = b2[c];
#pragma unroll 4
  for (int k = 0; k < 256; ++k) {
    float w2 = W2[k * 64 + c];
    a0 = fmaf(hs[grp][k], w2, a0);
    a1 = fmaf(hs[grp + 4][k], w2, a1);
  }
  {
    float val = a0 + xs[grp][c];
    float mean = wave_sum(val) * (1.f / 64.f);
    float dv = val - mean;
    float var = wave_sum(dv * dv) * (1.f / 64.f);
    X[base + grp * 64 + c] = dv * rsqrtf(var + 1e-5f) * g[c] + be[c];
  }
  {
    float val = a1 + xs[grp + 4][c];
    float mean = wave_sum(val) * (1.f / 64.f);
    float dv = val - mean;
    float var = wave_sum(dv * dv) * (1.f / 64.f);
    X[base + (grp + 4) * 64 + c] = dv * rsqrtf(var + 1e-5f) * g[c] + be[c];
  }
}

// -------- decoder head on last timestep: 64->32->16->1, wave per (b,n) -----
__global__ void k_head(const float* __restrict__ X, const float* __restrict__ dW1,
    const float* __restrict__ db1, const float* __restrict__ dW2, const float* __restrict__ db2,
    const float* __restrict__ dW3, const float* __restrict__ db3, float* __restrict__ out) {
  __shared__ float h1s[4][32];
  __shared__ float h2s[4][16];
  int grp = threadIdx.x >> 6, lane = threadIdx.x & 63;
  int idx = blockIdx.x * 4 + grp;      // 0..511  (b*256+n)
  int b = idx >> 8, n = idx & 255;
  const float* row = X + ((size_t)(b * S_ + 15 * N_ + n)) * 64;
  if (lane < 32) {
    float a = db1[lane];
#pragma unroll 8
    for (int k = 0; k < 64; ++k) a = fmaf(row[k], dW1[k * 32 + lane], a);
    h1s[grp][lane] = fmaxf(a, 0.f);
  }
  __syncthreads();
  if (lane < 16) {
    float a = db2[lane];
#pragma unroll
    for (int k = 0; k < 32; ++k) a = fmaf(h1s[grp][k], dW2[k * 16 + lane], a);
    h2s[grp][lane] = fmaxf(a, 0.f);
  }
  __syncthreads();
  if (lane == 0) {
    float a = db3[0];
#pragma unroll
    for (int k = 0; k < 16; ++k) a = fmaf(h2s[grp][k], dW3[k], a);
    out[idx] = a;
  }
}

}  // namespace

extern "C" void kernel_launch(void* const* d_in, const int* in_sizes, int n_in,
                              void* d_out, int out_size, void* d_ws, size_t ws_size,
                              hipStream_t stream) {
  const float* x_seq = (const float*)d_in[0];
  // d_in[1] = edge_index (unused by reference)
  const float* Wi   = (const float*)d_in[2];
  const float* bi   = (const float*)d_in[3];
  const float* Wqkv = (const float*)d_in[4];
  const float* bqkv = (const float*)d_in[5];
  const float* Wo   = (const float*)d_in[6];
  const float* bo   = (const float*)d_in[7];
  const float* ln1g = (const float*)d_in[8];
  const float* ln1b = (const float*)d_in[9];
  const float* W1   = (const float*)d_in[10];
  const float* b1   = (const float*)d_in[11];
  const float* W2   = (const float*)d_in[12];
  const float* b2   = (const float*)d_in[13];
  const float* ln2g = (const float*)d_in[14];
  const float* ln2b = (const float*)d_in[15];
  const float* dW1  = (const float*)d_in[16];
  const float* db1  = (const float*)d_in[17];
  const float* dW2  = (const float*)d_in[18];
  const float* db2  = (const float*)d_in[19];
  const float* dW3  = (const float*)d_in[20];
  const float* db3  = (const float*)d_in[21];

  float* ws   = (float*)d_ws;  // needs >= 30.6 MB
  float* X    = ws + OFF_X;
  float* QKV  = ws + OFF_QKV;
  float* ATTN = ws + OFF_ATTN;
  float* PM   = ws + OFF_PM;
  float* PL   = ws + OFF_PL;
  float* PACC = ws + OFF_PACC;

  k_init_x<<<2048, 256, 0, stream>>>(x_seq, Wi, bi, X);
  for (int l = 0; l < 2; ++l) {
    k_qkv<<<8192, 192, 0, stream>>>(X, Wqkv + l * 64 * 192, bqkv + l * 192, QKV);
    k_attn<<<8 * PAIRS, 256, 0, stream>>>(QKV, PM, PL, PACC);
    k_combine<<<128, 256, 0, stream>>>(PM, PL, PACC, ATTN);
    k_proj_ln1<<<2048, 256, 0, stream>>>(ATTN, Wo + l * 4096, bo + l * 64,
                                         ln1g + l * 64, ln1b + l * 64, X);
    k_ffn_ln2<<<1024, 256, 0, stream>>>(W1 + l * 64 * 256, b1 + l * 256,
                                        W2 + l * 256 * 64, b2 + l * 64,
                                        ln2g + l * 64, ln2b + l * 64, X);
  }
  k_head<<<128, 256, 0, stream>>>(X, dW1, db1, dW2, db2, dW3, db3, (float*)d_out);
}

// Round 5
// 145.555 us; speedup vs baseline: 3.3368x; 1.4749x over previous
//
#include <hip/hip_runtime.h>
#include <math.h>

// GlobalTransformer: B=2, T=16, N=256 (S=4096), H=64, NHEAD=4, dh=16, L=2
// Round 5: rank-1 layer-0 QKV (FI=1), layer-1 computed only for t=15,
// fused proj/LN/FFN(/qkv/head) kernels, K staged hi/lo in LDS. 7 dispatches.

namespace {
constexpr int T_ = 16, N_ = 256, S_ = 4096;
constexpr int PAIRS = 136;   // valid (tq,kt) pairs per bh (layer 0)

// workspace layout (float offsets); total 7,639,296 floats = 30.6 MB
constexpr size_t OFF_A    = 0;         // [192]   Wi@Wqkv0
constexpr size_t OFF_BT   = 256;       // [16][192] (bi+tp)@Wqkv0 + bqkv0
constexpr size_t OFF_XB   = 3328;      // [16][64]  bi+tp
constexpr size_t OFF_X    = 4352;      // [B*S][64]
constexpr size_t OFF_QKV  = 528640;    // [B*S][192] (layer 1)
constexpr size_t OFF_ATTN = 2101504;   // [B*S][64]
constexpr size_t OFF_PM   = 2625792;   // [1088][256] (log2-space max)
constexpr size_t OFF_PL   = 2904320;   // [1088][256]
constexpr size_t OFF_PACC = 3182848;   // [1088][16][256]

typedef float  f32x16 __attribute__((ext_vector_type(16)));
typedef short  short8 __attribute__((ext_vector_type(8)));

__device__ inline float wave_sum(float v) {
#pragma unroll
  for (int off = 32; off > 0; off >>= 1) v += __shfl_xor(v, off, 64);
  return v;
}
__device__ inline unsigned bf16_rne(float f) {
  unsigned u = __float_as_uint(f);
  return (u + 0x7FFFu + ((u >> 16) & 1u)) >> 16;
}
__device__ inline unsigned pack2(float a, float b) {   // low<-a, high<-b
  return bf16_rne(a) | (bf16_rne(b) << 16);
}
__device__ inline f32x16 zero16() {
  f32x16 z;
#pragma unroll
  for (int i = 0; i < 16; ++i) z[i] = 0.f;
  return z;
}
// sinusoidal PE element
__device__ inline float pe_val(int t, int h) {
  float div = __expf((float)(h & ~1) * (-0.14391156831212787f));
  float arg = (float)t * div;
  return (h & 1) ? cosf(arg) : sinf(arg);
}

// -------- setup: A = Wi@Wqkv0 ; Bt = (bi+tp)@Wqkv0 + bqkv0 ; Xb = bi+tp ----
__global__ void k_setup(const float* __restrict__ Wi, const float* __restrict__ bi,
                        const float* __restrict__ Wqkv, const float* __restrict__ bqkv,
                        float* __restrict__ A, float* __restrict__ Bt,
                        float* __restrict__ Xb) {
  int t = blockIdx.x, c = threadIdx.x;   // grid 17 x 192
  if (t < 16) {
    float acc = bqkv[c];
#pragma unroll 8
    for (int h = 0; h < 64; ++h) {
      float xb = bi[h] + pe_val(t, h);
      acc = fmaf(xb, Wqkv[h * 192 + c], acc);
    }
    Bt[t * 192 + c] = acc;
    if (c < 64) Xb[t * 64 + c] = bi[c] + pe_val(t, c);
  } else {
    float acc = 0.f;
#pragma unroll 8
    for (int h = 0; h < 64; ++h) acc = fmaf(Wi[h], Wqkv[h * 192 + c], acc);
    A[c] = acc;
  }
}

// -------- MFMA flash attention partials -------------------------------------
// LAYER 0: Q/K/V synthesized from x_seq (rank-1) via A/Bt; blocks (bh,(tq,kt)).
// LAYER 1: Q/K/V from QKV buffer; tq=15 only; blocks (bh,kt).
// 4 waves; wave w owns q-rows [64w,64w+64). K staged hi/lo-split in LDS.
// Softmax/pack/PV body identical to round-4 verified code.
template <int LAYER>
__global__ __launch_bounds__(256, 4) void k_attn(
    const float* __restrict__ QKV, const float* __restrict__ x_seq,
    const float* __restrict__ A, const float* __restrict__ Bt,
    float* __restrict__ PM, float* __restrict__ PL, float* __restrict__ PACC) {
  __shared__ short KH[2][256][8];   // [d-half][key][d-elem], bf16 hi
  __shared__ short KL[2][256][8];   // bf16 lo
  __shared__ short VT[32][264];     // [d: 16 valid + 16 zeroed][key + pad]

  int blk = blockIdx.x;
  int bh, tq, kt;
  if (LAYER == 0) {
    bh = blk / PAIRS;
    int p = blk % PAIRS;
    tq = 0;
    while (p >= tq + 1) { p -= tq + 1; ++tq; }
    kt = p;
  } else {
    bh = blk >> 4; kt = blk & 15; tq = 15;
  }
  int b = bh >> 2, h = bh & 3;
  int tid = threadIdx.x, w = tid >> 6, lane = tid & 63;
  int l31 = lane & 31, hi = lane >> 5;
  const size_t qkvbase = (size_t)b * S_ * 192;

  // ---- zero VT d-rows 16..31 ----
  for (int i = tid; i < 16 * 264; i += 256) (&VT[16][0])[i] = 0;

  // ---- stage K (hi/lo split) and V^T : thread tid handles key tid ----
  {
    float kf[16], vf[16];
    if (LAYER == 1) {
      const float* kp = QKV + qkvbase + (size_t)(kt * N_ + tid) * 192 + 64 + h * 16;
#pragma unroll
      for (int i = 0; i < 4; ++i) {
        float4 k4 = *(const float4*)(kp + 4 * i);
        kf[4 * i] = k4.x; kf[4 * i + 1] = k4.y; kf[4 * i + 2] = k4.z; kf[4 * i + 3] = k4.w;
        float4 v4 = *(const float4*)(kp + 64 + 4 * i);
        vf[4 * i] = v4.x; vf[4 * i + 1] = v4.y; vf[4 * i + 2] = v4.z; vf[4 * i + 3] = v4.w;
      }
    } else {
      float xv = x_seq[b * S_ + kt * N_ + tid];
#pragma unroll
      for (int i = 0; i < 16; ++i) {
        kf[i] = fmaf(xv, A[64 + h * 16 + i],  Bt[kt * 192 + 64 + h * 16 + i]);
        vf[i] = fmaf(xv, A[128 + h * 16 + i], Bt[kt * 192 + 128 + h * 16 + i]);
      }
    }
    short8 kh0, kh1, kl0, kl1;
#pragma unroll
    for (int i = 0; i < 8; ++i) {
      unsigned ht0 = __float_as_uint(kf[i]) & 0xFFFF0000u;
      kh0[i] = (short)(ht0 >> 16);
      kl0[i] = (short)bf16_rne(kf[i] - __uint_as_float(ht0));
      unsigned ht1 = __float_as_uint(kf[i + 8]) & 0xFFFF0000u;
      kh1[i] = (short)(ht1 >> 16);
      kl1[i] = (short)bf16_rne(kf[i + 8] - __uint_as_float(ht1));
    }
    *(short8*)&KH[0][tid][0] = kh0;
    *(short8*)&KH[1][tid][0] = kh1;
    *(short8*)&KL[0][tid][0] = kl0;
    *(short8*)&KL[1][tid][0] = kl1;
#pragma unroll
    for (int i = 0; i < 16; ++i) VT[i][tid] = (short)bf16_rne(vf[i]);
  }
  __syncthreads();

  // ---- Q fragments (scaled by log2e/4), hi/lo split ----
  const float cscale = 0.36067376022224085f;  // (1/sqrt(16)) * log2(e)
  short8 Qh[2], Ql[2];
#pragma unroll
  for (int qs = 0; qs < 2; ++qs) {
    int qloc = w * 64 + qs * 32 + l31;
    float qf[8];
    if (LAYER == 1) {
      const float* qp = QKV + qkvbase + (size_t)(tq * N_ + qloc) * 192 + h * 16 + 8 * hi;
      float4 a4 = *(const float4*)(qp), b4 = *(const float4*)(qp + 4);
      qf[0] = a4.x; qf[1] = a4.y; qf[2] = a4.z; qf[3] = a4.w;
      qf[4] = b4.x; qf[5] = b4.y; qf[6] = b4.z; qf[7] = b4.w;
    } else {
      float xq = x_seq[b * S_ + tq * N_ + qloc];
#pragma unroll
      for (int i = 0; i < 8; ++i)
        qf[i] = fmaf(xq, A[h * 16 + 8 * hi + i], Bt[tq * 192 + h * 16 + 8 * hi + i]);
    }
#pragma unroll
    for (int i = 0; i < 8; ++i) {
      float q = qf[i] * cscale;
      unsigned ht = __float_as_uint(q) & 0xFFFF0000u;
      Qh[qs][i] = (short)(ht >> 16);
      Ql[qs][i] = (short)bf16_rne(q - __uint_as_float(ht));
    }
  }

  f32x16 O0 = zero16(), O1 = zero16();
  float m[2] = {-INFINITY, -INFINITY}, lsum[2] = {0.f, 0.f};

  for (int ks = 0; ks < 8; ++ks) {
    const short8 Kh = *(const short8*)&KH[hi][ks * 32 + l31][0];
    const short8 Kl = *(const short8*)&KL[hi][ks * 32 + l31][0];
    const short8 Va = *(const short8*)&VT[l31][ks * 32 + 8 * hi];
    const short8 Vb = *(const short8*)&VT[l31][ks * 32 + 8 * hi + 16];

#pragma unroll
    for (int qs = 0; qs < 2; ++qs) {
      // S^T[32k x 32q] = K * Q^T  (split: Kh*Qh + Kl*Qh + Kh*Ql)
      f32x16 S = zero16();
      S = __builtin_amdgcn_mfma_f32_32x32x16_bf16(Kh, Qh[qs], S, 0, 0, 0);
      S = __builtin_amdgcn_mfma_f32_32x32x16_bf16(Kl, Qh[qs], S, 0, 0, 0);
      S = __builtin_amdgcn_mfma_f32_32x32x16_bf16(Kh, Ql[qs], S, 0, 0, 0);
      // reg r holds subtile-key (r&3)+8*(r>>2)+4*hi for q-col l31

      float pm = S[0];
#pragma unroll
      for (int r = 1; r < 16; ++r) pm = fmaxf(pm, S[r]);
      pm = fmaxf(pm, __shfl_xor(pm, 32, 64));
      float mq = m[qs];
      if (__any(pm > mq)) {              // wave-uniform rescale
        float mn = fmaxf(mq, pm);
        float al = __builtin_amdgcn_exp2f(mq - mn);  // exp2(-inf)=0 first time
        m[qs] = mn; mq = mn;
        lsum[qs] *= al;
        if (qs == 0) {
#pragma unroll
          for (int r = 0; r < 16; ++r) O0[r] *= al;
        } else {
#pragma unroll
          for (int r = 0; r < 16; ++r) O1[r] *= al;
        }
      }
      float pr[16], ps = 0.f;
#pragma unroll
      for (int r = 0; r < 16; ++r) {
        pr[r] = __builtin_amdgcn_exp2f(S[r] - mq);
        ps += pr[r];
      }
      lsum[qs] += ps + __shfl_xor(ps, 32, 64);

      // assemble P^T B-fragments (elem e = key 8*hi+e, +16 for P1)
      unsigned w01 = pack2(pr[0],  pr[1]);
      unsigned w23 = pack2(pr[2],  pr[3]);
      unsigned w45 = pack2(pr[4],  pr[5]);
      unsigned w67 = pack2(pr[6],  pr[7]);
      unsigned w89 = pack2(pr[8],  pr[9]);
      unsigned wab = pack2(pr[10], pr[11]);
      unsigned wcd = pack2(pr[12], pr[13]);
      unsigned wef = pack2(pr[14], pr[15]);
      unsigned e01 = __shfl_xor(w01, 32, 64), e23 = __shfl_xor(w23, 32, 64);
      unsigned e45 = __shfl_xor(w45, 32, 64), e67 = __shfl_xor(w67, 32, 64);
      unsigned e89 = __shfl_xor(w89, 32, 64), eab = __shfl_xor(wab, 32, 64);
      unsigned ecd = __shfl_xor(wcd, 32, 64), eef = __shfl_xor(wef, 32, 64);
      union { short8 s; unsigned u[4]; } P0, P1;
      P0.u[0] = hi ? e45 : w01;
      P0.u[1] = hi ? e67 : w23;
      P0.u[2] = hi ? w45 : e01;
      P0.u[3] = hi ? w67 : e23;
      P1.u[0] = hi ? ecd : w89;
      P1.u[1] = hi ? eef : wab;
      P1.u[2] = hi ? wcd : e89;
      P1.u[3] = hi ? wef : eab;

      if (qs == 0) {
        O0 = __builtin_amdgcn_mfma_f32_32x32x16_bf16(Va, P0.s, O0, 0, 0, 0);
        O0 = __builtin_amdgcn_mfma_f32_32x32x16_bf16(Vb, P1.s, O0, 0, 0, 0);
      } else {
        O1 = __builtin_amdgcn_mfma_f32_32x32x16_bf16(Va, P0.s, O1, 0, 0, 0);
        O1 = __builtin_amdgcn_mfma_f32_32x32x16_bf16(Vb, P1.s, O1, 0, 0, 0);
      }
    }
  }

  // ---- epilogue: write partials (m,l in log2 space; O^T rows d=0..15) ----
  int slot = blk;
#pragma unroll
  for (int qs = 0; qs < 2; ++qs) {
    int qloc = w * 64 + qs * 32 + l31;
    if (lane < 32) {
      PM[(size_t)slot * 256 + qloc] = m[qs];
      PL[(size_t)slot * 256 + qloc] = lsum[qs];
    }
#pragma unroll
    for (int r = 0; r < 8; ++r) {
      int d = (r & 3) + 8 * (r >> 2) + 4 * hi;
      float val = (qs == 0) ? O0[r] : O1[r];
      PACC[((size_t)slot * 16 + d) * 256 + qloc] = val;
    }
  }
}

// -------- merge partials -> ATTN [B,S,64] (head-interleaved) ---------------
// LAYER 0: 256 blocks (bh,tq,dhalf), long-tq blocks first. LAYER 1: 16 blocks.
template <int LAYER>
__global__ void k_combine(const float* __restrict__ PM, const float* __restrict__ PL,
                          const float* __restrict__ PACC, float* __restrict__ ATTN) {
  int id = blockIdx.x * 256 + threadIdx.x;
  int n = id & 255, dhalf, tq, bh, ns, sb;
  if (LAYER == 0) {
    dhalf = (id >> 8) & 1;
    tq = 15 - ((id >> 9) & 15);
    bh = id >> 13;
    ns = tq + 1;
    sb = bh * PAIRS + tq * (tq + 1) / 2;
  } else {
    dhalf = (id >> 8) & 1;
    tq = 15;
    bh = id >> 9;
    ns = 16;
    sb = bh * 16;
  }
  float M = -INFINITY;
  for (int s = 0; s < ns; ++s) M = fmaxf(M, PM[(size_t)(sb + s) * 256 + n]);
  float L = 0.f, acc[8];
#pragma unroll
  for (int d = 0; d < 8; ++d) acc[d] = 0.f;
  for (int s = 0; s < ns; ++s) {
    float wgt = __builtin_amdgcn_exp2f(PM[(size_t)(sb + s) * 256 + n] - M);
    L = fmaf(PL[(size_t)(sb + s) * 256 + n], wgt, L);
#pragma unroll
    for (int d = 0; d < 8; ++d)
      acc[d] = fmaf(PACC[((size_t)(sb + s) * 16 + dhalf * 8 + d) * 256 + n], wgt, acc[d]);
  }
  float inv = 1.f / L;
  int b = bh >> 2, h = bh & 3;
  float* op = ATTN + ((size_t)(b * S_ + tq * N_ + n)) * 64 + h * 16 + dhalf * 8;
  float4 o0, o1;
  o0.x = acc[0] * inv; o0.y = acc[1] * inv; o0.z = acc[2] * inv; o0.w = acc[3] * inv;
  o1.x = acc[4] * inv; o1.y = acc[5] * inv; o1.z = acc[6] * inv; o1.w = acc[7] * inv;
  *(float4*)op = o0;
  *(float4*)(op + 4) = o1;
}

// -------- fused: o@Wo+bo + resid + LN1 + FFN + resid + LN2 (+qkv | +head) --
// LAYER 0: 1024 blocks x 8 rows; residual from rank-1 X; writes X and QKV(l1).
// LAYER 1: 64 blocks covering only t=15 rows; residual from X; computes head.
template <int LAYER>
__global__ __launch_bounds__(256) void k_fused(
    const float* __restrict__ ATTN, const float* __restrict__ Wo,
    const float* __restrict__ bo, const float* __restrict__ g1,
    const float* __restrict__ be1, const float* __restrict__ W1,
    const float* __restrict__ bb1, const float* __restrict__ W2,
    const float* __restrict__ bb2, const float* __restrict__ g2,
    const float* __restrict__ be2,
    const float* __restrict__ x_seq, const float* __restrict__ Wi,
    const float* __restrict__ Xb, float* __restrict__ X,
    const float* __restrict__ Wq1, const float* __restrict__ bq1,
    float* __restrict__ QKV,
    const float* __restrict__ dW1, const float* __restrict__ db1,
    const float* __restrict__ dW2, const float* __restrict__ db2,
    const float* __restrict__ dW3, const float* __restrict__ db3,
    float* __restrict__ out) {
  __shared__ float os[8][64], rs[8][64], xs[8][64], x2[8][64], hs[8][256];
  __shared__ float h1s[8][32], h2s[8][16];
  int tid = threadIdx.x;
  int row0;
  if (LAYER == 0) {
    row0 = blockIdx.x * 8;
  } else {
    int bb = blockIdx.x >> 5;                  // batch
    row0 = bb * S_ + 15 * N_ + (blockIdx.x & 31) * 8;
  }
  size_t base = (size_t)row0 * 64;

#pragma unroll
  for (int i = 0; i < 2; ++i) {
    int idx = tid + 256 * i;
    int r = idx >> 6, hh = idx & 63;
    os[r][hh] = ATTN[base + idx];
    if (LAYER == 0) {
      int gr = row0 + r, t = (gr >> 8) & 15;
      rs[r][hh] = fmaf(x_seq[gr], Wi[hh], Xb[t * 64 + hh]);
    } else {
      rs[r][hh] = X[base + idx];
    }
  }
  __syncthreads();

  int c = tid & 63, grp = tid >> 6;
  // proj + LN1 for rows grp, grp+4
#pragma unroll
  for (int rr = 0; rr < 2; ++rr) {
    int r = grp + 4 * rr;
    float a = bo[c];
#pragma unroll 8
    for (int k = 0; k < 64; ++k) a = fmaf(os[r][k], Wo[k * 64 + c], a);
    float val = a + rs[r][c];
    float mean = wave_sum(val) * (1.f / 64.f);
    float dv = val - mean;
    float var = wave_sum(dv * dv) * (1.f / 64.f);
    xs[r][c] = dv * rsqrtf(var + 1e-5f) * g1[c] + be1[c];
  }
  __syncthreads();

  // FFN phase 1: 64 -> 256, relu
  float am[8];
#pragma unroll
  for (int r = 0; r < 8; ++r) am[r] = bb1[tid];
#pragma unroll 4
  for (int k = 0; k < 64; ++k) {
    float w1 = W1[k * 256 + tid];
#pragma unroll
    for (int r = 0; r < 8; ++r) am[r] = fmaf(xs[r][k], w1, am[r]);
  }
#pragma unroll
  for (int r = 0; r < 8; ++r) hs[r][tid] = fmaxf(am[r], 0.f);
  __syncthreads();

  // FFN phase 2: 256 -> 64, + resid + LN2
  float a0 = bb2[c], a1 = bb2[c];
#pragma unroll 4
  for (int k = 0; k < 256; ++k) {
    float w2 = W2[k * 64 + c];
    a0 = fmaf(hs[grp][k], w2, a0);
    a1 = fmaf(hs[grp + 4][k], w2, a1);
  }
  {
    float val = a0 + xs[grp][c];
    float mean = wave_sum(val) * (1.f / 64.f);
    float dv = val - mean;
    float var = wave_sum(dv * dv) * (1.f / 64.f);
    float xn = dv * rsqrtf(var + 1e-5f) * g2[c] + be2[c];
    x2[grp][c] = xn;
    if (LAYER == 0) X[base + grp * 64 + c] = xn;
  }
  {
    float val = a1 + xs[grp + 4][c];
    float mean = wave_sum(val) * (1.f / 64.f);
    float dv = val - mean;
    float var = wave_sum(dv * dv) * (1.f / 64.f);
    float xn = dv * rsqrtf(var + 1e-5f) * g2[c] + be2[c];
    x2[grp + 4][c] = xn;
    if (LAYER == 0) X[base + (grp + 4) * 64 + c] = xn;
  }
  __syncthreads();

  if (LAYER == 0) {
    // qkv for layer 1: 8 rows x 192 cols
#pragma unroll
    for (int rep = 0; rep < 6; ++rep) {
      int idx = tid + 256 * rep;       // 0..1535
      int r = idx / 192, cc = idx % 192;
      float acc = bq1[cc];
#pragma unroll 8
      for (int k = 0; k < 64; ++k) acc = fmaf(x2[r][k], Wq1[k * 192 + cc], acc);
      QKV[(size_t)(row0 + r) * 192 + cc] = acc;
    }
  } else {
    // decoder head: 64 -> 32 -> 16 -> 1 on these (t=15) rows
    {
      int r = tid >> 5, mid = tid & 31;
      float a = db1[mid];
#pragma unroll 8
      for (int k = 0; k < 64; ++k) a = fmaf(x2[r][k], dW1[k * 32 + mid], a);
      h1s[r][mid] = fmaxf(a, 0.f);
    }
    __syncthreads();
    if (tid < 128) {
      int r = tid >> 4, low = tid & 15;
      float a = db2[low];
#pragma unroll
      for (int k = 0; k < 32; ++k) a = fmaf(h1s[r][k], dW2[k * 16 + low], a);
      h2s[r][low] = fmaxf(a, 0.f);
    }
    __syncthreads();
    if (tid < 8) {
      float a = db3[0];
#pragma unroll
      for (int k = 0; k < 16; ++k) a = fmaf(h2s[tid][k], dW3[k], a);
      int gr = row0 + tid;
      out[(gr >> 12) * 256 + (gr & 255)] = a;
    }
  }
}

}  // namespace

extern "C" void kernel_launch(void* const* d_in, const int* in_sizes, int n_in,
                              void* d_out, int out_size, void* d_ws, size_t ws_size,
                              hipStream_t stream) {
  const float* x_seq = (const float*)d_in[0];
  // d_in[1] = edge_index (unused by reference)
  const float* Wi   = (const float*)d_in[2];
  const float* bi   = (const float*)d_in[3];
  const float* Wqkv = (const float*)d_in[4];
  const float* bqkv = (const float*)d_in[5];
  const float* Wo   = (const float*)d_in[6];
  const float* bo   = (const float*)d_in[7];
  const float* ln1g = (const float*)d_in[8];
  const float* ln1b = (const float*)d_in[9];
  const float* W1   = (const float*)d_in[10];
  const float* b1   = (const float*)d_in[11];
  const float* W2   = (const float*)d_in[12];
  const float* b2   = (const float*)d_in[13];
  const float* ln2g = (const float*)d_in[14];
  const float* ln2b = (const float*)d_in[15];
  const float* dW1  = (const float*)d_in[16];
  const float* db1  = (const float*)d_in[17];
  const float* dW2  = (const float*)d_in[18];
  const float* db2  = (const float*)d_in[19];
  const float* dW3  = (const float*)d_in[20];
  const float* db3  = (const float*)d_in[21];

  float* ws   = (float*)d_ws;  // needs >= 30.6 MB
  float* A    = ws + OFF_A;
  float* Bt   = ws + OFF_BT;
  float* Xb   = ws + OFF_XB;
  float* X    = ws + OFF_X;
  float* QKV  = ws + OFF_QKV;
  float* ATTN = ws + OFF_ATTN;
  float* PM   = ws + OFF_PM;
  float* PL   = ws + OFF_PL;
  float* PACC = ws + OFF_PACC;

  k_setup<<<17, 192, 0, stream>>>(Wi, bi, Wqkv, bqkv, A, Bt, Xb);

  // ---- layer 0 ----
  k_attn<0><<<8 * PAIRS, 256, 0, stream>>>(nullptr, x_seq, A, Bt, PM, PL, PACC);
  k_combine<0><<<256, 256, 0, stream>>>(PM, PL, PACC, ATTN);
  k_fused<0><<<1024, 256, 0, stream>>>(ATTN, Wo, bo, ln1g, ln1b,
                                       W1, b1, W2, b2, ln2g, ln2b,
                                       x_seq, Wi, Xb, X,
                                       Wqkv + 64 * 192, bqkv + 192, QKV,
                                       nullptr, nullptr, nullptr, nullptr,
                                       nullptr, nullptr, nullptr);

  // ---- layer 1 (only tq = 15 feeds the head) ----
  k_attn<1><<<128, 256, 0, stream>>>(QKV, x_seq, A, Bt, PM, PL, PACC);
  k_combine<1><<<16, 256, 0, stream>>>(PM, PL, PACC, ATTN);
  k_fused<1><<<64, 256, 0, stream>>>(ATTN, Wo + 4096, bo + 64,
                                     ln1g + 64, ln1b + 64,
                                     W1 + 64 * 256, b1 + 256,
                                     W2 + 256 * 64, b2 + 64,
                                     ln2g + 64, ln2b + 64,
                                     x_seq, Wi, Xb, X,
                                     nullptr, nullptr, nullptr,
                                     dW1, db1, dW2, db2, dW3, db3,
                                     (float*)d_out);
}

// Round 6
// 108.349 us; speedup vs baseline: 4.4826x; 1.3434x over previous
//
#include <hip/hip_runtime.h>
#include <math.h>

// GlobalTransformer: B=2, T=16, N=256 (S=4096), H=64, NHEAD=4, dh=16, L=2
// Round 6: layer-0 attention via rank-1 algebra (FI=1): s = a*x' + c[t'],
// analytic group-max, partials = (Mg, sum_p, sum_p*x') per (query, kt).
// Combines fused into the fused kernels. 5 dispatches.

namespace {
constexpr int T_ = 16, N_ = 256, S_ = 4096;
constexpr int PAIRS = 136;   // valid (tq,kt) pairs per bh (layer 0)

// ws float offsets (total 4,265,472 floats = 17.1 MB)
constexpr size_t OFF_A    = 0;        // [192]   Wi@Wqkv0
constexpr size_t OFF_BT   = 192;      // [16][192] (bi+tp)@Wqkv0 + bqkv0
constexpr size_t OFF_XB   = 3264;     // [16][64]  bi+tp
constexpr size_t OFF_ALPH = 4288;     // [4]       k2*Aq.Ak
constexpr size_t OFF_BET  = 4292;     // [4][16]   k2*Aq.Bk[t']
constexpr size_t OFF_GAM  = 4356;     // [4][16]   k2*Ak.Bq[t]
constexpr size_t OFF_DELT = 4420;     // [4][16][16] k2*Bq[t].Bk[t']
constexpr size_t OFF_MN   = 5444;     // [2][16] min_n x_seq
constexpr size_t OFF_MX   = 5476;     // [2][16] max_n x_seq
constexpr size_t OFF_X    = 5632;     // [B*S][64] (only t=15 rows written)
constexpr size_t OFF_QKV  = 529920;   // [B*S][192] (layer 1)
constexpr size_t OFF_P0   = 2102784;  // [8][16][16][3][256] layer-0 partials
constexpr size_t OFF_PM1  = 3675648;  // [128][256]
constexpr size_t OFF_PL1  = 3708416;  // [128][256]
constexpr size_t OFF_PA1  = 3741184;  // [128][16][256]

typedef float  f32x16 __attribute__((ext_vector_type(16)));
typedef short  short8 __attribute__((ext_vector_type(8)));

__device__ inline float wave_sum(float v) {
#pragma unroll
  for (int off = 32; off > 0; off >>= 1) v += __shfl_xor(v, off, 64);
  return v;
}
__device__ inline unsigned bf16_rne(float f) {
  unsigned u = __float_as_uint(f);
  return (u + 0x7FFFu + ((u >> 16) & 1u)) >> 16;
}
__device__ inline unsigned pack2(float a, float b) {   // low<-a, high<-b
  return bf16_rne(a) | (bf16_rne(b) << 16);
}
__device__ inline f32x16 zero16() {
  f32x16 z;
#pragma unroll
  for (int i = 0; i < 16; ++i) z[i] = 0.f;
  return z;
}
__device__ inline float pe_val(int t, int h) {
  float div = __expf((float)(h & ~1) * (-0.14391156831212787f));  // -ln(1e4)/64
  float arg = (float)t * div;
  return (h & 1) ? cosf(arg) : sinf(arg);
}

// -------- setup: blocks 0..15 Bt/Xb, 16 A, 17 score tables, 18 mn/mx ------
__global__ void k_setup(const float* __restrict__ x_seq,
                        const float* __restrict__ Wi, const float* __restrict__ bi,
                        const float* __restrict__ Wqkv, const float* __restrict__ bqkv,
                        float* __restrict__ A, float* __restrict__ Bt,
                        float* __restrict__ Xb,
                        float* __restrict__ ALPH, float* __restrict__ BET,
                        float* __restrict__ GAM, float* __restrict__ DELT,
                        float* __restrict__ MN, float* __restrict__ MX) {
  int t = blockIdx.x, tid = threadIdx.x;
  if (t < 16) {
    if (tid < 192) {
      float acc = bqkv[tid];
#pragma unroll 8
      for (int h = 0; h < 64; ++h)
        acc = fmaf(bi[h] + pe_val(t, h), Wqkv[h * 192 + tid], acc);
      Bt[t * 192 + tid] = acc;
    }
    if (tid < 64) Xb[t * 64 + tid] = bi[tid] + pe_val(t, tid);
  } else if (t == 16) {
    if (tid < 192) {
      float acc = 0.f;
#pragma unroll 8
      for (int h = 0; h < 64; ++h) acc = fmaf(Wi[h], Wqkv[h * 192 + tid], acc);
      A[tid] = acc;
    }
  } else if (t == 17) {
    __shared__ float sA[128];       // Aq|Ak
    __shared__ float sB[16][128];   // Bq|Bk per timestep
    if (tid < 128) {
      float acc = 0.f;
#pragma unroll 8
      for (int h = 0; h < 64; ++h) acc = fmaf(Wi[h], Wqkv[h * 192 + tid], acc);
      sA[tid] = acc;
    }
    {
      int tt = tid >> 4, i = tid & 15;
      float accv[8];
#pragma unroll
      for (int j = 0; j < 8; ++j) accv[j] = bqkv[i * 8 + j];
      for (int h = 0; h < 64; ++h) {
        float xb = bi[h] + pe_val(tt, h);
#pragma unroll
        for (int j = 0; j < 8; ++j)
          accv[j] = fmaf(xb, Wqkv[h * 192 + i * 8 + j], accv[j]);
      }
#pragma unroll
      for (int j = 0; j < 8; ++j) sB[tt][i * 8 + j] = accv[j];
    }
    __syncthreads();
    const float k2 = 0.36067376022224085f;  // (1/sqrt(16)) * log2(e)
    if (tid < 4) {
      float d = 0.f;
#pragma unroll
      for (int i = 0; i < 16; ++i) d = fmaf(sA[tid * 16 + i], sA[64 + tid * 16 + i], d);
      ALPH[tid] = k2 * d;
    }
    if (tid < 64) {
      int h = tid >> 4, tp2 = tid & 15;
      float d = 0.f, g = 0.f;
#pragma unroll
      for (int i = 0; i < 16; ++i) {
        d = fmaf(sA[h * 16 + i], sB[tp2][64 + h * 16 + i], d);      // Aq.Bk[t']
        g = fmaf(sA[64 + h * 16 + i], sB[tp2][h * 16 + i], g);      // Ak.Bq[t]
      }
      BET[h * 16 + tp2] = k2 * d;
      GAM[h * 16 + tp2] = k2 * g;
    }
#pragma unroll
    for (int q = 0; q < 4; ++q) {
      int idx = tid + 256 * q;   // 1024 items: [h][tq][t']
      int h = idx >> 8, ta = (idx >> 4) & 15, tb = idx & 15;
      float d = 0.f;
#pragma unroll
      for (int i = 0; i < 16; ++i)
        d = fmaf(sB[ta][h * 16 + i], sB[tb][64 + h * 16 + i], d);   // Bq[ta].Bk[tb]
      DELT[h * 256 + ta * 16 + tb] = k2 * d;
    }
  } else {
    // t == 18: per-(b,t') min/max of x_seq
    int g = tid >> 3, i = tid & 7;           // g = b*16 + t'
    const float* xp = x_seq + (g >> 4) * S_ + (g & 15) * N_;
    float mn = 1e30f, mx = -1e30f;
    for (int j = i; j < 256; j += 8) {
      float v = xp[j];
      mn = fminf(mn, v); mx = fmaxf(mx, v);
    }
#pragma unroll
    for (int off = 1; off < 8; off <<= 1) {
      mn = fminf(mn, __shfl_xor(mn, off, 64));
      mx = fmaxf(mx, __shfl_xor(mx, off, 64));
    }
    if (i == 0) { MN[g] = mn; MX[g] = mx; }
  }
}

// -------- layer-0 attention partials via rank-1 algebra --------------------
// block = (bh, (tq,kt)); thread = query n. s2 = a*x' + c[kt] (log2 space);
// Mg analytic; store (Mg, sum exp2(a(x'-xe)), sum x'*exp2(...)).
__global__ __launch_bounds__(256, 4) void k_attn0(
    const float* __restrict__ x_seq,
    const float* __restrict__ ALPH, const float* __restrict__ BET,
    const float* __restrict__ GAM, const float* __restrict__ DELT,
    const float* __restrict__ MN, const float* __restrict__ MX,
    float* __restrict__ P0) {
  __shared__ float4 xk4[64];
  int blk = blockIdx.x;
  int bh = blk / PAIRS, pair = blk % PAIRS;
  int b = bh >> 2, h = bh & 3;
  int tq = 0, p = pair;
  while (p >= tq + 1) { p -= tq + 1; ++tq; }
  int kt = p;
  int tid = threadIdx.x;
  if (tid < 64) xk4[tid] = *(const float4*)(x_seq + (size_t)(b * S_ + kt * N_) + 4 * tid);
  __syncthreads();

  float x = x_seq[b * S_ + tq * N_ + tid];
  float a = fmaf(ALPH[h], x, GAM[h * 16 + tq]);
  float xext = (a >= 0.f) ? MX[b * 16 + kt] : MN[b * 16 + kt];
  float axext = a * xext;
  float Mg = axext + fmaf(BET[h * 16 + kt], x, DELT[h * 256 + tq * 16 + kt]);
  float sp0 = 0.f, sp1 = 0.f, sp2 = 0.f, sp3 = 0.f;
  float sx0 = 0.f, sx1 = 0.f, sx2 = 0.f, sx3 = 0.f;
#pragma unroll 8
  for (int j = 0; j < 64; ++j) {
    float4 xv = xk4[j];
    float e0 = __builtin_amdgcn_exp2f(fmaf(a, xv.x, -axext));
    float e1 = __builtin_amdgcn_exp2f(fmaf(a, xv.y, -axext));
    float e2 = __builtin_amdgcn_exp2f(fmaf(a, xv.z, -axext));
    float e3 = __builtin_amdgcn_exp2f(fmaf(a, xv.w, -axext));
    sp0 += e0; sp1 += e1; sp2 += e2; sp3 += e3;
    sx0 = fmaf(xv.x, e0, sx0); sx1 = fmaf(xv.y, e1, sx1);
    sx2 = fmaf(xv.z, e2, sx2); sx3 = fmaf(xv.w, e3, sx3);
  }
  size_t pb = ((size_t)(bh * 16 + tq) * 16 + kt) * 768;
  P0[pb + tid]       = Mg;
  P0[pb + 256 + tid] = (sp0 + sp1) + (sp2 + sp3);
  P0[pb + 512 + tid] = (sx0 + sx1) + (sx2 + sx3);
}

// -------- fused0: combine + proj + LN1 + FFN + LN2 + qkv(layer1) -----------
// block = 16 rows sharing (b,t); 512 blocks.
__global__ __launch_bounds__(256, 4) void k_fused0(
    const float* __restrict__ P0, const float* __restrict__ A,
    const float* __restrict__ Bt, const float* __restrict__ Xb,
    const float* __restrict__ x_seq, const float* __restrict__ Wi,
    const float* __restrict__ Wo, const float* __restrict__ bo,
    const float* __restrict__ g1, const float* __restrict__ be1,
    const float* __restrict__ W1, const float* __restrict__ bb1,
    const float* __restrict__ W2, const float* __restrict__ bb2,
    const float* __restrict__ g2, const float* __restrict__ be2,
    const float* __restrict__ Wq1, const float* __restrict__ bq1,
    float* __restrict__ X, float* __restrict__ QKV) {
  __shared__ float os[16][64], rs[16][64], xs[16][64], x2[16][64], hs[16][256];
  int tid = threadIdx.x;
  int row0 = blockIdx.x * 16;
  int b = row0 >> 12, t = (row0 >> 8) & 15, n0 = row0 & 255;

  // ---- phase A: attention combine -> os (already normalized) ----
  {
    int h = tid >> 6, d4 = (tid >> 4) & 3, r = tid & 15;
    int n = n0 + r, bh = b * 4 + h;
    float M = -INFINITY, D = 0.f, SX = 0.f;
    float bacc0 = 0.f, bacc1 = 0.f, bacc2 = 0.f, bacc3 = 0.f;
    for (int kt = 0; kt <= t; ++kt) {
      size_t pb = ((size_t)(bh * 16 + t) * 16 + kt) * 768 + n;
      float mg = P0[pb], sp = P0[pb + 256], sx = P0[pb + 512];
      float mnv = fmaxf(M, mg);
      float sc = __builtin_amdgcn_exp2f(M - mnv);   // first iter: exp2(-inf)=0
      float w  = __builtin_amdgcn_exp2f(mg - mnv);
      float wsp = w * sp;
      D  = fmaf(w, sp, D * sc);
      SX = fmaf(w, sx, SX * sc);
      float4 bv4 = *(const float4*)(Bt + kt * 192 + 128 + h * 16 + d4 * 4);
      bacc0 = fmaf(wsp, bv4.x, bacc0 * sc);
      bacc1 = fmaf(wsp, bv4.y, bacc1 * sc);
      bacc2 = fmaf(wsp, bv4.z, bacc2 * sc);
      bacc3 = fmaf(wsp, bv4.w, bacc3 * sc);
      M = mnv;
    }
    float invD = 1.f / D;
    float4 av4 = *(const float4*)(A + 128 + h * 16 + d4 * 4);
    os[r][h * 16 + d4 * 4 + 0] = fmaf(SX, av4.x, bacc0) * invD;
    os[r][h * 16 + d4 * 4 + 1] = fmaf(SX, av4.y, bacc1) * invD;
    os[r][h * 16 + d4 * 4 + 2] = fmaf(SX, av4.z, bacc2) * invD;
    os[r][h * 16 + d4 * 4 + 3] = fmaf(SX, av4.w, bacc3) * invD;
  }
  // ---- phase A2: residual (rank-1 X0) ----
#pragma unroll
  for (int i = 0; i < 4; ++i) {
    int idx = tid + 256 * i;
    int r = idx >> 6, cc = idx & 63;
    rs[r][cc] = fmaf(x_seq[row0 + r], Wi[cc], Xb[t * 64 + cc]);
  }
  __syncthreads();

  int c = tid & 63, grp = tid >> 6;
  // ---- phase B: proj + LN1 (wave grp handles rows grp+4*rr) ----
#pragma unroll
  for (int rr = 0; rr < 4; ++rr) {
    int r = grp + 4 * rr;
    float a = bo[c];
#pragma unroll 8
    for (int k = 0; k < 64; ++k) a = fmaf(os[r][k], Wo[k * 64 + c], a);
    float val = a + rs[r][c];
    float mean = wave_sum(val) * (1.f / 64.f);
    float dv = val - mean;
    float var = wave_sum(dv * dv) * (1.f / 64.f);
    xs[r][c] = dv * rsqrtf(var + 1e-5f) * g1[c] + be1[c];
  }
  __syncthreads();

  // ---- phase C: FFN1 64->256 relu ----
  {
    float am[16];
#pragma unroll
    for (int i = 0; i < 16; ++i) am[i] = bb1[tid];
    for (int k4 = 0; k4 < 16; ++k4) {
      float w0 = W1[(4 * k4 + 0) * 256 + tid];
      float w1v = W1[(4 * k4 + 1) * 256 + tid];
      float w2v = W1[(4 * k4 + 2) * 256 + tid];
      float w3v = W1[(4 * k4 + 3) * 256 + tid];
#pragma unroll
      for (int r = 0; r < 16; ++r) {
        float4 xv = *(const float4*)&xs[r][4 * k4];
        am[r] = fmaf(xv.x, w0, am[r]);
        am[r] = fmaf(xv.y, w1v, am[r]);
        am[r] = fmaf(xv.z, w2v, am[r]);
        am[r] = fmaf(xv.w, w3v, am[r]);
      }
    }
#pragma unroll
    for (int r = 0; r < 16; ++r) hs[r][tid] = fmaxf(am[r], 0.f);
  }
  __syncthreads();

  // ---- phase D: FFN2 256->64 + resid + LN2 ----
  {
    float a0 = bb2[c], a1 = bb2[c], a2 = bb2[c], a3 = bb2[c];
    for (int k4 = 0; k4 < 64; ++k4) {
      float w0 = W2[(4 * k4 + 0) * 64 + c];
      float w1v = W2[(4 * k4 + 1) * 64 + c];
      float w2v = W2[(4 * k4 + 2) * 64 + c];
      float w3v = W2[(4 * k4 + 3) * 64 + c];
      float4 h0 = *(const float4*)&hs[grp][4 * k4];
      float4 h1 = *(const float4*)&hs[grp + 4][4 * k4];
      float4 h2 = *(const float4*)&hs[grp + 8][4 * k4];
      float4 h3 = *(const float4*)&hs[grp + 12][4 * k4];
      a0 = fmaf(h0.x, w0, a0); a0 = fmaf(h0.y, w1v, a0);
      a0 = fmaf(h0.z, w2v, a0); a0 = fmaf(h0.w, w3v, a0);
      a1 = fmaf(h1.x, w0, a1); a1 = fmaf(h1.y, w1v, a1);
      a1 = fmaf(h1.z, w2v, a1); a1 = fmaf(h1.w, w3v, a1);
      a2 = fmaf(h2.x, w0, a2); a2 = fmaf(h2.y, w1v, a2);
      a2 = fmaf(h2.z, w2v, a2); a2 = fmaf(h2.w, w3v, a2);
      a3 = fmaf(h3.x, w0, a3); a3 = fmaf(h3.y, w1v, a3);
      a3 = fmaf(h3.z, w2v, a3); a3 = fmaf(h3.w, w3v, a3);
    }
    float av[4] = {a0, a1, a2, a3};
#pragma unroll
    for (int rr = 0; rr < 4; ++rr) {
      int r = grp + 4 * rr;
      float val = av[rr] + xs[r][c];
      float mean = wave_sum(val) * (1.f / 64.f);
      float dv = val - mean;
      float var = wave_sum(dv * dv) * (1.f / 64.f);
      float xn = dv * rsqrtf(var + 1e-5f) * g2[c] + be2[c];
      x2[r][c] = xn;
      if (t == 15) X[(size_t)(row0 + r) * 64 + c] = xn;
    }
  }
  __syncthreads();

  // ---- phase E: qkv for layer 1 ----
  if (tid < 192) {
    float acc[16];
#pragma unroll
    for (int r = 0; r < 16; ++r) acc[r] = bq1[tid];
    for (int k4 = 0; k4 < 16; ++k4) {
      float w0 = Wq1[(4 * k4 + 0) * 192 + tid];
      float w1v = Wq1[(4 * k4 + 1) * 192 + tid];
      float w2v = Wq1[(4 * k4 + 2) * 192 + tid];
      float w3v = Wq1[(4 * k4 + 3) * 192 + tid];
#pragma unroll
      for (int r = 0; r < 16; ++r) {
        float4 xv = *(const float4*)&x2[r][4 * k4];
        acc[r] = fmaf(xv.x, w0, acc[r]);
        acc[r] = fmaf(xv.y, w1v, acc[r]);
        acc[r] = fmaf(xv.z, w2v, acc[r]);
        acc[r] = fmaf(xv.w, w3v, acc[r]);
      }
    }
#pragma unroll
    for (int r = 0; r < 16; ++r)
      QKV[(size_t)(row0 + r) * 192 + tid] = acc[r];
  }
}

// -------- layer-1 MFMA flash attention (tq=15 only), round-4-verified body -
__global__ __launch_bounds__(256, 4) void k_attn1(const float* __restrict__ QKV,
    float* __restrict__ PM, float* __restrict__ PL, float* __restrict__ PACC) {
  __shared__ short KH[2][256][8];
  __shared__ short KL[2][256][8];
  __shared__ short VT[32][264];
  int blk = blockIdx.x;
  int bh = blk >> 4, kt = blk & 15;
  const int tq = 15;
  int b = bh >> 2, h = bh & 3;
  int tid = threadIdx.x, w = tid >> 6, lane = tid & 63;
  int l31 = lane & 31, hi = lane >> 5;
  const size_t qkvbase = (size_t)b * S_ * 192;

  for (int i = tid; i < 16 * 264; i += 256) (&VT[16][0])[i] = 0;
  {
    const float* kp = QKV + qkvbase + (size_t)(kt * N_ + tid) * 192 + 64 + h * 16;
    float kf[16], vf[16];
#pragma unroll
    for (int i = 0; i < 4; ++i) {
      float4 k4 = *(const float4*)(kp + 4 * i);
      kf[4 * i] = k4.x; kf[4 * i + 1] = k4.y; kf[4 * i + 2] = k4.z; kf[4 * i + 3] = k4.w;
      float4 v4 = *(const float4*)(kp + 64 + 4 * i);
      vf[4 * i] = v4.x; vf[4 * i + 1] = v4.y; vf[4 * i + 2] = v4.z; vf[4 * i + 3] = v4.w;
    }
    short8 kh0, kh1, kl0, kl1;
#pragma unroll
    for (int i = 0; i < 8; ++i) {
      unsigned ht0 = __float_as_uint(kf[i]) & 0xFFFF0000u;
      kh0[i] = (short)(ht0 >> 16);
      kl0[i] = (short)bf16_rne(kf[i] - __uint_as_float(ht0));
      unsigned ht1 = __float_as_uint(kf[i + 8]) & 0xFFFF0000u;
      kh1[i] = (short)(ht1 >> 16);
      kl1[i] = (short)bf16_rne(kf[i + 8] - __uint_as_float(ht1));
    }
    *(short8*)&KH[0][tid][0] = kh0;
    *(short8*)&KH[1][tid][0] = kh1;
    *(short8*)&KL[0][tid][0] = kl0;
    *(short8*)&KL[1][tid][0] = kl1;
#pragma unroll
    for (int i = 0; i < 16; ++i) VT[i][tid] = (short)bf16_rne(vf[i]);
  }
  __syncthreads();

  const float cscale = 0.36067376022224085f;
  short8 Qh[2], Ql[2];
#pragma unroll
  for (int qs = 0; qs < 2; ++qs) {
    int qloc = w * 64 + qs * 32 + l31;
    const float* qp = QKV + qkvbase + (size_t)(tq * N_ + qloc) * 192 + h * 16 + 8 * hi;
    float4 a4 = *(const float4*)(qp), b4 = *(const float4*)(qp + 4);
    float qf[8] = {a4.x, a4.y, a4.z, a4.w, b4.x, b4.y, b4.z, b4.w};
#pragma unroll
    for (int i = 0; i < 8; ++i) {
      float q = qf[i] * cscale;
      unsigned ht = __float_as_uint(q) & 0xFFFF0000u;
      Qh[qs][i] = (short)(ht >> 16);
      Ql[qs][i] = (short)bf16_rne(q - __uint_as_float(ht));
    }
  }

  f32x16 O0 = zero16(), O1 = zero16();
  float m[2] = {-INFINITY, -INFINITY}, lsum[2] = {0.f, 0.f};

  for (int ks = 0; ks < 8; ++ks) {
    const short8 Kh = *(const short8*)&KH[hi][ks * 32 + l31][0];
    const short8 Kl = *(const short8*)&KL[hi][ks * 32 + l31][0];
    const short8 Va = *(const short8*)&VT[l31][ks * 32 + 8 * hi];
    const short8 Vb = *(const short8*)&VT[l31][ks * 32 + 8 * hi + 16];

#pragma unroll
    for (int qs = 0; qs < 2; ++qs) {
      f32x16 S = zero16();
      S = __builtin_amdgcn_mfma_f32_32x32x16_bf16(Kh, Qh[qs], S, 0, 0, 0);
      S = __builtin_amdgcn_mfma_f32_32x32x16_bf16(Kl, Qh[qs], S, 0, 0, 0);
      S = __builtin_amdgcn_mfma_f32_32x32x16_bf16(Kh, Ql[qs], S, 0, 0, 0);

      float pm = S[0];
#pragma unroll
      for (int r = 1; r < 16; ++r) pm = fmaxf(pm, S[r]);
      pm = fmaxf(pm, __shfl_xor(pm, 32, 64));
      float mq = m[qs];
      if (__any(pm > mq)) {
        float mn = fmaxf(mq, pm);
        float al = __builtin_amdgcn_exp2f(mq - mn);
        m[qs] = mn; mq = mn;
        lsum[qs] *= al;
        if (qs == 0) {
#pragma unroll
          for (int r = 0; r < 16; ++r) O0[r] *= al;
        } else {
#pragma unroll
          for (int r = 0; r < 16; ++r) O1[r] *= al;
        }
      }
      float pr[16], ps = 0.f;
#pragma unroll
      for (int r = 0; r < 16; ++r) {
        pr[r] = __builtin_amdgcn_exp2f(S[r] - mq);
        ps += pr[r];
      }
      lsum[qs] += ps + __shfl_xor(ps, 32, 64);

      unsigned w01 = pack2(pr[0],  pr[1]);
      unsigned w23 = pack2(pr[2],  pr[3]);
      unsigned w45 = pack2(pr[4],  pr[5]);
      unsigned w67 = pack2(pr[6],  pr[7]);
      unsigned w89 = pack2(pr[8],  pr[9]);
      unsigned wab = pack2(pr[10], pr[11]);
      unsigned wcd = pack2(pr[12], pr[13]);
      unsigned wef = pack2(pr[14], pr[15]);
      unsigned e01 = __shfl_xor(w01, 32, 64), e23 = __shfl_xor(w23, 32, 64);
      unsigned e45 = __shfl_xor(w45, 32, 64), e67 = __shfl_xor(w67, 32, 64);
      unsigned e89 = __shfl_xor(w89, 32, 64), eab = __shfl_xor(wab, 32, 64);
      unsigned ecd = __shfl_xor(wcd, 32, 64), eef = __shfl_xor(wef, 32, 64);
      union { short8 s; unsigned u[4]; } P0u, P1u;
      P0u.u[0] = hi ? e45 : w01;
      P0u.u[1] = hi ? e67 : w23;
      P0u.u[2] = hi ? w45 : e01;
      P0u.u[3] = hi ? w67 : e23;
      P1u.u[0] = hi ? ecd : w89;
      P1u.u[1] = hi ? eef : wab;
      P1u.u[2] = hi ? wcd : e89;
      P1u.u[3] = hi ? wef : eab;

      if (qs == 0) {
        O0 = __builtin_amdgcn_mfma_f32_32x32x16_bf16(Va, P0u.s, O0, 0, 0, 0);
        O0 = __builtin_amdgcn_mfma_f32_32x32x16_bf16(Vb, P1u.s, O0, 0, 0, 0);
      } else {
        O1 = __builtin_amdgcn_mfma_f32_32x32x16_bf16(Va, P0u.s, O1, 0, 0, 0);
        O1 = __builtin_amdgcn_mfma_f32_32x32x16_bf16(Vb, P1u.s, O1, 0, 0, 0);
      }
    }
  }

  int slot = blk;
#pragma unroll
  for (int qs = 0; qs < 2; ++qs) {
    int qloc = w * 64 + qs * 32 + l31;
    if (lane < 32) {
      PM[(size_t)slot * 256 + qloc] = m[qs];
      PL[(size_t)slot * 256 + qloc] = lsum[qs];
    }
#pragma unroll
    for (int r = 0; r < 8; ++r) {
      int d = (r & 3) + 8 * (r >> 2) + 4 * hi;
      float val = (qs == 0) ? O0[r] : O1[r];
      PACC[((size_t)slot * 16 + d) * 256 + qloc] = val;
    }
  }
}

// -------- fused1: combine + proj + LN1 + FFN + LN2 + head (t=15 rows) ------
__global__ __launch_bounds__(256) void k_fused1(
    const float* __restrict__ PM1, const float* __restrict__ PL1,
    const float* __restrict__ PA1,
    const float* __restrict__ Wo, const float* __restrict__ bo,
    const float* __restrict__ g1, const float* __restrict__ be1,
    const float* __restrict__ W1, const float* __restrict__ bb1,
    const float* __restrict__ W2, const float* __restrict__ bb2,
    const float* __restrict__ g2, const float* __restrict__ be2,
    const float* __restrict__ X,
    const float* __restrict__ dW1, const float* __restrict__ db1,
    const float* __restrict__ dW2, const float* __restrict__ db2,
    const float* __restrict__ dW3, const float* __restrict__ db3,
    float* __restrict__ out) {
  __shared__ float os[8][64], rs[8][64], xs[8][64], x2[8][64], hs[8][256];
  __shared__ float h1s[8][32], h2s[8][16];
  int tid = threadIdx.x;
  int bb = blockIdx.x >> 5;
  int nbase = (blockIdx.x & 31) * 8;
  int row0 = bb * S_ + 15 * N_ + nbase;
  size_t base = (size_t)row0 * 64;

  // phase A: combine MFMA partials -> os
#pragma unroll
  for (int qq = 0; qq < 2; ++qq) {
    int idx = tid + 256 * qq;
    int r = idx & 7, h = (idx >> 3) & 3, d = (idx >> 5) & 15;
    int n = nbase + r;
    int sb = (bb * 4 + h) * 16;
    float M = -INFINITY;
#pragma unroll
    for (int s = 0; s < 16; ++s) M = fmaxf(M, PM1[(size_t)(sb + s) * 256 + n]);
    float D = 0.f, od = 0.f;
#pragma unroll
    for (int s = 0; s < 16; ++s) {
      float wgt = __builtin_amdgcn_exp2f(PM1[(size_t)(sb + s) * 256 + n] - M);
      D = fmaf(PL1[(size_t)(sb + s) * 256 + n], wgt, D);
      od = fmaf(PA1[((size_t)(sb + s) * 16 + d) * 256 + n], wgt, od);
    }
    os[r][h * 16 + d] = od / D;
  }
#pragma unroll
  for (int i = 0; i < 2; ++i) {
    int idx = tid + 256 * i;
    rs[idx >> 6][idx & 63] = X[base + idx];
  }
  __syncthreads();

  int c = tid & 63, grp = tid >> 6;
#pragma unroll
  for (int rr = 0; rr < 2; ++rr) {
    int r = grp + 4 * rr;
    float a = bo[c];
#pragma unroll 8
    for (int k = 0; k < 64; ++k) a = fmaf(os[r][k], Wo[k * 64 + c], a);
    float val = a + rs[r][c];
    float mean = wave_sum(val) * (1.f / 64.f);
    float dv = val - mean;
    float var = wave_sum(dv * dv) * (1.f / 64.f);
    xs[r][c] = dv * rsqrtf(var + 1e-5f) * g1[c] + be1[c];
  }
  __syncthreads();

  float am[8];
#pragma unroll
  for (int r = 0; r < 8; ++r) am[r] = bb1[tid];
#pragma unroll 4
  for (int k = 0; k < 64; ++k) {
    float w1 = W1[k * 256 + tid];
#pragma unroll
    for (int r = 0; r < 8; ++r) am[r] = fmaf(xs[r][k], w1, am[r]);
  }
#pragma unroll
  for (int r = 0; r < 8; ++r) hs[r][tid] = fmaxf(am[r], 0.f);
  __syncthreads();

  float a0 = bb2[c], a1 = bb2[c];
#pragma unroll 4
  for (int k = 0; k < 256; ++k) {
    float w2 = W2[k * 64 + c];
    a0 = fmaf(hs[grp][k], w2, a0);
    a1 = fmaf(hs[grp + 4][k], w2, a1);
  }
  {
    float val = a0 + xs[grp][c];
    float mean = wave_sum(val) * (1.f / 64.f);
    float dv = val - mean;
    float var = wave_sum(dv * dv) * (1.f / 64.f);
    x2[grp][c] = dv * rsqrtf(var + 1e-5f) * g2[c] + be2[c];
  }
  {
    float val = a1 + xs[grp + 4][c];
    float mean = wave_sum(val) * (1.f / 64.f);
    float dv = val - mean;
    float var = wave_sum(dv * dv) * (1.f / 64.f);
    x2[grp + 4][c] = dv * rsqrtf(var + 1e-5f) * g2[c] + be2[c];
  }
  __syncthreads();

  {
    int r = tid >> 5, mid = tid & 31;
    float a = db1[mid];
#pragma unroll 8
    for (int k = 0; k < 64; ++k) a = fmaf(x2[r][k], dW1[k * 32 + mid], a);
    h1s[r][mid] = fmaxf(a, 0.f);
  }
  __syncthreads();
  if (tid < 128) {
    int r = tid >> 4, low = tid & 15;
    float a = db2[low];
#pragma unroll
    for (int k = 0; k < 32; ++k) a = fmaf(h1s[r][k], dW2[k * 16 + low], a);
    h2s[r][low] = fmaxf(a, 0.f);
  }
  __syncthreads();
  if (tid < 8) {
    float a = db3[0];
#pragma unroll
    for (int k = 0; k < 16; ++k) a = fmaf(h2s[tid][k], dW3[k], a);
    out[bb * 256 + nbase + tid] = a;
  }
}

}  // namespace

extern "C" void kernel_launch(void* const* d_in, const int* in_sizes, int n_in,
                              void* d_out, int out_size, void* d_ws, size_t ws_size,
                              hipStream_t stream) {
  const float* x_seq = (const float*)d_in[0];
  // d_in[1] = edge_index (unused by reference)
  const float* Wi   = (const float*)d_in[2];
  const float* bi   = (const float*)d_in[3];
  const float* Wqkv = (const float*)d_in[4];
  const float* bqkv = (const float*)d_in[5];
  const float* Wo   = (const float*)d_in[6];
  const float* bo   = (const float*)d_in[7];
  const float* ln1g = (const float*)d_in[8];
  const float* ln1b = (const float*)d_in[9];
  const float* W1   = (const float*)d_in[10];
  const float* b1   = (const float*)d_in[11];
  const float* W2   = (const float*)d_in[12];
  const float* b2   = (const float*)d_in[13];
  const float* ln2g = (const float*)d_in[14];
  const float* ln2b = (const float*)d_in[15];
  const float* dW1  = (const float*)d_in[16];
  const float* db1  = (const float*)d_in[17];
  const float* dW2  = (const float*)d_in[18];
  const float* db2  = (const float*)d_in[19];
  const float* dW3  = (const float*)d_in[20];
  const float* db3  = (const float*)d_in[21];

  float* ws   = (float*)d_ws;  // needs >= 17.1 MB
  float* A    = ws + OFF_A;
  float* Bt   = ws + OFF_BT;
  float* Xb   = ws + OFF_XB;
  float* ALPH = ws + OFF_ALPH;
  float* BET  = ws + OFF_BET;
  float* GAM  = ws + OFF_GAM;
  float* DELT = ws + OFF_DELT;
  float* MN   = ws + OFF_MN;
  float* MX   = ws + OFF_MX;
  float* X    = ws + OFF_X;
  float* QKV  = ws + OFF_QKV;
  float* P0   = ws + OFF_P0;
  float* PM1  = ws + OFF_PM1;
  float* PL1  = ws + OFF_PL1;
  float* PA1  = ws + OFF_PA1;

  k_setup<<<19, 256, 0, stream>>>(x_seq, Wi, bi, Wqkv, bqkv, A, Bt, Xb,
                                  ALPH, BET, GAM, DELT, MN, MX);
  k_attn0<<<8 * PAIRS, 256, 0, stream>>>(x_seq, ALPH, BET, GAM, DELT, MN, MX, P0);
  k_fused0<<<512, 256, 0, stream>>>(P0, A, Bt, Xb, x_seq, Wi,
                                    Wo, bo, ln1g, ln1b, W1, b1, W2, b2,
                                    ln2g, ln2b, Wqkv + 64 * 192, bqkv + 192,
                                    X, QKV);
  k_attn1<<<128, 256, 0, stream>>>(QKV, PM1, PL1, PA1);
  k_fused1<<<64, 256, 0, stream>>>(PM1, PL1, PA1,
                                   Wo + 4096, bo + 64, ln1g + 64, ln1b + 64,
                                   W1 + 64 * 256, b1 + 256, W2 + 256 * 64, b2 + 64,
                                   ln2g + 64, ln2b + 64, X,
                                   dW1, db1, dW2, db2, dW3, db3, (float*)d_out);
}

// Round 7
// 107.514 us; speedup vs baseline: 4.5174x; 1.0078x over previous
//
#include <hip/hip_runtime.h>
#include <math.h>

// GlobalTransformer: B=2, T=16, N=256 (S=4096), H=64, NHEAD=4, dh=16, L=2
// Round 7: same algorithm as round 6 (rank-1 layer-0 attention, t=15-only
// layer 1), restructured for occupancy: fused0 = 8 rows x 1024 blocks,
// fused1 = 2 rows x 128 threads x 256 blocks. 5 dispatches.

namespace {
constexpr int T_ = 16, N_ = 256, S_ = 4096;
constexpr int PAIRS = 136;   // valid (tq,kt) pairs per bh (layer 0)

// ws float offsets (total 4,265,472 floats = 17.1 MB)
constexpr size_t OFF_A    = 0;        // [192]   Wi@Wqkv0
constexpr size_t OFF_BT   = 192;      // [16][192] (bi+tp)@Wqkv0 + bqkv0
constexpr size_t OFF_XB   = 3264;     // [16][64]  bi+tp
constexpr size_t OFF_ALPH = 4288;     // [4]       k2*Aq.Ak
constexpr size_t OFF_BET  = 4292;     // [4][16]   k2*Aq.Bk[t']
constexpr size_t OFF_GAM  = 4356;     // [4][16]   k2*Ak.Bq[t]
constexpr size_t OFF_DELT = 4420;     // [4][16][16] k2*Bq[t].Bk[t']
constexpr size_t OFF_MN   = 5444;     // [2][16] min_n x_seq
constexpr size_t OFF_MX   = 5476;     // [2][16] max_n x_seq
constexpr size_t OFF_X    = 5632;     // [B*S][64] (only t=15 rows written)
constexpr size_t OFF_QKV  = 529920;   // [B*S][192] (layer 1; Q cols only t=15)
constexpr size_t OFF_P0   = 2102784;  // [8][16][16][3][256] layer-0 partials
constexpr size_t OFF_PM1  = 3675648;  // [128][256]
constexpr size_t OFF_PL1  = 3708416;  // [128][256]
constexpr size_t OFF_PA1  = 3741184;  // [128][16][256]

typedef float  f32x16 __attribute__((ext_vector_type(16)));
typedef short  short8 __attribute__((ext_vector_type(8)));

__device__ inline float wave_sum(float v) {
#pragma unroll
  for (int off = 32; off > 0; off >>= 1) v += __shfl_xor(v, off, 64);
  return v;
}
__device__ inline unsigned bf16_rne(float f) {
  unsigned u = __float_as_uint(f);
  return (u + 0x7FFFu + ((u >> 16) & 1u)) >> 16;
}
__device__ inline unsigned pack2(float a, float b) {   // low<-a, high<-b
  return bf16_rne(a) | (bf16_rne(b) << 16);
}
__device__ inline f32x16 zero16() {
  f32x16 z;
#pragma unroll
  for (int i = 0; i < 16; ++i) z[i] = 0.f;
  return z;
}
__device__ inline float pe_val(int t, int h) {
  float div = __expf((float)(h & ~1) * (-0.14391156831212787f));  // -ln(1e4)/64
  float arg = (float)t * div;
  return (h & 1) ? cosf(arg) : sinf(arg);
}

// -------- setup: blocks 0..15 Bt/Xb, 16 A, 17 score tables, 18 mn/mx ------
__global__ void k_setup(const float* __restrict__ x_seq,
                        const float* __restrict__ Wi, const float* __restrict__ bi,
                        const float* __restrict__ Wqkv, const float* __restrict__ bqkv,
                        float* __restrict__ A, float* __restrict__ Bt,
                        float* __restrict__ Xb,
                        float* __restrict__ ALPH, float* __restrict__ BET,
                        float* __restrict__ GAM, float* __restrict__ DELT,
                        float* __restrict__ MN, float* __restrict__ MX) {
  int t = blockIdx.x, tid = threadIdx.x;
  if (t < 16) {
    if (tid < 192) {
      float acc = bqkv[tid];
#pragma unroll 8
      for (int h = 0; h < 64; ++h)
        acc = fmaf(bi[h] + pe_val(t, h), Wqkv[h * 192 + tid], acc);
      Bt[t * 192 + tid] = acc;
    }
    if (tid < 64) Xb[t * 64 + tid] = bi[tid] + pe_val(t, tid);
  } else if (t == 16) {
    if (tid < 192) {
      float acc = 0.f;
#pragma unroll 8
      for (int h = 0; h < 64; ++h) acc = fmaf(Wi[h], Wqkv[h * 192 + tid], acc);
      A[tid] = acc;
    }
  } else if (t == 17) {
    __shared__ float sA[128];       // Aq|Ak
    __shared__ float sB[16][128];   // Bq|Bk per timestep
    if (tid < 128) {
      float acc = 0.f;
#pragma unroll 8
      for (int h = 0; h < 64; ++h) acc = fmaf(Wi[h], Wqkv[h * 192 + tid], acc);
      sA[tid] = acc;
    }
    {
      int tt = tid >> 4, i = tid & 15;
      float accv[8];
#pragma unroll
      for (int j = 0; j < 8; ++j) accv[j] = bqkv[i * 8 + j];
      for (int h = 0; h < 64; ++h) {
        float xb = bi[h] + pe_val(tt, h);
#pragma unroll
        for (int j = 0; j < 8; ++j)
          accv[j] = fmaf(xb, Wqkv[h * 192 + i * 8 + j], accv[j]);
      }
#pragma unroll
      for (int j = 0; j < 8; ++j) sB[tt][i * 8 + j] = accv[j];
    }
    __syncthreads();
    const float k2 = 0.36067376022224085f;  // (1/sqrt(16)) * log2(e)
    if (tid < 4) {
      float d = 0.f;
#pragma unroll
      for (int i = 0; i < 16; ++i) d = fmaf(sA[tid * 16 + i], sA[64 + tid * 16 + i], d);
      ALPH[tid] = k2 * d;
    }
    if (tid < 64) {
      int h = tid >> 4, tp2 = tid & 15;
      float d = 0.f, g = 0.f;
#pragma unroll
      for (int i = 0; i < 16; ++i) {
        d = fmaf(sA[h * 16 + i], sB[tp2][64 + h * 16 + i], d);      // Aq.Bk[t']
        g = fmaf(sA[64 + h * 16 + i], sB[tp2][h * 16 + i], g);      // Ak.Bq[t]
      }
      BET[h * 16 + tp2] = k2 * d;
      GAM[h * 16 + tp2] = k2 * g;
    }
#pragma unroll
    for (int q = 0; q < 4; ++q) {
      int idx = tid + 256 * q;   // 1024 items: [h][tq][t']
      int h = idx >> 8, ta = (idx >> 4) & 15, tb = idx & 15;
      float d = 0.f;
#pragma unroll
      for (int i = 0; i < 16; ++i)
        d = fmaf(sB[ta][h * 16 + i], sB[tb][64 + h * 16 + i], d);   // Bq[ta].Bk[tb]
      DELT[h * 256 + ta * 16 + tb] = k2 * d;
    }
  } else {
    // t == 18: per-(b,t') min/max of x_seq
    int g = tid >> 3, i = tid & 7;           // g = b*16 + t'
    const float* xp = x_seq + (g >> 4) * S_ + (g & 15) * N_;
    float mn = 1e30f, mx = -1e30f;
    for (int j = i; j < 256; j += 8) {
      float v = xp[j];
      mn = fminf(mn, v); mx = fmaxf(mx, v);
    }
#pragma unroll
    for (int off = 1; off < 8; off <<= 1) {
      mn = fminf(mn, __shfl_xor(mn, off, 64));
      mx = fmaxf(mx, __shfl_xor(mx, off, 64));
    }
    if (i == 0) { MN[g] = mn; MX[g] = mx; }
  }
}

// -------- layer-0 attention partials via rank-1 algebra --------------------
__global__ __launch_bounds__(256, 4) void k_attn0(
    const float* __restrict__ x_seq,
    const float* __restrict__ ALPH, const float* __restrict__ BET,
    const float* __restrict__ GAM, const float* __restrict__ DELT,
    const float* __restrict__ MN, const float* __restrict__ MX,
    float* __restrict__ P0) {
  __shared__ float4 xk4[64];
  int blk = blockIdx.x;
  int bh = blk / PAIRS, pair = blk % PAIRS;
  int b = bh >> 2, h = bh & 3;
  int tq = 0, p = pair;
  while (p >= tq + 1) { p -= tq + 1; ++tq; }
  int kt = p;
  int tid = threadIdx.x;
  if (tid < 64) xk4[tid] = *(const float4*)(x_seq + (size_t)(b * S_ + kt * N_) + 4 * tid);
  __syncthreads();

  float x = x_seq[b * S_ + tq * N_ + tid];
  float a = fmaf(ALPH[h], x, GAM[h * 16 + tq]);
  float xext = (a >= 0.f) ? MX[b * 16 + kt] : MN[b * 16 + kt];
  float axext = a * xext;
  float Mg = axext + fmaf(BET[h * 16 + kt], x, DELT[h * 256 + tq * 16 + kt]);
  float sp0 = 0.f, sp1 = 0.f, sp2 = 0.f, sp3 = 0.f;
  float sx0 = 0.f, sx1 = 0.f, sx2 = 0.f, sx3 = 0.f;
#pragma unroll 8
  for (int j = 0; j < 64; ++j) {
    float4 xv = xk4[j];
    float e0 = __builtin_amdgcn_exp2f(fmaf(a, xv.x, -axext));
    float e1 = __builtin_amdgcn_exp2f(fmaf(a, xv.y, -axext));
    float e2 = __builtin_amdgcn_exp2f(fmaf(a, xv.z, -axext));
    float e3 = __builtin_amdgcn_exp2f(fmaf(a, xv.w, -axext));
    sp0 += e0; sp1 += e1; sp2 += e2; sp3 += e3;
    sx0 = fmaf(xv.x, e0, sx0); sx1 = fmaf(xv.y, e1, sx1);
    sx2 = fmaf(xv.z, e2, sx2); sx3 = fmaf(xv.w, e3, sx3);
  }
  size_t pb = ((size_t)(bh * 16 + tq) * 16 + kt) * 768;
  P0[pb + tid]       = Mg;
  P0[pb + 256 + tid] = (sp0 + sp1) + (sp2 + sp3);
  P0[pb + 512 + tid] = (sx0 + sx1) + (sx2 + sx3);
}

// -------- fused0: combine + proj + LN1 + FFN + LN2 + qkv(layer1) -----------
// block = 8 rows sharing (b,t); 1024 blocks -> 4 resident blocks/CU.
__global__ __launch_bounds__(256, 4) void k_fused0(
    const float* __restrict__ P0, const float* __restrict__ A,
    const float* __restrict__ Bt, const float* __restrict__ Xb,
    const float* __restrict__ x_seq, const float* __restrict__ Wi,
    const float* __restrict__ Wo, const float* __restrict__ bo,
    const float* __restrict__ g1, const float* __restrict__ be1,
    const float* __restrict__ W1, const float* __restrict__ bb1,
    const float* __restrict__ W2, const float* __restrict__ bb2,
    const float* __restrict__ g2, const float* __restrict__ be2,
    const float* __restrict__ Wq1, const float* __restrict__ bq1,
    float* __restrict__ X, float* __restrict__ QKV) {
  __shared__ float os[8][64], rs[8][64], xs[8][64], x2[8][64], hs[8][256];
  int tid = threadIdx.x;
  int row0 = blockIdx.x * 8;
  int b = row0 >> 12, t = (row0 >> 8) & 15, n0 = row0 & 255;

  // ---- phase A: attention combine -> os (normalized) ----
  {
    int r = tid & 7, h = (tid >> 3) & 3, d2 = tid >> 5;   // d2 = 0..7 (2 d each)
    int n = n0 + r, bh = b * 4 + h;
    float M = -INFINITY, D = 0.f, SX = 0.f, bacc0 = 0.f, bacc1 = 0.f;
    for (int kt = 0; kt <= t; ++kt) {
      size_t pb = ((size_t)(bh * 16 + t) * 16 + kt) * 768 + n;
      float mg = P0[pb], sp = P0[pb + 256], sx = P0[pb + 512];
      float mnv = fmaxf(M, mg);
      float sc = __builtin_amdgcn_exp2f(M - mnv);   // first iter: exp2(-inf)=0
      float w  = __builtin_amdgcn_exp2f(mg - mnv);
      float wsp = w * sp;
      D  = fmaf(w, sp, D * sc);
      SX = fmaf(w, sx, SX * sc);
      float2 bv = *(const float2*)(Bt + kt * 192 + 128 + h * 16 + d2 * 2);
      bacc0 = fmaf(wsp, bv.x, bacc0 * sc);
      bacc1 = fmaf(wsp, bv.y, bacc1 * sc);
      M = mnv;
    }
    float invD = 1.f / D;
    float2 av = *(const float2*)(A + 128 + h * 16 + d2 * 2);
    os[r][h * 16 + d2 * 2 + 0] = fmaf(SX, av.x, bacc0) * invD;
    os[r][h * 16 + d2 * 2 + 1] = fmaf(SX, av.y, bacc1) * invD;
  }
  // ---- phase A2: residual (rank-1 X0) ----
  {
    int idx = tid;                    // 8*64 = 512 = 2*256
#pragma unroll
    for (int i = 0; i < 2; ++i, idx += 256) {
      int r = idx >> 6, cc = idx & 63;
      rs[r][cc] = fmaf(x_seq[row0 + r], Wi[cc], Xb[t * 64 + cc]);
    }
  }
  __syncthreads();

  int c = tid & 63, grp = tid >> 6;
  // ---- phase B: proj + LN1 (wave grp: rows grp, grp+4) ----
#pragma unroll
  for (int rr = 0; rr < 2; ++rr) {
    int r = grp + 4 * rr;
    float a = bo[c];
#pragma unroll 8
    for (int k = 0; k < 64; ++k) a = fmaf(os[r][k], Wo[k * 64 + c], a);
    float val = a + rs[r][c];
    float mean = wave_sum(val) * (1.f / 64.f);
    float dv = val - mean;
    float var = wave_sum(dv * dv) * (1.f / 64.f);
    xs[r][c] = dv * rsqrtf(var + 1e-5f) * g1[c] + be1[c];
  }
  __syncthreads();

  // ---- phase C: FFN1 64->256 relu ----
  {
    float am[8];
#pragma unroll
    for (int i = 0; i < 8; ++i) am[i] = bb1[tid];
    for (int k4 = 0; k4 < 16; ++k4) {
      float w0 = W1[(4 * k4 + 0) * 256 + tid];
      float w1v = W1[(4 * k4 + 1) * 256 + tid];
      float w2v = W1[(4 * k4 + 2) * 256 + tid];
      float w3v = W1[(4 * k4 + 3) * 256 + tid];
#pragma unroll
      for (int r = 0; r < 8; ++r) {
        float4 xv = *(const float4*)&xs[r][4 * k4];
        am[r] = fmaf(xv.x, w0, am[r]);
        am[r] = fmaf(xv.y, w1v, am[r]);
        am[r] = fmaf(xv.z, w2v, am[r]);
        am[r] = fmaf(xv.w, w3v, am[r]);
      }
    }
#pragma unroll
    for (int r = 0; r < 8; ++r) hs[r][tid] = fmaxf(am[r], 0.f);
  }
  __syncthreads();

  // ---- phase D: FFN2 256->64 + resid + LN2 ----
  {
    float a0 = bb2[c], a1 = bb2[c];
    for (int k4 = 0; k4 < 64; ++k4) {
      float w0 = W2[(4 * k4 + 0) * 64 + c];
      float w1v = W2[(4 * k4 + 1) * 64 + c];
      float w2v = W2[(4 * k4 + 2) * 64 + c];
      float w3v = W2[(4 * k4 + 3) * 64 + c];
      float4 h0 = *(const float4*)&hs[grp][4 * k4];
      float4 h1 = *(const float4*)&hs[grp + 4][4 * k4];
      a0 = fmaf(h0.x, w0, a0); a0 = fmaf(h0.y, w1v, a0);
      a0 = fmaf(h0.z, w2v, a0); a0 = fmaf(h0.w, w3v, a0);
      a1 = fmaf(h1.x, w0, a1); a1 = fmaf(h1.y, w1v, a1);
      a1 = fmaf(h1.z, w2v, a1); a1 = fmaf(h1.w, w3v, a1);
    }
    float av[2] = {a0, a1};
#pragma unroll
    for (int rr = 0; rr < 2; ++rr) {
      int r = grp + 4 * rr;
      float val = av[rr] + xs[r][c];
      float mean = wave_sum(val) * (1.f / 64.f);
      float dv = val - mean;
      float var = wave_sum(dv * dv) * (1.f / 64.f);
      float xn = dv * rsqrtf(var + 1e-5f) * g2[c] + be2[c];
      x2[r][c] = xn;
      if (t == 15) X[(size_t)(row0 + r) * 64 + c] = xn;
    }
  }
  __syncthreads();

  // ---- phase E: qkv for layer 1 (K,V always; Q only for t=15 rows) ----
  {
    int ncol = (t == 15) ? 192 : 128;
    int cb = (t == 15) ? 0 : 64;
    if (tid < ncol) {
      int col = cb + tid;
      float acc[8];
#pragma unroll
      for (int r = 0; r < 8; ++r) acc[r] = bq1[col];
      for (int k4 = 0; k4 < 16; ++k4) {
        float w0 = Wq1[(4 * k4 + 0) * 192 + col];
        float w1v = Wq1[(4 * k4 + 1) * 192 + col];
        float w2v = Wq1[(4 * k4 + 2) * 192 + col];
        float w3v = Wq1[(4 * k4 + 3) * 192 + col];
#pragma unroll
        for (int r = 0; r < 8; ++r) {
          float4 xv = *(const float4*)&x2[r][4 * k4];
          acc[r] = fmaf(xv.x, w0, acc[r]);
          acc[r] = fmaf(xv.y, w1v, acc[r]);
          acc[r] = fmaf(xv.z, w2v, acc[r]);
          acc[r] = fmaf(xv.w, w3v, acc[r]);
        }
      }
#pragma unroll
      for (int r = 0; r < 8; ++r)
        QKV[(size_t)(row0 + r) * 192 + col] = acc[r];
    }
  }
}

// -------- layer-1 MFMA flash attention (tq=15 only), round-4-verified body -
__global__ __launch_bounds__(256, 4) void k_attn1(const float* __restrict__ QKV,
    float* __restrict__ PM, float* __restrict__ PL, float* __restrict__ PACC) {
  __shared__ short KH[2][256][8];
  __shared__ short KL[2][256][8];
  __shared__ short VT[32][264];
  int blk = blockIdx.x;
  int bh = blk >> 4, kt = blk & 15;
  const int tq = 15;
  int b = bh >> 2, h = bh & 3;
  int tid = threadIdx.x, w = tid >> 6, lane = tid & 63;
  int l31 = lane & 31, hi = lane >> 5;
  const size_t qkvbase = (size_t)b * S_ * 192;

  for (int i = tid; i < 16 * 264; i += 256) (&VT[16][0])[i] = 0;
  {
    const float* kp = QKV + qkvbase + (size_t)(kt * N_ + tid) * 192 + 64 + h * 16;
    float kf[16], vf[16];
#pragma unroll
    for (int i = 0; i < 4; ++i) {
      float4 k4 = *(const float4*)(kp + 4 * i);
      kf[4 * i] = k4.x; kf[4 * i + 1] = k4.y; kf[4 * i + 2] = k4.z; kf[4 * i + 3] = k4.w;
      float4 v4 = *(const float4*)(kp + 64 + 4 * i);
      vf[4 * i] = v4.x; vf[4 * i + 1] = v4.y; vf[4 * i + 2] = v4.z; vf[4 * i + 3] = v4.w;
    }
    short8 kh0, kh1, kl0, kl1;
#pragma unroll
    for (int i = 0; i < 8; ++i) {
      unsigned ht0 = __float_as_uint(kf[i]) & 0xFFFF0000u;
      kh0[i] = (short)(ht0 >> 16);
      kl0[i] = (short)bf16_rne(kf[i] - __uint_as_float(ht0));
      unsigned ht1 = __float_as_uint(kf[i + 8]) & 0xFFFF0000u;
      kh1[i] = (short)(ht1 >> 16);
      kl1[i] = (short)bf16_rne(kf[i + 8] - __uint_as_float(ht1));
    }
    *(short8*)&KH[0][tid][0] = kh0;
    *(short8*)&KH[1][tid][0] = kh1;
    *(short8*)&KL[0][tid][0] = kl0;
    *(short8*)&KL[1][tid][0] = kl1;
#pragma unroll
    for (int i = 0; i < 16; ++i) VT[i][tid] = (short)bf16_rne(vf[i]);
  }
  __syncthreads();

  const float cscale = 0.36067376022224085f;
  short8 Qh[2], Ql[2];
#pragma unroll
  for (int qs = 0; qs < 2; ++qs) {
    int qloc = w * 64 + qs * 32 + l31;
    const float* qp = QKV + qkvbase + (size_t)(tq * N_ + qloc) * 192 + h * 16 + 8 * hi;
    float4 a4 = *(const float4*)(qp), b4 = *(const float4*)(qp + 4);
    float qf[8] = {a4.x, a4.y, a4.z, a4.w, b4.x, b4.y, b4.z, b4.w};
#pragma unroll
    for (int i = 0; i < 8; ++i) {
      float q = qf[i] * cscale;
      unsigned ht = __float_as_uint(q) & 0xFFFF0000u;
      Qh[qs][i] = (short)(ht >> 16);
      Ql[qs][i] = (short)bf16_rne(q - __uint_as_float(ht));
    }
  }

  f32x16 O0 = zero16(), O1 = zero16();
  float m[2] = {-INFINITY, -INFINITY}, lsum[2] = {0.f, 0.f};

  for (int ks = 0; ks < 8; ++ks) {
    const short8 Kh = *(const short8*)&KH[hi][ks * 32 + l31][0];
    const short8 Kl = *(const short8*)&KL[hi][ks * 32 + l31][0];
    const short8 Va = *(const short8*)&VT[l31][ks * 32 + 8 * hi];
    const short8 Vb = *(const short8*)&VT[l31][ks * 32 + 8 * hi + 16];

#pragma unroll
    for (int qs = 0; qs < 2; ++qs) {
      f32x16 S = zero16();
      S = __builtin_amdgcn_mfma_f32_32x32x16_bf16(Kh, Qh[qs], S, 0, 0, 0);
      S = __builtin_amdgcn_mfma_f32_32x32x16_bf16(Kl, Qh[qs], S, 0, 0, 0);
      S = __builtin_amdgcn_mfma_f32_32x32x16_bf16(Kh, Ql[qs], S, 0, 0, 0);

      float pm = S[0];
#pragma unroll
      for (int r = 1; r < 16; ++r) pm = fmaxf(pm, S[r]);
      pm = fmaxf(pm, __shfl_xor(pm, 32, 64));
      float mq = m[qs];
      if (__any(pm > mq)) {
        float mn = fmaxf(mq, pm);
        float al = __builtin_amdgcn_exp2f(mq - mn);
        m[qs] = mn; mq = mn;
        lsum[qs] *= al;
        if (qs == 0) {
#pragma unroll
          for (int r = 0; r < 16; ++r) O0[r] *= al;
        } else {
#pragma unroll
          for (int r = 0; r < 16; ++r) O1[r] *= al;
        }
      }
      float pr[16], ps = 0.f;
#pragma unroll
      for (int r = 0; r < 16; ++r) {
        pr[r] = __builtin_amdgcn_exp2f(S[r] - mq);
        ps += pr[r];
      }
      lsum[qs] += ps + __shfl_xor(ps, 32, 64);

      unsigned w01 = pack2(pr[0],  pr[1]);
      unsigned w23 = pack2(pr[2],  pr[3]);
      unsigned w45 = pack2(pr[4],  pr[5]);
      unsigned w67 = pack2(pr[6],  pr[7]);
      unsigned w89 = pack2(pr[8],  pr[9]);
      unsigned wab = pack2(pr[10], pr[11]);
      unsigned wcd = pack2(pr[12], pr[13]);
      unsigned wef = pack2(pr[14], pr[15]);
      unsigned e01 = __shfl_xor(w01, 32, 64), e23 = __shfl_xor(w23, 32, 64);
      unsigned e45 = __shfl_xor(w45, 32, 64), e67 = __shfl_xor(w67, 32, 64);
      unsigned e89 = __shfl_xor(w89, 32, 64), eab = __shfl_xor(wab, 32, 64);
      unsigned ecd = __shfl_xor(wcd, 32, 64), eef = __shfl_xor(wef, 32, 64);
      union { short8 s; unsigned u[4]; } P0u, P1u;
      P0u.u[0] = hi ? e45 : w01;
      P0u.u[1] = hi ? e67 : w23;
      P0u.u[2] = hi ? w45 : e01;
      P0u.u[3] = hi ? w67 : e23;
      P1u.u[0] = hi ? ecd : w89;
      P1u.u[1] = hi ? eef : wab;
      P1u.u[2] = hi ? wcd : e89;
      P1u.u[3] = hi ? wef : eab;

      if (qs == 0) {
        O0 = __builtin_amdgcn_mfma_f32_32x32x16_bf16(Va, P0u.s, O0, 0, 0, 0);
        O0 = __builtin_amdgcn_mfma_f32_32x32x16_bf16(Vb, P1u.s, O0, 0, 0, 0);
      } else {
        O1 = __builtin_amdgcn_mfma_f32_32x32x16_bf16(Va, P0u.s, O1, 0, 0, 0);
        O1 = __builtin_amdgcn_mfma_f32_32x32x16_bf16(Vb, P1u.s, O1, 0, 0, 0);
      }
    }
  }

  int slot = blk;
#pragma unroll
  for (int qs = 0; qs < 2; ++qs) {
    int qloc = w * 64 + qs * 32 + l31;
    if (lane < 32) {
      PM[(size_t)slot * 256 + qloc] = m[qs];
      PL[(size_t)slot * 256 + qloc] = lsum[qs];
    }
#pragma unroll
    for (int r = 0; r < 8; ++r) {
      int d = (r & 3) + 8 * (r >> 2) + 4 * hi;
      float val = (qs == 0) ? O0[r] : O1[r];
      PACC[((size_t)slot * 16 + d) * 256 + qloc] = val;
    }
  }
}

// -------- fused1: combine + proj + LN1 + FFN + LN2 + head ------------------
// 2 rows x 128 threads x 256 blocks (one block per CU).
__global__ __launch_bounds__(128, 2) void k_fused1(
    const float* __restrict__ PM1, const float* __restrict__ PL1,
    const float* __restrict__ PA1,
    const float* __restrict__ Wo, const float* __restrict__ bo,
    const float* __restrict__ g1, const float* __restrict__ be1,
    const float* __restrict__ W1, const float* __restrict__ bb1,
    const float* __restrict__ W2, const float* __restrict__ bb2,
    const float* __restrict__ g2, const float* __restrict__ be2,
    const float* __restrict__ X,
    const float* __restrict__ dW1, const float* __restrict__ db1,
    const float* __restrict__ dW2, const float* __restrict__ db2,
    const float* __restrict__ dW3, const float* __restrict__ db3,
    float* __restrict__ out) {
  __shared__ float os[2][64], rs[2][64], xs[2][64], x2[2][64], hs[2][256];
  __shared__ float h1s[2][32], h2s[2][16];
  int tid = threadIdx.x;
  int bb = blockIdx.x >> 7;                 // batch
  int nbase = (blockIdx.x & 127) * 2;       // first of 2 node rows
  int row0 = bb * S_ + 15 * N_ + nbase;
  size_t base = (size_t)row0 * 64;

  // phase A: combine MFMA partials -> os ; load residual rows -> rs
  {
    int d = tid & 15, h = (tid >> 4) & 3, r = tid >> 6;   // 16*4*2 = 128
    int n = nbase + r;
    int sb = (bb * 4 + h) * 16;
    float M = -INFINITY;
#pragma unroll
    for (int s = 0; s < 16; ++s) M = fmaxf(M, PM1[(size_t)(sb + s) * 256 + n]);
    float D = 0.f, od = 0.f;
#pragma unroll
    for (int s = 0; s < 16; ++s) {
      float wgt = __builtin_amdgcn_exp2f(PM1[(size_t)(sb + s) * 256 + n] - M);
      D = fmaf(PL1[(size_t)(sb + s) * 256 + n], wgt, D);
      od = fmaf(PA1[((size_t)(sb + s) * 16 + d) * 256 + n], wgt, od);
    }
    os[r][h * 16 + d] = od / D;
    rs[tid >> 6][tid & 63] = X[base + tid];
  }
  __syncthreads();

  int c = tid & 63, grp = tid >> 6;   // grp = row (0/1)
  // proj + LN1
  {
    float a = bo[c];
#pragma unroll 8
    for (int k = 0; k < 64; ++k) a = fmaf(os[grp][k], Wo[k * 64 + c], a);
    float val = a + rs[grp][c];
    float mean = wave_sum(val) * (1.f / 64.f);
    float dv = val - mean;
    float var = wave_sum(dv * dv) * (1.f / 64.f);
    xs[grp][c] = dv * rsqrtf(var + 1e-5f) * g1[c] + be1[c];
  }
  __syncthreads();

  // FFN1: each thread 2 mids x 2 rows
  {
    float am00 = bb1[tid], am01 = bb1[tid];
    float am10 = bb1[tid + 128], am11 = bb1[tid + 128];
#pragma unroll 8
    for (int k = 0; k < 64; ++k) {
      float wA = W1[k * 256 + tid];
      float wB = W1[k * 256 + tid + 128];
      float x0 = xs[0][k], x1 = xs[1][k];
      am00 = fmaf(x0, wA, am00); am01 = fmaf(x1, wA, am01);
      am10 = fmaf(x0, wB, am10); am11 = fmaf(x1, wB, am11);
    }
    hs[0][tid] = fmaxf(am00, 0.f);
    hs[1][tid] = fmaxf(am01, 0.f);
    hs[0][tid + 128] = fmaxf(am10, 0.f);
    hs[1][tid + 128] = fmaxf(am11, 0.f);
  }
  __syncthreads();

  // FFN2 + resid + LN2
  {
    float a = bb2[c];
#pragma unroll 4
    for (int k = 0; k < 256; ++k) a = fmaf(hs[grp][k], W2[k * 64 + c], a);
    float val = a + xs[grp][c];
    float mean = wave_sum(val) * (1.f / 64.f);
    float dv = val - mean;
    float var = wave_sum(dv * dv) * (1.f / 64.f);
    x2[grp][c] = dv * rsqrtf(var + 1e-5f) * g2[c] + be2[c];
  }
  __syncthreads();

  // head: 64 -> 32 -> 16 -> 1
  if (tid < 64) {
    int r = tid >> 5, mid = tid & 31;
    float a = db1[mid];
#pragma unroll 8
    for (int k = 0; k < 64; ++k) a = fmaf(x2[r][k], dW1[k * 32 + mid], a);
    h1s[r][mid] = fmaxf(a, 0.f);
  }
  __syncthreads();
  if (tid < 32) {
    int r = tid >> 4, low = tid & 15;
    float a = db2[low];
#pragma unroll
    for (int k = 0; k < 32; ++k) a = fmaf(h1s[r][k], dW2[k * 16 + low], a);
    h2s[r][low] = fmaxf(a, 0.f);
  }
  __syncthreads();
  if (tid < 2) {
    float a = db3[0];
#pragma unroll
    for (int k = 0; k < 16; ++k) a = fmaf(h2s[tid][k], dW3[k], a);
    out[bb * 256 + nbase + tid] = a;
  }
}

}  // namespace

extern "C" void kernel_launch(void* const* d_in, const int* in_sizes, int n_in,
                              void* d_out, int out_size, void* d_ws, size_t ws_size,
                              hipStream_t stream) {
  const float* x_seq = (const float*)d_in[0];
  // d_in[1] = edge_index (unused by reference)
  const float* Wi   = (const float*)d_in[2];
  const float* bi   = (const float*)d_in[3];
  const float* Wqkv = (const float*)d_in[4];
  const float* bqkv = (const float*)d_in[5];
  const float* Wo   = (const float*)d_in[6];
  const float* bo   = (const float*)d_in[7];
  const float* ln1g = (const float*)d_in[8];
  const float* ln1b = (const float*)d_in[9];
  const float* W1   = (const float*)d_in[10];
  const float* b1   = (const float*)d_in[11];
  const float* W2   = (const float*)d_in[12];
  const float* b2   = (const float*)d_in[13];
  const float* ln2g = (const float*)d_in[14];
  const float* ln2b = (const float*)d_in[15];
  const float* dW1  = (const float*)d_in[16];
  const float* db1  = (const float*)d_in[17];
  const float* dW2  = (const float*)d_in[18];
  const float* db2  = (const float*)d_in[19];
  const float* dW3  = (const float*)d_in[20];
  const float* db3  = (const float*)d_in[21];

  float* ws   = (float*)d_ws;  // needs >= 17.1 MB
  float* A    = ws + OFF_A;
  float* Bt   = ws + OFF_BT;
  float* Xb   = ws + OFF_XB;
  float* ALPH = ws + OFF_ALPH;
  float* BET  = ws + OFF_BET;
  float* GAM  = ws + OFF_GAM;
  float* DELT = ws + OFF_DELT;
  float* MN   = ws + OFF_MN;
  float* MX   = ws + OFF_MX;
  float* X    = ws + OFF_X;
  float* QKV  = ws + OFF_QKV;
  float* P0   = ws + OFF_P0;
  float* PM1  = ws + OFF_PM1;
  float* PL1  = ws + OFF_PL1;
  float* PA1  = ws + OFF_PA1;

  k_setup<<<19, 256, 0, stream>>>(x_seq, Wi, bi, Wqkv, bqkv, A, Bt, Xb,
                                  ALPH, BET, GAM, DELT, MN, MX);
  k_attn0<<<8 * PAIRS, 256, 0, stream>>>(x_seq, ALPH, BET, GAM, DELT, MN, MX, P0);
  k_fused0<<<1024, 256, 0, stream>>>(P0, A, Bt, Xb, x_seq, Wi,
                                     Wo, bo, ln1g, ln1b, W1, b1, W2, b2,
                                     ln2g, ln2b, Wqkv + 64 * 192, bqkv + 192,
                                     X, QKV);
  k_attn1<<<128, 256, 0, stream>>>(QKV, PM1, PL1, PA1);
  k_fused1<<<256, 128, 0, stream>>>(PM1, PL1, PA1,
                                    Wo + 4096, bo + 64, ln1g + 64, ln1b + 64,
                                    W1 + 64 * 256, b1 + 256, W2 + 256 * 64, b2 + 64,
                                    ln2g + 64, ln2b + 64, X,
                                    dW1, db1, dW2, db2, dW3, db3, (float*)d_out);
}

// Round 8
// 88.774 us; speedup vs baseline: 5.4710x; 1.2111x over previous
//
#include <hip/hip_runtime.h>
#include <math.h>

// GlobalTransformer: B=2, T=16, N=256 (S=4096), H=64, NHEAD=4, dh=16, L=2
// Round 8: PA1 stored [slot][n][d] (one 64B line per (slot,n)) so fused1's
// combine is fully coalesced; fused1 = 128 blocks x 256 thr x 4 rows.
// Rest identical to round 7. 5 dispatches.

namespace {
constexpr int T_ = 16, N_ = 256, S_ = 4096;
constexpr int PAIRS = 136;   // valid (tq,kt) pairs per bh (layer 0)

// ws float offsets (total 4,265,472 floats = 17.1 MB)
constexpr size_t OFF_A    = 0;        // [192]   Wi@Wqkv0
constexpr size_t OFF_BT   = 192;      // [16][192] (bi+tp)@Wqkv0 + bqkv0
constexpr size_t OFF_XB   = 3264;     // [16][64]  bi+tp
constexpr size_t OFF_ALPH = 4288;     // [4]       k2*Aq.Ak
constexpr size_t OFF_BET  = 4292;     // [4][16]   k2*Aq.Bk[t']
constexpr size_t OFF_GAM  = 4356;     // [4][16]   k2*Ak.Bq[t]
constexpr size_t OFF_DELT = 4420;     // [4][16][16] k2*Bq[t].Bk[t']
constexpr size_t OFF_MN   = 5444;     // [2][16] min_n x_seq
constexpr size_t OFF_MX   = 5476;     // [2][16] max_n x_seq
constexpr size_t OFF_X    = 5632;     // [B*S][64] (only t=15 rows written)
constexpr size_t OFF_QKV  = 529920;   // [B*S][192] (layer 1; Q cols only t=15)
constexpr size_t OFF_P0   = 2102784;  // [8][16][16][3][256] layer-0 partials
constexpr size_t OFF_PM1  = 3675648;  // [128][256]
constexpr size_t OFF_PL1  = 3708416;  // [128][256]
constexpr size_t OFF_PA1  = 3741184;  // [128][256][16]  (d contiguous!)

typedef float  f32x16 __attribute__((ext_vector_type(16)));
typedef short  short8 __attribute__((ext_vector_type(8)));

__device__ inline float wave_sum(float v) {
#pragma unroll
  for (int off = 32; off > 0; off >>= 1) v += __shfl_xor(v, off, 64);
  return v;
}
__device__ inline unsigned bf16_rne(float f) {
  unsigned u = __float_as_uint(f);
  return (u + 0x7FFFu + ((u >> 16) & 1u)) >> 16;
}
__device__ inline unsigned pack2(float a, float b) {   // low<-a, high<-b
  return bf16_rne(a) | (bf16_rne(b) << 16);
}
__device__ inline f32x16 zero16() {
  f32x16 z;
#pragma unroll
  for (int i = 0; i < 16; ++i) z[i] = 0.f;
  return z;
}
__device__ inline float pe_val(int t, int h) {
  float div = __expf((float)(h & ~1) * (-0.14391156831212787f));  // -ln(1e4)/64
  float arg = (float)t * div;
  return (h & 1) ? cosf(arg) : sinf(arg);
}

// -------- setup: blocks 0..15 Bt/Xb, 16 A, 17 score tables, 18 mn/mx ------
__global__ void k_setup(const float* __restrict__ x_seq,
                        const float* __restrict__ Wi, const float* __restrict__ bi,
                        const float* __restrict__ Wqkv, const float* __restrict__ bqkv,
                        float* __restrict__ A, float* __restrict__ Bt,
                        float* __restrict__ Xb,
                        float* __restrict__ ALPH, float* __restrict__ BET,
                        float* __restrict__ GAM, float* __restrict__ DELT,
                        float* __restrict__ MN, float* __restrict__ MX) {
  int t = blockIdx.x, tid = threadIdx.x;
  if (t < 16) {
    if (tid < 192) {
      float acc = bqkv[tid];
#pragma unroll 8
      for (int h = 0; h < 64; ++h)
        acc = fmaf(bi[h] + pe_val(t, h), Wqkv[h * 192 + tid], acc);
      Bt[t * 192 + tid] = acc;
    }
    if (tid < 64) Xb[t * 64 + tid] = bi[tid] + pe_val(t, tid);
  } else if (t == 16) {
    if (tid < 192) {
      float acc = 0.f;
#pragma unroll 8
      for (int h = 0; h < 64; ++h) acc = fmaf(Wi[h], Wqkv[h * 192 + tid], acc);
      A[tid] = acc;
    }
  } else if (t == 17) {
    __shared__ float sA[128];       // Aq|Ak
    __shared__ float sB[16][128];   // Bq|Bk per timestep
    if (tid < 128) {
      float acc = 0.f;
#pragma unroll 8
      for (int h = 0; h < 64; ++h) acc = fmaf(Wi[h], Wqkv[h * 192 + tid], acc);
      sA[tid] = acc;
    }
    {
      int tt = tid >> 4, i = tid & 15;
      float accv[8];
#pragma unroll
      for (int j = 0; j < 8; ++j) accv[j] = bqkv[i * 8 + j];
      for (int h = 0; h < 64; ++h) {
        float xb = bi[h] + pe_val(tt, h);
#pragma unroll
        for (int j = 0; j < 8; ++j)
          accv[j] = fmaf(xb, Wqkv[h * 192 + i * 8 + j], accv[j]);
      }
#pragma unroll
      for (int j = 0; j < 8; ++j) sB[tt][i * 8 + j] = accv[j];
    }
    __syncthreads();
    const float k2 = 0.36067376022224085f;  // (1/sqrt(16)) * log2(e)
    if (tid < 4) {
      float d = 0.f;
#pragma unroll
      for (int i = 0; i < 16; ++i) d = fmaf(sA[tid * 16 + i], sA[64 + tid * 16 + i], d);
      ALPH[tid] = k2 * d;
    }
    if (tid < 64) {
      int h = tid >> 4, tp2 = tid & 15;
      float d = 0.f, g = 0.f;
#pragma unroll
      for (int i = 0; i < 16; ++i) {
        d = fmaf(sA[h * 16 + i], sB[tp2][64 + h * 16 + i], d);      // Aq.Bk[t']
        g = fmaf(sA[64 + h * 16 + i], sB[tp2][h * 16 + i], g);      // Ak.Bq[t]
      }
      BET[h * 16 + tp2] = k2 * d;
      GAM[h * 16 + tp2] = k2 * g;
    }
#pragma unroll
    for (int q = 0; q < 4; ++q) {
      int idx = tid + 256 * q;   // 1024 items: [h][tq][t']
      int h = idx >> 8, ta = (idx >> 4) & 15, tb = idx & 15;
      float d = 0.f;
#pragma unroll
      for (int i = 0; i < 16; ++i)
        d = fmaf(sB[ta][h * 16 + i], sB[tb][64 + h * 16 + i], d);   // Bq[ta].Bk[tb]
      DELT[h * 256 + ta * 16 + tb] = k2 * d;
    }
  } else {
    // t == 18: per-(b,t') min/max of x_seq
    int g = tid >> 3, i = tid & 7;           // g = b*16 + t'
    const float* xp = x_seq + (g >> 4) * S_ + (g & 15) * N_;
    float mn = 1e30f, mx = -1e30f;
    for (int j = i; j < 256; j += 8) {
      float v = xp[j];
      mn = fminf(mn, v); mx = fmaxf(mx, v);
    }
#pragma unroll
    for (int off = 1; off < 8; off <<= 1) {
      mn = fminf(mn, __shfl_xor(mn, off, 64));
      mx = fmaxf(mx, __shfl_xor(mx, off, 64));
    }
    if (i == 0) { MN[g] = mn; MX[g] = mx; }
  }
}

// -------- layer-0 attention partials via rank-1 algebra --------------------
__global__ __launch_bounds__(256, 4) void k_attn0(
    const float* __restrict__ x_seq,
    const float* __restrict__ ALPH, const float* __restrict__ BET,
    const float* __restrict__ GAM, const float* __restrict__ DELT,
    const float* __restrict__ MN, const float* __restrict__ MX,
    float* __restrict__ P0) {
  __shared__ float4 xk4[64];
  int blk = blockIdx.x;
  int bh = blk / PAIRS, pair = blk % PAIRS;
  int b = bh >> 2, h = bh & 3;
  int tq = 0, p = pair;
  while (p >= tq + 1) { p -= tq + 1; ++tq; }
  int kt = p;
  int tid = threadIdx.x;
  if (tid < 64) xk4[tid] = *(const float4*)(x_seq + (size_t)(b * S_ + kt * N_) + 4 * tid);
  __syncthreads();

  float x = x_seq[b * S_ + tq * N_ + tid];
  float a = fmaf(ALPH[h], x, GAM[h * 16 + tq]);
  float xext = (a >= 0.f) ? MX[b * 16 + kt] : MN[b * 16 + kt];
  float axext = a * xext;
  float Mg = axext + fmaf(BET[h * 16 + kt], x, DELT[h * 256 + tq * 16 + kt]);
  float sp0 = 0.f, sp1 = 0.f, sp2 = 0.f, sp3 = 0.f;
  float sx0 = 0.f, sx1 = 0.f, sx2 = 0.f, sx3 = 0.f;
#pragma unroll 8
  for (int j = 0; j < 64; ++j) {
    float4 xv = xk4[j];
    float e0 = __builtin_amdgcn_exp2f(fmaf(a, xv.x, -axext));
    float e1 = __builtin_amdgcn_exp2f(fmaf(a, xv.y, -axext));
    float e2 = __builtin_amdgcn_exp2f(fmaf(a, xv.z, -axext));
    float e3 = __builtin_amdgcn_exp2f(fmaf(a, xv.w, -axext));
    sp0 += e0; sp1 += e1; sp2 += e2; sp3 += e3;
    sx0 = fmaf(xv.x, e0, sx0); sx1 = fmaf(xv.y, e1, sx1);
    sx2 = fmaf(xv.z, e2, sx2); sx3 = fmaf(xv.w, e3, sx3);
  }
  size_t pb = ((size_t)(bh * 16 + tq) * 16 + kt) * 768;
  P0[pb + tid]       = Mg;
  P0[pb + 256 + tid] = (sp0 + sp1) + (sp2 + sp3);
  P0[pb + 512 + tid] = (sx0 + sx1) + (sx2 + sx3);
}

// -------- fused0: combine + proj + LN1 + FFN + LN2 + qkv(layer1) -----------
// block = 8 rows sharing (b,t); 1024 blocks -> 4 resident blocks/CU.
__global__ __launch_bounds__(256, 4) void k_fused0(
    const float* __restrict__ P0, const float* __restrict__ A,
    const float* __restrict__ Bt, const float* __restrict__ Xb,
    const float* __restrict__ x_seq, const float* __restrict__ Wi,
    const float* __restrict__ Wo, const float* __restrict__ bo,
    const float* __restrict__ g1, const float* __restrict__ be1,
    const float* __restrict__ W1, const float* __restrict__ bb1,
    const float* __restrict__ W2, const float* __restrict__ bb2,
    const float* __restrict__ g2, const float* __restrict__ be2,
    const float* __restrict__ Wq1, const float* __restrict__ bq1,
    float* __restrict__ X, float* __restrict__ QKV) {
  __shared__ float os[8][64], rs[8][64], xs[8][64], x2[8][64], hs[8][256];
  int tid = threadIdx.x;
  int row0 = blockIdx.x * 8;
  int b = row0 >> 12, t = (row0 >> 8) & 15, n0 = row0 & 255;

  // ---- phase A: attention combine -> os (normalized) ----
  {
    int r = tid & 7, h = (tid >> 3) & 3, d2 = tid >> 5;   // d2 = 0..7 (2 d each)
    int n = n0 + r, bh = b * 4 + h;
    float M = -INFINITY, D = 0.f, SX = 0.f, bacc0 = 0.f, bacc1 = 0.f;
    for (int kt = 0; kt <= t; ++kt) {
      size_t pb = ((size_t)(bh * 16 + t) * 16 + kt) * 768 + n;
      float mg = P0[pb], sp = P0[pb + 256], sx = P0[pb + 512];
      float mnv = fmaxf(M, mg);
      float sc = __builtin_amdgcn_exp2f(M - mnv);   // first iter: exp2(-inf)=0
      float w  = __builtin_amdgcn_exp2f(mg - mnv);
      float wsp = w * sp;
      D  = fmaf(w, sp, D * sc);
      SX = fmaf(w, sx, SX * sc);
      float2 bv = *(const float2*)(Bt + kt * 192 + 128 + h * 16 + d2 * 2);
      bacc0 = fmaf(wsp, bv.x, bacc0 * sc);
      bacc1 = fmaf(wsp, bv.y, bacc1 * sc);
      M = mnv;
    }
    float invD = 1.f / D;
    float2 av = *(const float2*)(A + 128 + h * 16 + d2 * 2);
    os[r][h * 16 + d2 * 2 + 0] = fmaf(SX, av.x, bacc0) * invD;
    os[r][h * 16 + d2 * 2 + 1] = fmaf(SX, av.y, bacc1) * invD;
  }
  // ---- phase A2: residual (rank-1 X0) ----
  {
    int idx = tid;                    // 8*64 = 512 = 2*256
#pragma unroll
    for (int i = 0; i < 2; ++i, idx += 256) {
      int r = idx >> 6, cc = idx & 63;
      rs[r][cc] = fmaf(x_seq[row0 + r], Wi[cc], Xb[t * 64 + cc]);
    }
  }
  __syncthreads();

  int c = tid & 63, grp = tid >> 6;
  // ---- phase B: proj + LN1 (wave grp: rows grp, grp+4) ----
#pragma unroll
  for (int rr = 0; rr < 2; ++rr) {
    int r = grp + 4 * rr;
    float a = bo[c];
#pragma unroll 8
    for (int k = 0; k < 64; ++k) a = fmaf(os[r][k], Wo[k * 64 + c], a);
    float val = a + rs[r][c];
    float mean = wave_sum(val) * (1.f / 64.f);
    float dv = val - mean;
    float var = wave_sum(dv * dv) * (1.f / 64.f);
    xs[r][c] = dv * rsqrtf(var + 1e-5f) * g1[c] + be1[c];
  }
  __syncthreads();

  // ---- phase C: FFN1 64->256 relu ----
  {
    float am[8];
#pragma unroll
    for (int i = 0; i < 8; ++i) am[i] = bb1[tid];
    for (int k4 = 0; k4 < 16; ++k4) {
      float w0 = W1[(4 * k4 + 0) * 256 + tid];
      float w1v = W1[(4 * k4 + 1) * 256 + tid];
      float w2v = W1[(4 * k4 + 2) * 256 + tid];
      float w3v = W1[(4 * k4 + 3) * 256 + tid];
#pragma unroll
      for (int r = 0; r < 8; ++r) {
        float4 xv = *(const float4*)&xs[r][4 * k4];
        am[r] = fmaf(xv.x, w0, am[r]);
        am[r] = fmaf(xv.y, w1v, am[r]);
        am[r] = fmaf(xv.z, w2v, am[r]);
        am[r] = fmaf(xv.w, w3v, am[r]);
      }
    }
#pragma unroll
    for (int r = 0; r < 8; ++r) hs[r][tid] = fmaxf(am[r], 0.f);
  }
  __syncthreads();

  // ---- phase D: FFN2 256->64 + resid + LN2 ----
  {
    float a0 = bb2[c], a1 = bb2[c];
    for (int k4 = 0; k4 < 64; ++k4) {
      float w0 = W2[(4 * k4 + 0) * 64 + c];
      float w1v = W2[(4 * k4 + 1) * 64 + c];
      float w2v = W2[(4 * k4 + 2) * 64 + c];
      float w3v = W2[(4 * k4 + 3) * 64 + c];
      float4 h0 = *(const float4*)&hs[grp][4 * k4];
      float4 h1 = *(const float4*)&hs[grp + 4][4 * k4];
      a0 = fmaf(h0.x, w0, a0); a0 = fmaf(h0.y, w1v, a0);
      a0 = fmaf(h0.z, w2v, a0); a0 = fmaf(h0.w, w3v, a0);
      a1 = fmaf(h1.x, w0, a1); a1 = fmaf(h1.y, w1v, a1);
      a1 = fmaf(h1.z, w2v, a1); a1 = fmaf(h1.w, w3v, a1);
    }
    float av[2] = {a0, a1};
#pragma unroll
    for (int rr = 0; rr < 2; ++rr) {
      int r = grp + 4 * rr;
      float val = av[rr] + xs[r][c];
      float mean = wave_sum(val) * (1.f / 64.f);
      float dv = val - mean;
      float var = wave_sum(dv * dv) * (1.f / 64.f);
      float xn = dv * rsqrtf(var + 1e-5f) * g2[c] + be2[c];
      x2[r][c] = xn;
      if (t == 15) X[(size_t)(row0 + r) * 64 + c] = xn;
    }
  }
  __syncthreads();

  // ---- phase E: qkv for layer 1 (K,V always; Q only for t=15 rows) ----
  {
    int ncol = (t == 15) ? 192 : 128;
    int cb = (t == 15) ? 0 : 64;
    if (tid < ncol) {
      int col = cb + tid;
      float acc[8];
#pragma unroll
      for (int r = 0; r < 8; ++r) acc[r] = bq1[col];
      for (int k4 = 0; k4 < 16; ++k4) {
        float w0 = Wq1[(4 * k4 + 0) * 192 + col];
        float w1v = Wq1[(4 * k4 + 1) * 192 + col];
        float w2v = Wq1[(4 * k4 + 2) * 192 + col];
        float w3v = Wq1[(4 * k4 + 3) * 192 + col];
#pragma unroll
        for (int r = 0; r < 8; ++r) {
          float4 xv = *(const float4*)&x2[r][4 * k4];
          acc[r] = fmaf(xv.x, w0, acc[r]);
          acc[r] = fmaf(xv.y, w1v, acc[r]);
          acc[r] = fmaf(xv.z, w2v, acc[r]);
          acc[r] = fmaf(xv.w, w3v, acc[r]);
        }
      }
#pragma unroll
      for (int r = 0; r < 8; ++r)
        QKV[(size_t)(row0 + r) * 192 + col] = acc[r];
    }
  }
}

// -------- layer-1 MFMA flash attention (tq=15 only) ------------------------
// PA1 written [slot][n][d] (d contiguous) for coalesced combine reads.
__global__ __launch_bounds__(256, 4) void k_attn1(const float* __restrict__ QKV,
    float* __restrict__ PM, float* __restrict__ PL, float* __restrict__ PACC) {
  __shared__ short KH[2][256][8];
  __shared__ short KL[2][256][8];
  __shared__ short VT[32][264];
  int blk = blockIdx.x;
  int bh = blk >> 4, kt = blk & 15;
  const int tq = 15;
  int b = bh >> 2, h = bh & 3;
  int tid = threadIdx.x, w = tid >> 6, lane = tid & 63;
  int l31 = lane & 31, hi = lane >> 5;
  const size_t qkvbase = (size_t)b * S_ * 192;

  for (int i = tid; i < 16 * 264; i += 256) (&VT[16][0])[i] = 0;
  {
    const float* kp = QKV + qkvbase + (size_t)(kt * N_ + tid) * 192 + 64 + h * 16;
    float kf[16], vf[16];
#pragma unroll
    for (int i = 0; i < 4; ++i) {
      float4 k4 = *(const float4*)(kp + 4 * i);
      kf[4 * i] = k4.x; kf[4 * i + 1] = k4.y; kf[4 * i + 2] = k4.z; kf[4 * i + 3] = k4.w;
      float4 v4 = *(const float4*)(kp + 64 + 4 * i);
      vf[4 * i] = v4.x; vf[4 * i + 1] = v4.y; vf[4 * i + 2] = v4.z; vf[4 * i + 3] = v4.w;
    }
    short8 kh0, kh1, kl0, kl1;
#pragma unroll
    for (int i = 0; i < 8; ++i) {
      unsigned ht0 = __float_as_uint(kf[i]) & 0xFFFF0000u;
      kh0[i] = (short)(ht0 >> 16);
      kl0[i] = (short)bf16_rne(kf[i] - __uint_as_float(ht0));
      unsigned ht1 = __float_as_uint(kf[i + 8]) & 0xFFFF0000u;
      kh1[i] = (short)(ht1 >> 16);
      kl1[i] = (short)bf16_rne(kf[i + 8] - __uint_as_float(ht1));
    }
    *(short8*)&KH[0][tid][0] = kh0;
    *(short8*)&KH[1][tid][0] = kh1;
    *(short8*)&KL[0][tid][0] = kl0;
    *(short8*)&KL[1][tid][0] = kl1;
#pragma unroll
    for (int i = 0; i < 16; ++i) VT[i][tid] = (short)bf16_rne(vf[i]);
  }
  __syncthreads();

  const float cscale = 0.36067376022224085f;
  short8 Qh[2], Ql[2];
#pragma unroll
  for (int qs = 0; qs < 2; ++qs) {
    int qloc = w * 64 + qs * 32 + l31;
    const float* qp = QKV + qkvbase + (size_t)(tq * N_ + qloc) * 192 + h * 16 + 8 * hi;
    float4 a4 = *(const float4*)(qp), b4 = *(const float4*)(qp + 4);
    float qf[8] = {a4.x, a4.y, a4.z, a4.w, b4.x, b4.y, b4.z, b4.w};
#pragma unroll
    for (int i = 0; i < 8; ++i) {
      float q = qf[i] * cscale;
      unsigned ht = __float_as_uint(q) & 0xFFFF0000u;
      Qh[qs][i] = (short)(ht >> 16);
      Ql[qs][i] = (short)bf16_rne(q - __uint_as_float(ht));
    }
  }

  f32x16 O0 = zero16(), O1 = zero16();
  float m[2] = {-INFINITY, -INFINITY}, lsum[2] = {0.f, 0.f};

  for (int ks = 0; ks < 8; ++ks) {
    const short8 Kh = *(const short8*)&KH[hi][ks * 32 + l31][0];
    const short8 Kl = *(const short8*)&KL[hi][ks * 32 + l31][0];
    const short8 Va = *(const short8*)&VT[l31][ks * 32 + 8 * hi];
    const short8 Vb = *(const short8*)&VT[l31][ks * 32 + 8 * hi + 16];

#pragma unroll
    for (int qs = 0; qs < 2; ++qs) {
      f32x16 S = zero16();
      S = __builtin_amdgcn_mfma_f32_32x32x16_bf16(Kh, Qh[qs], S, 0, 0, 0);
      S = __builtin_amdgcn_mfma_f32_32x32x16_bf16(Kl, Qh[qs], S, 0, 0, 0);
      S = __builtin_amdgcn_mfma_f32_32x32x16_bf16(Kh, Ql[qs], S, 0, 0, 0);

      float pm = S[0];
#pragma unroll
      for (int r = 1; r < 16; ++r) pm = fmaxf(pm, S[r]);
      pm = fmaxf(pm, __shfl_xor(pm, 32, 64));
      float mq = m[qs];
      if (__any(pm > mq)) {
        float mn = fmaxf(mq, pm);
        float al = __builtin_amdgcn_exp2f(mq - mn);
        m[qs] = mn; mq = mn;
        lsum[qs] *= al;
        if (qs == 0) {
#pragma unroll
          for (int r = 0; r < 16; ++r) O0[r] *= al;
        } else {
#pragma unroll
          for (int r = 0; r < 16; ++r) O1[r] *= al;
        }
      }
      float pr[16], ps = 0.f;
#pragma unroll
      for (int r = 0; r < 16; ++r) {
        pr[r] = __builtin_amdgcn_exp2f(S[r] - mq);
        ps += pr[r];
      }
      lsum[qs] += ps + __shfl_xor(ps, 32, 64);

      unsigned w01 = pack2(pr[0],  pr[1]);
      unsigned w23 = pack2(pr[2],  pr[3]);
      unsigned w45 = pack2(pr[4],  pr[5]);
      unsigned w67 = pack2(pr[6],  pr[7]);
      unsigned w89 = pack2(pr[8],  pr[9]);
      unsigned wab = pack2(pr[10], pr[11]);
      unsigned wcd = pack2(pr[12], pr[13]);
      unsigned wef = pack2(pr[14], pr[15]);
      unsigned e01 = __shfl_xor(w01, 32, 64), e23 = __shfl_xor(w23, 32, 64);
      unsigned e45 = __shfl_xor(w45, 32, 64), e67 = __shfl_xor(w67, 32, 64);
      unsigned e89 = __shfl_xor(w89, 32, 64), eab = __shfl_xor(wab, 32, 64);
      unsigned ecd = __shfl_xor(wcd, 32, 64), eef = __shfl_xor(wef, 32, 64);
      union { short8 s; unsigned u[4]; } P0u, P1u;
      P0u.u[0] = hi ? e45 : w01;
      P0u.u[1] = hi ? e67 : w23;
      P0u.u[2] = hi ? w45 : e01;
      P0u.u[3] = hi ? w67 : e23;
      P1u.u[0] = hi ? ecd : w89;
      P1u.u[1] = hi ? eef : wab;
      P1u.u[2] = hi ? wcd : e89;
      P1u.u[3] = hi ? wef : eab;

      if (qs == 0) {
        O0 = __builtin_amdgcn_mfma_f32_32x32x16_bf16(Va, P0u.s, O0, 0, 0, 0);
        O0 = __builtin_amdgcn_mfma_f32_32x32x16_bf16(Vb, P1u.s, O0, 0, 0, 0);
      } else {
        O1 = __builtin_amdgcn_mfma_f32_32x32x16_bf16(Va, P0u.s, O1, 0, 0, 0);
        O1 = __builtin_amdgcn_mfma_f32_32x32x16_bf16(Vb, P1u.s, O1, 0, 0, 0);
      }
    }
  }

  // ---- epilogue: PM/PL per query; PACC[slot][n][d] with d contiguous ----
  int slot = blk;
#pragma unroll
  for (int qs = 0; qs < 2; ++qs) {
    int qloc = w * 64 + qs * 32 + l31;
    if (lane < 32) {
      PM[(size_t)slot * 256 + qloc] = m[qs];
      PL[(size_t)slot * 256 + qloc] = lsum[qs];
    }
    // reg r -> d = (r&3) + 8*(r>>2) + 4*hi : r=0..3 -> d=4hi..4hi+3,
    // r=4..7 -> d=8+4hi..11+4hi  (two contiguous float4 runs)
    float* pa = PACC + (size_t)slot * 4096 + (size_t)qloc * 16;
    float4 lo4, hi4;
    if (qs == 0) {
      lo4 = make_float4(O0[0], O0[1], O0[2], O0[3]);
      hi4 = make_float4(O0[4], O0[5], O0[6], O0[7]);
    } else {
      lo4 = make_float4(O1[0], O1[1], O1[2], O1[3]);
      hi4 = make_float4(O1[4], O1[5], O1[6], O1[7]);
    }
    *(float4*)(pa + 4 * hi)     = lo4;
    *(float4*)(pa + 8 + 4 * hi) = hi4;
  }
}

// -------- fused1: combine + proj + LN1 + FFN + LN2 + head ------------------
// 128 blocks x 256 threads x 4 rows; phase-A reads fully coalesced.
__global__ __launch_bounds__(256, 2) void k_fused1(
    const float* __restrict__ PM1, const float* __restrict__ PL1,
    const float* __restrict__ PA1,
    const float* __restrict__ Wo, const float* __restrict__ bo,
    const float* __restrict__ g1, const float* __restrict__ be1,
    const float* __restrict__ W1, const float* __restrict__ bb1,
    const float* __restrict__ W2, const float* __restrict__ bb2,
    const float* __restrict__ g2, const float* __restrict__ be2,
    const float* __restrict__ X,
    const float* __restrict__ dW1, const float* __restrict__ db1,
    const float* __restrict__ dW2, const float* __restrict__ db2,
    const float* __restrict__ dW3, const float* __restrict__ db3,
    float* __restrict__ out) {
  __shared__ float os[4][64], rs[4][64], xs[4][64], x2[4][64], hs[4][256];
  __shared__ float h1s[4][32], h2s[4][16];
  int tid = threadIdx.x;
  int bb = blockIdx.x >> 6;                 // batch
  int nbase = (blockIdx.x & 63) * 4;        // first of 4 node rows
  int row0 = bb * S_ + 15 * N_ + nbase;
  size_t base = (size_t)row0 * 64;

  // phase A: combine MFMA partials -> os (coalesced: wave = 4 n x 16 d)
  {
    int d = tid & 15, r = (tid >> 4) & 3, h = tid >> 6;
    int n = nbase + r;
    int sb = (bb * 4 + h) * 16;
    float M = -INFINITY;
#pragma unroll
    for (int s = 0; s < 16; ++s) M = fmaxf(M, PM1[(size_t)(sb + s) * 256 + n]);
    float D = 0.f, od = 0.f;
#pragma unroll
    for (int s = 0; s < 16; ++s) {
      float wgt = __builtin_amdgcn_exp2f(PM1[(size_t)(sb + s) * 256 + n] - M);
      D = fmaf(PL1[(size_t)(sb + s) * 256 + n], wgt, D);
      od = fmaf(PA1[(size_t)(sb + s) * 4096 + (size_t)n * 16 + d], wgt, od);
    }
    os[r][h * 16 + d] = od / D;
    rs[tid >> 6][tid & 63] = X[base + tid];   // 4 rows x 64
  }
  __syncthreads();

  int c = tid & 63, grp = tid >> 6;   // grp = row (0..3), one wave per row
  // proj + LN1
  {
    float a = bo[c];
#pragma unroll 8
    for (int k = 0; k < 64; ++k) a = fmaf(os[grp][k], Wo[k * 64 + c], a);
    float val = a + rs[grp][c];
    float mean = wave_sum(val) * (1.f / 64.f);
    float dv = val - mean;
    float var = wave_sum(dv * dv) * (1.f / 64.f);
    xs[grp][c] = dv * rsqrtf(var + 1e-5f) * g1[c] + be1[c];
  }
  __syncthreads();

  // FFN1: thread = mid (0..255), 4 rows
  {
    float am0 = bb1[tid], am1 = am0, am2 = am0, am3 = am0;
    for (int k4 = 0; k4 < 16; ++k4) {
      float w0 = W1[(4 * k4 + 0) * 256 + tid];
      float w1v = W1[(4 * k4 + 1) * 256 + tid];
      float w2v = W1[(4 * k4 + 2) * 256 + tid];
      float w3v = W1[(4 * k4 + 3) * 256 + tid];
      float4 x0 = *(const float4*)&xs[0][4 * k4];
      float4 x1 = *(const float4*)&xs[1][4 * k4];
      float4 x2v = *(const float4*)&xs[2][4 * k4];
      float4 x3 = *(const float4*)&xs[3][4 * k4];
      am0 = fmaf(x0.x, w0, am0); am0 = fmaf(x0.y, w1v, am0);
      am0 = fmaf(x0.z, w2v, am0); am0 = fmaf(x0.w, w3v, am0);
      am1 = fmaf(x1.x, w0, am1); am1 = fmaf(x1.y, w1v, am1);
      am1 = fmaf(x1.z, w2v, am1); am1 = fmaf(x1.w, w3v, am1);
      am2 = fmaf(x2v.x, w0, am2); am2 = fmaf(x2v.y, w1v, am2);
      am2 = fmaf(x2v.z, w2v, am2); am2 = fmaf(x2v.w, w3v, am2);
      am3 = fmaf(x3.x, w0, am3); am3 = fmaf(x3.y, w1v, am3);
      am3 = fmaf(x3.z, w2v, am3); am3 = fmaf(x3.w, w3v, am3);
    }
    hs[0][tid] = fmaxf(am0, 0.f);
    hs[1][tid] = fmaxf(am1, 0.f);
    hs[2][tid] = fmaxf(am2, 0.f);
    hs[3][tid] = fmaxf(am3, 0.f);
  }
  __syncthreads();

  // FFN2 + resid + LN2 (wave grp = row)
  {
    float a = bb2[c];
    for (int k4 = 0; k4 < 64; ++k4) {
      float w0 = W2[(4 * k4 + 0) * 64 + c];
      float w1v = W2[(4 * k4 + 1) * 64 + c];
      float w2v = W2[(4 * k4 + 2) * 64 + c];
      float w3v = W2[(4 * k4 + 3) * 64 + c];
      float4 hv = *(const float4*)&hs[grp][4 * k4];
      a = fmaf(hv.x, w0, a); a = fmaf(hv.y, w1v, a);
      a = fmaf(hv.z, w2v, a); a = fmaf(hv.w, w3v, a);
    }
    float val = a + xs[grp][c];
    float mean = wave_sum(val) * (1.f / 64.f);
    float dv = val - mean;
    float var = wave_sum(dv * dv) * (1.f / 64.f);
    x2[grp][c] = dv * rsqrtf(var + 1e-5f) * g2[c] + be2[c];
  }
  __syncthreads();

  // head: 64 -> 32 -> 16 -> 1
  if (tid < 128) {
    int r = tid >> 5, mid = tid & 31;
    float a = db1[mid];
#pragma unroll 8
    for (int k = 0; k < 64; ++k) a = fmaf(x2[r][k], dW1[k * 32 + mid], a);
    h1s[r][mid] = fmaxf(a, 0.f);
  }
  __syncthreads();
  if (tid < 64) {
    int r = tid >> 4, low = tid & 15;
    float a = db2[low];
#pragma unroll
    for (int k = 0; k < 32; ++k) a = fmaf(h1s[r][k], dW2[k * 16 + low], a);
    h2s[r][low] = fmaxf(a, 0.f);
  }
  __syncthreads();
  if (tid < 4) {
    float a = db3[0];
#pragma unroll
    for (int k = 0; k < 16; ++k) a = fmaf(h2s[tid][k], dW3[k], a);
    out[bb * 256 + nbase + tid] = a;
  }
}

}  // namespace

extern "C" void kernel_launch(void* const* d_in, const int* in_sizes, int n_in,
                              void* d_out, int out_size, void* d_ws, size_t ws_size,
                              hipStream_t stream) {
  const float* x_seq = (const float*)d_in[0];
  // d_in[1] = edge_index (unused by reference)
  const float* Wi   = (const float*)d_in[2];
  const float* bi   = (const float*)d_in[3];
  const float* Wqkv = (const float*)d_in[4];
  const float* bqkv = (const float*)d_in[5];
  const float* Wo   = (const float*)d_in[6];
  const float* bo   = (const float*)d_in[7];
  const float* ln1g = (const float*)d_in[8];
  const float* ln1b = (const float*)d_in[9];
  const float* W1   = (const float*)d_in[10];
  const float* b1   = (const float*)d_in[11];
  const float* W2   = (const float*)d_in[12];
  const float* b2   = (const float*)d_in[13];
  const float* ln2g = (const float*)d_in[14];
  const float* ln2b = (const float*)d_in[15];
  const float* dW1  = (const float*)d_in[16];
  const float* db1  = (const float*)d_in[17];
  const float* dW2  = (const float*)d_in[18];
  const float* db2  = (const float*)d_in[19];
  const float* dW3  = (const float*)d_in[20];
  const float* db3  = (const float*)d_in[21];

  float* ws   = (float*)d_ws;  // needs >= 17.1 MB
  float* A    = ws + OFF_A;
  float* Bt   = ws + OFF_BT;
  float* Xb   = ws + OFF_XB;
  float* ALPH = ws + OFF_ALPH;
  float* BET  = ws + OFF_BET;
  float* GAM  = ws + OFF_GAM;
  float* DELT = ws + OFF_DELT;
  float* MN   = ws + OFF_MN;
  float* MX   = ws + OFF_MX;
  float* X    = ws + OFF_X;
  float* QKV  = ws + OFF_QKV;
  float* P0   = ws + OFF_P0;
  float* PM1  = ws + OFF_PM1;
  float* PL1  = ws + OFF_PL1;
  float* PA1  = ws + OFF_PA1;

  k_setup<<<19, 256, 0, stream>>>(x_seq, Wi, bi, Wqkv, bqkv, A, Bt, Xb,
                                  ALPH, BET, GAM, DELT, MN, MX);
  k_attn0<<<8 * PAIRS, 256, 0, stream>>>(x_seq, ALPH, BET, GAM, DELT, MN, MX, P0);
  k_fused0<<<1024, 256, 0, stream>>>(P0, A, Bt, Xb, x_seq, Wi,
                                     Wo, bo, ln1g, ln1b, W1, b1, W2, b2,
                                     ln2g, ln2b, Wqkv + 64 * 192, bqkv + 192,
                                     X, QKV);
  k_attn1<<<128, 256, 0, stream>>>(QKV, PM1, PL1, PA1);
  k_fused1<<<128, 256, 0, stream>>>(PM1, PL1, PA1,
                                    Wo + 4096, bo + 64, ln1g + 64, ln1b + 64,
                                    W1 + 64 * 256, b1 + 256, W2 + 256 * 64, b2 + 64,
                                    ln2g + 64, ln2b + 64, X,
                                    dW1, db1, dW2, db2, dW3, db3, (float*)d_out);
}

// Round 9
// 86.237 us; speedup vs baseline: 5.6319x; 1.0294x over previous
//
#include <hip/hip_runtime.h>
#include <math.h>

// GlobalTransformer: B=2, T=16, N=256 (S=4096), H=64, NHEAD=4, dh=16, L=2
// Round 9: fused0 rebuilt on MFMA (all GEMM phases as Y^T = W^T @ X^T with
// hi/lo bf16 split operands); weights pre-transposed+split in setup.
// attn0 / attn1 / fused1 identical to round 8. 5 dispatches.

namespace {
constexpr int T_ = 16, N_ = 256, S_ = 4096;
constexpr int PAIRS = 136;   // valid (tq,kt) pairs per bh (layer 0)

// ws float offsets (total 4,314,624 floats = 17.3 MB)
constexpr size_t OFF_A    = 0;        // [192]   Wi@Wqkv0
constexpr size_t OFF_BT   = 192;      // [16][192] (bi+tp)@Wqkv0 + bqkv0
constexpr size_t OFF_XB   = 3264;     // [16][64]  bi+tp
constexpr size_t OFF_ALPH = 4288;     // [4]
constexpr size_t OFF_BET  = 4292;     // [4][16]
constexpr size_t OFF_GAM  = 4356;     // [4][16]
constexpr size_t OFF_DELT = 4420;     // [4][16][16]
constexpr size_t OFF_MN   = 5444;     // [2][16]
constexpr size_t OFF_MX   = 5476;     // [2][16]
constexpr size_t OFF_X    = 5632;     // [B*S][64] (only t=15 rows written)
constexpr size_t OFF_QKV  = 529920;   // [B*S][192] (layer 1; Q cols only t=15)
constexpr size_t OFF_P0   = 2102784;  // [8][16][16][3][256]
constexpr size_t OFF_PM1  = 3675648;  // [128][256]
constexpr size_t OFF_PL1  = 3708416;  // [128][256]
constexpr size_t OFF_PA1  = 3741184;  // [128][256][16]
constexpr size_t OFF_WT   = 4265472;  // 49152 floats = 98304 shorts (see below)
// WT (shorts): WoT_h 0, WoT_l 4096, W1T_h 8192, W1T_l 24576,
//              W2T_h 40960, W2T_l 57344, WqT_h 73728, WqT_l 86016

typedef float  f32x16 __attribute__((ext_vector_type(16)));
typedef short  short8 __attribute__((ext_vector_type(8)));

__device__ inline float wave_sum(float v) {
#pragma unroll
  for (int off = 32; off > 0; off >>= 1) v += __shfl_xor(v, off, 64);
  return v;
}
__device__ inline unsigned bf16_rne(float f) {
  unsigned u = __float_as_uint(f);
  return (u + 0x7FFFu + ((u >> 16) & 1u)) >> 16;
}
__device__ inline unsigned pack2(float a, float b) {   // low<-a, high<-b
  return bf16_rne(a) | (bf16_rne(b) << 16);
}
__device__ inline f32x16 zero16() {
  f32x16 z;
#pragma unroll
  for (int i = 0; i < 16; ++i) z[i] = 0.f;
  return z;
}
__device__ inline float pe_val(int t, int h) {
  float div = __expf((float)(h & ~1) * (-0.14391156831212787f));
  float arg = (float)t * div;
  return (h & 1) ? cosf(arg) : sinf(arg);
}
__device__ inline float rebuild(short h, short l) {
  return __uint_as_float(((unsigned)(unsigned short)h) << 16) +
         __uint_as_float(((unsigned)(unsigned short)l) << 16);
}
// split 4 f32 -> 4 hi(trunc) + 4 lo(rne residual) shorts, stored as uint2
__device__ __forceinline__ void split4_store(short* hp, short* lp,
                                             float v0, float v1, float v2, float v3) {
  unsigned u0 = __float_as_uint(v0), u1 = __float_as_uint(v1);
  unsigned u2 = __float_as_uint(v2), u3 = __float_as_uint(v3);
  float r0 = v0 - __uint_as_float(u0 & 0xFFFF0000u);
  float r1 = v1 - __uint_as_float(u1 & 0xFFFF0000u);
  float r2 = v2 - __uint_as_float(u2 & 0xFFFF0000u);
  float r3 = v3 - __uint_as_float(u3 & 0xFFFF0000u);
  *(uint2*)hp = make_uint2((u0 >> 16) | (u1 & 0xFFFF0000u),
                           (u2 >> 16) | (u3 & 0xFFFF0000u));
  *(uint2*)lp = make_uint2(pack2(r0, r1), pack2(r2, r3));
}
// Y^T tile GEMM: A = W^T rows (out-ch), B = X^T cols (data rows) from LDS.
__device__ __forceinline__ f32x16 gemm_tile(
    const short* __restrict__ Wh, const short* __restrict__ Wl, int tileRow,
    int inDim, int nkt, const short* Bh, const short* Bl, int bstride,
    int l31, int hi) {
  f32x16 C = zero16();
  for (int kt = 0; kt < nkt; ++kt) {
    int ko = kt * 16 + 8 * hi;
    short8 Ah = *(const short8*)&Wh[tileRow * inDim + ko];
    short8 Al = *(const short8*)&Wl[tileRow * inDim + ko];
    short8 Bh8 = *(const short8*)&Bh[l31 * bstride + ko];
    short8 Bl8 = *(const short8*)&Bl[l31 * bstride + ko];
    C = __builtin_amdgcn_mfma_f32_32x32x16_bf16(Ah, Bh8, C, 0, 0, 0);
    C = __builtin_amdgcn_mfma_f32_32x32x16_bf16(Al, Bh8, C, 0, 0, 0);
    C = __builtin_amdgcn_mfma_f32_32x32x16_bf16(Ah, Bl8, C, 0, 0, 0);
  }
  return C;
}

// -------- setup: 0..15 Bt/Xb, 16 A, 17 tables, 18 mn/mx, 19..66 WT --------
__global__ void k_setup(const float* __restrict__ x_seq,
                        const float* __restrict__ Wi, const float* __restrict__ bi,
                        const float* __restrict__ Wqkv, const float* __restrict__ bqkv,
                        const float* __restrict__ Wo, const float* __restrict__ W1,
                        const float* __restrict__ W2,
                        float* __restrict__ A, float* __restrict__ Bt,
                        float* __restrict__ Xb,
                        float* __restrict__ ALPH, float* __restrict__ BET,
                        float* __restrict__ GAM, float* __restrict__ DELT,
                        float* __restrict__ MN, float* __restrict__ MX,
                        short* __restrict__ WT) {
  int t = blockIdx.x, tid = threadIdx.x;
  if (t < 16) {
    if (tid < 192) {
      float acc = bqkv[tid];
#pragma unroll 8
      for (int h = 0; h < 64; ++h)
        acc = fmaf(bi[h] + pe_val(t, h), Wqkv[h * 192 + tid], acc);
      Bt[t * 192 + tid] = acc;
    }
    if (tid < 64) Xb[t * 64 + tid] = bi[tid] + pe_val(t, tid);
  } else if (t == 16) {
    if (tid < 192) {
      float acc = 0.f;
#pragma unroll 8
      for (int h = 0; h < 64; ++h) acc = fmaf(Wi[h], Wqkv[h * 192 + tid], acc);
      A[tid] = acc;
    }
  } else if (t == 17) {
    __shared__ float sA[128];
    __shared__ float sB[16][128];
    if (tid < 128) {
      float acc = 0.f;
#pragma unroll 8
      for (int h = 0; h < 64; ++h) acc = fmaf(Wi[h], Wqkv[h * 192 + tid], acc);
      sA[tid] = acc;
    }
    {
      int tt = tid >> 4, i = tid & 15;
      float accv[8];
#pragma unroll
      for (int j = 0; j < 8; ++j) accv[j] = bqkv[i * 8 + j];
      for (int h = 0; h < 64; ++h) {
        float xb = bi[h] + pe_val(tt, h);
#pragma unroll
        for (int j = 0; j < 8; ++j)
          accv[j] = fmaf(xb, Wqkv[h * 192 + i * 8 + j], accv[j]);
      }
#pragma unroll
      for (int j = 0; j < 8; ++j) sB[tt][i * 8 + j] = accv[j];
    }
    __syncthreads();
    const float k2 = 0.36067376022224085f;  // (1/sqrt(16)) * log2(e)
    if (tid < 4) {
      float d = 0.f;
#pragma unroll
      for (int i = 0; i < 16; ++i) d = fmaf(sA[tid * 16 + i], sA[64 + tid * 16 + i], d);
      ALPH[tid] = k2 * d;
    }
    if (tid < 64) {
      int h = tid >> 4, tp2 = tid & 15;
      float d = 0.f, g = 0.f;
#pragma unroll
      for (int i = 0; i < 16; ++i) {
        d = fmaf(sA[h * 16 + i], sB[tp2][64 + h * 16 + i], d);
        g = fmaf(sA[64 + h * 16 + i], sB[tp2][h * 16 + i], g);
      }
      BET[h * 16 + tp2] = k2 * d;
      GAM[h * 16 + tp2] = k2 * g;
    }
#pragma unroll
    for (int q = 0; q < 4; ++q) {
      int idx = tid + 256 * q;
      int h = idx >> 8, ta = (idx >> 4) & 15, tb = idx & 15;
      float d = 0.f;
#pragma unroll
      for (int i = 0; i < 16; ++i)
        d = fmaf(sB[ta][h * 16 + i], sB[tb][64 + h * 16 + i], d);
      DELT[h * 256 + ta * 16 + tb] = k2 * d;
    }
  } else if (t == 18) {
    int g = tid >> 3, i = tid & 7;
    const float* xp = x_seq + (g >> 4) * S_ + (g & 15) * N_;
    float mn = 1e30f, mx = -1e30f;
    for (int j = i; j < 256; j += 8) {
      float v = xp[j];
      mn = fminf(mn, v); mx = fmaxf(mx, v);
    }
#pragma unroll
    for (int off = 1; off < 8; off <<= 1) {
      mn = fminf(mn, __shfl_xor(mn, off, 64));
      mx = fmaxf(mx, __shfl_xor(mx, off, 64));
    }
    if (i == 0) { MN[g] = mn; MX[g] = mx; }
  } else {
    // transpose + hi/lo split the fused0 weights (layer-0 Wo/W1/W2, layer-1 Wqkv)
    int tb2 = t - 19;   // 0..47
    const float* Wq1 = Wqkv + 64 * 192;
#pragma unroll
    for (int e = 0; e < 4; ++e) {
      int gi = tb2 * 1024 + e * 256 + tid;
      float v; int hdst, ldst;
      if (gi < 4096) {
        int o = gi >> 6, i = gi & 63; v = Wo[i * 64 + o];
        hdst = gi; ldst = gi + 4096;
      } else if (gi < 20480) {
        int li = gi - 4096; int o = li >> 6, i = li & 63; v = W1[i * 256 + o];
        hdst = 8192 + li; ldst = 24576 + li;
      } else if (gi < 36864) {
        int li = gi - 20480; int o = li >> 8, i = li & 255; v = W2[i * 64 + o];
        hdst = 40960 + li; ldst = 57344 + li;
      } else {
        int li = gi - 36864; int o = li >> 6, i = li & 63; v = Wq1[i * 192 + o];
        hdst = 73728 + li; ldst = 86016 + li;
      }
      unsigned u = __float_as_uint(v);
      WT[hdst] = (short)(u >> 16);
      WT[ldst] = (short)bf16_rne(v - __uint_as_float(u & 0xFFFF0000u));
    }
  }
}

// -------- layer-0 attention partials via rank-1 algebra (round 8) ----------
__global__ __launch_bounds__(256, 4) void k_attn0(
    const float* __restrict__ x_seq,
    const float* __restrict__ ALPH, const float* __restrict__ BET,
    const float* __restrict__ GAM, const float* __restrict__ DELT,
    const float* __restrict__ MN, const float* __restrict__ MX,
    float* __restrict__ P0) {
  __shared__ float4 xk4[64];
  int blk = blockIdx.x;
  int bh = blk / PAIRS, pair = blk % PAIRS;
  int b = bh >> 2, h = bh & 3;
  int tq = 0, p = pair;
  while (p >= tq + 1) { p -= tq + 1; ++tq; }
  int kt = p;
  int tid = threadIdx.x;
  if (tid < 64) xk4[tid] = *(const float4*)(x_seq + (size_t)(b * S_ + kt * N_) + 4 * tid);
  __syncthreads();

  float x = x_seq[b * S_ + tq * N_ + tid];
  float a = fmaf(ALPH[h], x, GAM[h * 16 + tq]);
  float xext = (a >= 0.f) ? MX[b * 16 + kt] : MN[b * 16 + kt];
  float axext = a * xext;
  float Mg = axext + fmaf(BET[h * 16 + kt], x, DELT[h * 256 + tq * 16 + kt]);
  float sp0 = 0.f, sp1 = 0.f, sp2 = 0.f, sp3 = 0.f;
  float sx0 = 0.f, sx1 = 0.f, sx2 = 0.f, sx3 = 0.f;
#pragma unroll 8
  for (int j = 0; j < 64; ++j) {
    float4 xv = xk4[j];
    float e0 = __builtin_amdgcn_exp2f(fmaf(a, xv.x, -axext));
    float e1 = __builtin_amdgcn_exp2f(fmaf(a, xv.y, -axext));
    float e2 = __builtin_amdgcn_exp2f(fmaf(a, xv.z, -axext));
    float e3 = __builtin_amdgcn_exp2f(fmaf(a, xv.w, -axext));
    sp0 += e0; sp1 += e1; sp2 += e2; sp3 += e3;
    sx0 = fmaf(xv.x, e0, sx0); sx1 = fmaf(xv.y, e1, sx1);
    sx2 = fmaf(xv.z, e2, sx2); sx3 = fmaf(xv.w, e3, sx3);
  }
  size_t pb = ((size_t)(bh * 16 + tq) * 16 + kt) * 768;
  P0[pb + tid]       = Mg;
  P0[pb + 256 + tid] = (sp0 + sp1) + (sp2 + sp3);
  P0[pb + 512 + tid] = (sx0 + sx1) + (sx2 + sx3);
}

// -------- fused0 (MFMA): combine + proj + LN1 + FFN + LN2 + qkv(layer1) ----
// 512 blocks x 16 rows x 256 threads (4 waves), 2 blocks/CU.
__global__ __launch_bounds__(256, 2) void k_fused0(
    const float* __restrict__ P0, const float* __restrict__ A,
    const float* __restrict__ Bt, const float* __restrict__ Xb,
    const float* __restrict__ x_seq, const float* __restrict__ Wi,
    const float* __restrict__ bo, const float* __restrict__ g1,
    const float* __restrict__ be1, const float* __restrict__ bb1,
    const float* __restrict__ bb2, const float* __restrict__ g2,
    const float* __restrict__ be2, const float* __restrict__ bq1,
    const short* __restrict__ WT,
    float* __restrict__ X, float* __restrict__ QKV) {
  // B-source buffers: rows 0-15 data, rows 16-31 zero (MFMA cols 16-31 unused)
  __shared__ short qbh[32][72], qbl[32][72];     // os, later reused as x2
  __shared__ short xsh[32][72], xsl[32][72];     // LN1 out
  __shared__ short hsh[32][264], hsl[32][264];   // ReLU(FFN1) out
  __shared__ float ys[16][68];                   // f32 GEMM output staging

  const short* WoTh = WT;          const short* WoTl = WT + 4096;
  const short* W1Th = WT + 8192;   const short* W1Tl = WT + 24576;
  const short* W2Th = WT + 40960;  const short* W2Tl = WT + 57344;
  const short* WqTh = WT + 73728;  const short* WqTl = WT + 86016;

  int blk = blockIdx.x;
  int b = blk >> 8, t = (blk >> 4) & 15, n0 = (blk & 15) * 16;
  int gbase = b * S_ + t * N_ + n0;
  int tid = threadIdx.x;
  int w = tid >> 6, lane = tid & 63, l31 = lane & 31, hi = lane >> 5;

  // zero rows 16..31 of all B-source buffers (once)
  for (int i = tid; i < 16 * 72; i += 256) {
    (&qbh[16][0])[i] = 0; (&qbl[16][0])[i] = 0;
    (&xsh[16][0])[i] = 0; (&xsl[16][0])[i] = 0;
  }
  for (int i = tid; i < 16 * 264; i += 256) {
    (&hsh[16][0])[i] = 0; (&hsl[16][0])[i] = 0;
  }

  // ---- phase A: attention combine (two-pass, loads independent) ----
  {
    int r = tid & 15, hh = (tid >> 4) & 3, d4 = tid >> 6;
    int n = n0 + r, bh4 = b * 4 + hh;
    size_t pbase = ((size_t)(bh4 * 16 + t) * 16) * 768 + n;
    float M = -INFINITY;
    for (int kt = 0; kt <= t; ++kt)
      M = fmaxf(M, P0[pbase + (size_t)kt * 768]);
    float D = 0.f, SX = 0.f, c0 = 0.f, c1 = 0.f, c2 = 0.f, c3 = 0.f;
    for (int kt = 0; kt <= t; ++kt) {
      size_t pb = pbase + (size_t)kt * 768;
      float wgt = __builtin_amdgcn_exp2f(P0[pb] - M);
      float wsp = wgt * P0[pb + 256];
      D += wsp;
      SX = fmaf(wgt, P0[pb + 512], SX);
      float4 bv = *(const float4*)(Bt + kt * 192 + 128 + hh * 16 + d4 * 4);
      c0 = fmaf(wsp, bv.x, c0); c1 = fmaf(wsp, bv.y, c1);
      c2 = fmaf(wsp, bv.z, c2); c3 = fmaf(wsp, bv.w, c3);
    }
    float invD = 1.f / D;
    float4 av = *(const float4*)(A + 128 + hh * 16 + d4 * 4);
    float o0 = fmaf(SX, av.x, c0) * invD;
    float o1 = fmaf(SX, av.y, c1) * invD;
    float o2 = fmaf(SX, av.z, c2) * invD;
    float o3 = fmaf(SX, av.w, c3) * invD;
    split4_store(&qbh[r][hh * 16 + d4 * 4], &qbl[r][hh * 16 + d4 * 4],
                 o0, o1, o2, o3);
  }
  __syncthreads();

  // ---- proj: os @ Wo (waves 0,1 -> out tiles 0,1) ----
  if (w < 2) {
    f32x16 C = gemm_tile(WoTh, WoTl, w * 32 + l31, 64, 4,
                         &qbh[0][0], &qbl[0][0], 72, l31, hi);
    if (l31 < 16) {
#pragma unroll
      for (int g = 0; g < 4; ++g)
        *(float4*)&ys[l31][w * 32 + g * 8 + 4 * hi] =
            make_float4(C[4 * g], C[4 * g + 1], C[4 * g + 2], C[4 * g + 3]);
    }
  }
  __syncthreads();

  // ---- LN1: val = proj + bo + residual; write hi/lo split xs ----
  {
    int c = tid & 63, grp = tid >> 6;
    float xb_c = Xb[t * 64 + c], wi_c = Wi[c], bo_c = bo[c];
    float g1c = g1[c], be1c = be1[c];
#pragma unroll
    for (int rr = 0; rr < 4; ++rr) {
      int row = grp * 4 + rr;
      float xv = x_seq[gbase + row];
      float val = ys[row][c] + bo_c + fmaf(xv, wi_c, xb_c);
      float mean = wave_sum(val) * (1.f / 64.f);
      float dv = val - mean;
      float var = wave_sum(dv * dv) * (1.f / 64.f);
      float xn = dv * rsqrtf(var + 1e-5f) * g1c + be1c;
      unsigned u = __float_as_uint(xn);
      xsh[row][c] = (short)(u >> 16);
      xsl[row][c] = (short)bf16_rne(xn - __uint_as_float(u & 0xFFFF0000u));
    }
  }
  __syncthreads();

  // ---- FFN1: xs @ W1, +b1, ReLU, split-store (each wave 2 of 8 tiles) ----
#pragma unroll
  for (int ti = 0; ti < 2; ++ti) {
    int tt = w + 4 * ti;
    f32x16 C = gemm_tile(W1Th, W1Tl, tt * 32 + l31, 64, 4,
                         &xsh[0][0], &xsl[0][0], 72, l31, hi);
    if (l31 < 16) {
#pragma unroll
      for (int g = 0; g < 4; ++g) {
        int cb = tt * 32 + g * 8 + 4 * hi;
        float v0 = fmaxf(C[4 * g + 0] + bb1[cb + 0], 0.f);
        float v1 = fmaxf(C[4 * g + 1] + bb1[cb + 1], 0.f);
        float v2 = fmaxf(C[4 * g + 2] + bb1[cb + 2], 0.f);
        float v3 = fmaxf(C[4 * g + 3] + bb1[cb + 3], 0.f);
        split4_store(&hsh[l31][cb], &hsl[l31][cb], v0, v1, v2, v3);
      }
    }
  }
  __syncthreads();

  // ---- FFN2: hs @ W2 (waves 0,1 -> out tiles 0,1; K = 256) ----
  if (w < 2) {
    f32x16 C = gemm_tile(W2Th, W2Tl, w * 32 + l31, 256, 16,
                         &hsh[0][0], &hsl[0][0], 264, l31, hi);
    if (l31 < 16) {
#pragma unroll
      for (int g = 0; g < 4; ++g)
        *(float4*)&ys[l31][w * 32 + g * 8 + 4 * hi] =
            make_float4(C[4 * g], C[4 * g + 1], C[4 * g + 2], C[4 * g + 3]);
    }
  }
  __syncthreads();

  // ---- LN2: val = ffn2 + b2 + xs; write x2 (into qb buffers); X at t=15 ----
  {
    int c = tid & 63, grp = tid >> 6;
    float b2c = bb2[c], g2c = g2[c], be2c = be2[c];
#pragma unroll
    for (int rr = 0; rr < 4; ++rr) {
      int row = grp * 4 + rr;
      float val = ys[row][c] + b2c + rebuild(xsh[row][c], xsl[row][c]);
      float mean = wave_sum(val) * (1.f / 64.f);
      float dv = val - mean;
      float var = wave_sum(dv * dv) * (1.f / 64.f);
      float xn = dv * rsqrtf(var + 1e-5f) * g2c + be2c;
      unsigned u = __float_as_uint(xn);
      qbh[row][c] = (short)(u >> 16);
      qbl[row][c] = (short)bf16_rne(xn - __uint_as_float(u & 0xFFFF0000u));
      if (t == 15) X[(size_t)(gbase + row) * 64 + c] = xn;
    }
  }
  __syncthreads();

  // ---- qkv(layer1): x2 @ Wq1 (+bq1) -> global; K/V always, Q only t=15 ----
  {
    int tlA = (t == 15) ? w : (2 + w);
    int ntl = (t == 15 && w < 2) ? 2 : 1;
    for (int ti = 0; ti < ntl; ++ti) {
      int tt = ti ? (w + 4) : tlA;
      f32x16 C = gemm_tile(WqTh, WqTl, tt * 32 + l31, 64, 4,
                           &qbh[0][0], &qbl[0][0], 72, l31, hi);
      if (l31 < 16) {
        size_t rb = (size_t)(gbase + l31) * 192;
#pragma unroll
        for (int g = 0; g < 4; ++g) {
          int cb = tt * 32 + g * 8 + 4 * hi;
          float4 o = make_float4(C[4 * g + 0] + bq1[cb + 0],
                                 C[4 * g + 1] + bq1[cb + 1],
                                 C[4 * g + 2] + bq1[cb + 2],
                                 C[4 * g + 3] + bq1[cb + 3]);
          *(float4*)&QKV[rb + cb] = o;
        }
      }
    }
  }
}

// -------- layer-1 MFMA flash attention (tq=15 only), round-8 verified ------
__global__ __launch_bounds__(256, 4) void k_attn1(const float* __restrict__ QKV,
    float* __restrict__ PM, float* __restrict__ PL, float* __restrict__ PACC) {
  __shared__ short KH[2][256][8];
  __shared__ short KL[2][256][8];
  __shared__ short VT[32][264];
  int blk = blockIdx.x;
  int bh = blk >> 4, kt = blk & 15;
  const int tq = 15;
  int b = bh >> 2, h = bh & 3;
  int tid = threadIdx.x, w = tid >> 6, lane = tid & 63;
  int l31 = lane & 31, hi = lane >> 5;
  const size_t qkvbase = (size_t)b * S_ * 192;

  for (int i = tid; i < 16 * 264; i += 256) (&VT[16][0])[i] = 0;
  {
    const float* kp = QKV + qkvbase + (size_t)(kt * N_ + tid) * 192 + 64 + h * 16;
    float kf[16], vf[16];
#pragma unroll
    for (int i = 0; i < 4; ++i) {
      float4 k4 = *(const float4*)(kp + 4 * i);
      kf[4 * i] = k4.x; kf[4 * i + 1] = k4.y; kf[4 * i + 2] = k4.z; kf[4 * i + 3] = k4.w;
      float4 v4 = *(const float4*)(kp + 64 + 4 * i);
      vf[4 * i] = v4.x; vf[4 * i + 1] = v4.y; vf[4 * i + 2] = v4.z; vf[4 * i + 3] = v4.w;
    }
    short8 kh0, kh1, kl0, kl1;
#pragma unroll
    for (int i = 0; i < 8; ++i) {
      unsigned ht0 = __float_as_uint(kf[i]) & 0xFFFF0000u;
      kh0[i] = (short)(ht0 >> 16);
      kl0[i] = (short)bf16_rne(kf[i] - __uint_as_float(ht0));
      unsigned ht1 = __float_as_uint(kf[i + 8]) & 0xFFFF0000u;
      kh1[i] = (short)(ht1 >> 16);
      kl1[i] = (short)bf16_rne(kf[i + 8] - __uint_as_float(ht1));
    }
    *(short8*)&KH[0][tid][0] = kh0;
    *(short8*)&KH[1][tid][0] = kh1;
    *(short8*)&KL[0][tid][0] = kl0;
    *(short8*)&KL[1][tid][0] = kl1;
#pragma unroll
    for (int i = 0; i < 16; ++i) VT[i][tid] = (short)bf16_rne(vf[i]);
  }
  __syncthreads();

  const float cscale = 0.36067376022224085f;
  short8 Qh[2], Ql[2];
#pragma unroll
  for (int qs = 0; qs < 2; ++qs) {
    int qloc = w * 64 + qs * 32 + l31;
    const float* qp = QKV + qkvbase + (size_t)(tq * N_ + qloc) * 192 + h * 16 + 8 * hi;
    float4 a4 = *(const float4*)(qp), b4 = *(const float4*)(qp + 4);
    float qf[8] = {a4.x, a4.y, a4.z, a4.w, b4.x, b4.y, b4.z, b4.w};
#pragma unroll
    for (int i = 0; i < 8; ++i) {
      float q = qf[i] * cscale;
      unsigned ht = __float_as_uint(q) & 0xFFFF0000u;
      Qh[qs][i] = (short)(ht >> 16);
      Ql[qs][i] = (short)bf16_rne(q - __uint_as_float(ht));
    }
  }

  f32x16 O0 = zero16(), O1 = zero16();
  float m[2] = {-INFINITY, -INFINITY}, lsum[2] = {0.f, 0.f};

  for (int ks = 0; ks < 8; ++ks) {
    const short8 Kh = *(const short8*)&KH[hi][ks * 32 + l31][0];
    const short8 Kl = *(const short8*)&KL[hi][ks * 32 + l31][0];
    const short8 Va = *(const short8*)&VT[l31][ks * 32 + 8 * hi];
    const short8 Vb = *(const short8*)&VT[l31][ks * 32 + 8 * hi + 16];

#pragma unroll
    for (int qs = 0; qs < 2; ++qs) {
      f32x16 S = zero16();
      S = __builtin_amdgcn_mfma_f32_32x32x16_bf16(Kh, Qh[qs], S, 0, 0, 0);
      S = __builtin_amdgcn_mfma_f32_32x32x16_bf16(Kl, Qh[qs], S, 0, 0, 0);
      S = __builtin_amdgcn_mfma_f32_32x32x16_bf16(Kh, Ql[qs], S, 0, 0, 0);

      float pm = S[0];
#pragma unroll
      for (int r = 1; r < 16; ++r) pm = fmaxf(pm, S[r]);
      pm = fmaxf(pm, __shfl_xor(pm, 32, 64));
      float mq = m[qs];
      if (__any(pm > mq)) {
        float mn = fmaxf(mq, pm);
        float al = __builtin_amdgcn_exp2f(mq - mn);
        m[qs] = mn; mq = mn;
        lsum[qs] *= al;
        if (qs == 0) {
#pragma unroll
          for (int r = 0; r < 16; ++r) O0[r] *= al;
        } else {
#pragma unroll
          for (int r = 0; r < 16; ++r) O1[r] *= al;
        }
      }
      float pr[16], ps = 0.f;
#pragma unroll
      for (int r = 0; r < 16; ++r) {
        pr[r] = __builtin_amdgcn_exp2f(S[r] - mq);
        ps += pr[r];
      }
      lsum[qs] += ps + __shfl_xor(ps, 32, 64);

      unsigned w01 = pack2(pr[0],  pr[1]);
      unsigned w23 = pack2(pr[2],  pr[3]);
      unsigned w45 = pack2(pr[4],  pr[5]);
      unsigned w67 = pack2(pr[6],  pr[7]);
      unsigned w89 = pack2(pr[8],  pr[9]);
      unsigned wab = pack2(pr[10], pr[11]);
      unsigned wcd = pack2(pr[12], pr[13]);
      unsigned wef = pack2(pr[14], pr[15]);
      unsigned e01 = __shfl_xor(w01, 32, 64), e23 = __shfl_xor(w23, 32, 64);
      unsigned e45 = __shfl_xor(w45, 32, 64), e67 = __shfl_xor(w67, 32, 64);
      unsigned e89 = __shfl_xor(w89, 32, 64), eab = __shfl_xor(wab, 32, 64);
      unsigned ecd = __shfl_xor(wcd, 32, 64), eef = __shfl_xor(wef, 32, 64);
      union { short8 s; unsigned u[4]; } P0u, P1u;
      P0u.u[0] = hi ? e45 : w01;
      P0u.u[1] = hi ? e67 : w23;
      P0u.u[2] = hi ? w45 : e01;
      P0u.u[3] = hi ? w67 : e23;
      P1u.u[0] = hi ? ecd : w89;
      P1u.u[1] = hi ? eef : wab;
      P1u.u[2] = hi ? wcd : e89;
      P1u.u[3] = hi ? wef : eab;

      if (qs == 0) {
        O0 = __builtin_amdgcn_mfma_f32_32x32x16_bf16(Va, P0u.s, O0, 0, 0, 0);
        O0 = __builtin_amdgcn_mfma_f32_32x32x16_bf16(Vb, P1u.s, O0, 0, 0, 0);
      } else {
        O1 = __builtin_amdgcn_mfma_f32_32x32x16_bf16(Va, P0u.s, O1, 0, 0, 0);
        O1 = __builtin_amdgcn_mfma_f32_32x32x16_bf16(Vb, P1u.s, O1, 0, 0, 0);
      }
    }
  }

  int slot = blk;
#pragma unroll
  for (int qs = 0; qs < 2; ++qs) {
    int qloc = w * 64 + qs * 32 + l31;
    if (lane < 32) {
      PM[(size_t)slot * 256 + qloc] = m[qs];
      PL[(size_t)slot * 256 + qloc] = lsum[qs];
    }
    float* pa = PACC + (size_t)slot * 4096 + (size_t)qloc * 16;
    float4 lo4, hi4;
    if (qs == 0) {
      lo4 = make_float4(O0[0], O0[1], O0[2], O0[3]);
      hi4 = make_float4(O0[4], O0[5], O0[6], O0[7]);
    } else {
      lo4 = make_float4(O1[0], O1[1], O1[2], O1[3]);
      hi4 = make_float4(O1[4], O1[5], O1[6], O1[7]);
    }
    *(float4*)(pa + 4 * hi)     = lo4;
    *(float4*)(pa + 8 + 4 * hi) = hi4;
  }
}

// -------- fused1: combine + proj + LN1 + FFN + LN2 + head (round 8) --------
__global__ __launch_bounds__(256, 2) void k_fused1(
    const float* __restrict__ PM1, const float* __restrict__ PL1,
    const float* __restrict__ PA1,
    const float* __restrict__ Wo, const float* __restrict__ bo,
    const float* __restrict__ g1, const float* __restrict__ be1,
    const float* __restrict__ W1, const float* __restrict__ bb1,
    const float* __restrict__ W2, const float* __restrict__ bb2,
    const float* __restrict__ g2, const float* __restrict__ be2,
    const float* __restrict__ X,
    const float* __restrict__ dW1, const float* __restrict__ db1,
    const float* __restrict__ dW2, const float* __restrict__ db2,
    const float* __restrict__ dW3, const float* __restrict__ db3,
    float* __restrict__ out) {
  __shared__ float os[4][64], rs[4][64], xs[4][64], x2[4][64], hs[4][256];
  __shared__ float h1s[4][32], h2s[4][16];
  int tid = threadIdx.x;
  int bb = blockIdx.x >> 6;
  int nbase = (blockIdx.x & 63) * 4;
  int row0 = bb * S_ + 15 * N_ + nbase;
  size_t base = (size_t)row0 * 64;

  {
    int d = tid & 15, r = (tid >> 4) & 3, h = tid >> 6;
    int n = nbase + r;
    int sb = (bb * 4 + h) * 16;
    float M = -INFINITY;
#pragma unroll
    for (int s = 0; s < 16; ++s) M = fmaxf(M, PM1[(size_t)(sb + s) * 256 + n]);
    float D = 0.f, od = 0.f;
#pragma unroll
    for (int s = 0; s < 16; ++s) {
      float wgt = __builtin_amdgcn_exp2f(PM1[(size_t)(sb + s) * 256 + n] - M);
      D = fmaf(PL1[(size_t)(sb + s) * 256 + n], wgt, D);
      od = fmaf(PA1[(size_t)(sb + s) * 4096 + (size_t)n * 16 + d], wgt, od);
    }
    os[r][h * 16 + d] = od / D;
    rs[tid >> 6][tid & 63] = X[base + tid];
  }
  __syncthreads();

  int c = tid & 63, grp = tid >> 6;
  {
    float a = bo[c];
#pragma unroll 8
    for (int k = 0; k < 64; ++k) a = fmaf(os[grp][k], Wo[k * 64 + c], a);
    float val = a + rs[grp][c];
    float mean = wave_sum(val) * (1.f / 64.f);
    float dv = val - mean;
    float var = wave_sum(dv * dv) * (1.f / 64.f);
    xs[grp][c] = dv * rsqrtf(var + 1e-5f) * g1[c] + be1[c];
  }
  __syncthreads();

  {
    float am0 = bb1[tid], am1 = am0, am2 = am0, am3 = am0;
    for (int k4 = 0; k4 < 16; ++k4) {
      float w0 = W1[(4 * k4 + 0) * 256 + tid];
      float w1v = W1[(4 * k4 + 1) * 256 + tid];
      float w2v = W1[(4 * k4 + 2) * 256 + tid];
      float w3v = W1[(4 * k4 + 3) * 256 + tid];
      float4 x0 = *(const float4*)&xs[0][4 * k4];
      float4 x1 = *(const float4*)&xs[1][4 * k4];
      float4 x2v = *(const float4*)&xs[2][4 * k4];
      float4 x3 = *(const float4*)&xs[3][4 * k4];
      am0 = fmaf(x0.x, w0, am0); am0 = fmaf(x0.y, w1v, am0);
      am0 = fmaf(x0.z, w2v, am0); am0 = fmaf(x0.w, w3v, am0);
      am1 = fmaf(x1.x, w0, am1); am1 = fmaf(x1.y, w1v, am1);
      am1 = fmaf(x1.z, w2v, am1); am1 = fmaf(x1.w, w3v, am1);
      am2 = fmaf(x2v.x, w0, am2); am2 = fmaf(x2v.y, w1v, am2);
      am2 = fmaf(x2v.z, w2v, am2); am2 = fmaf(x2v.w, w3v, am2);
      am3 = fmaf(x3.x, w0, am3); am3 = fmaf(x3.y, w1v, am3);
      am3 = fmaf(x3.z, w2v, am3); am3 = fmaf(x3.w, w3v, am3);
    }
    hs[0][tid] = fmaxf(am0, 0.f);
    hs[1][tid] = fmaxf(am1, 0.f);
    hs[2][tid] = fmaxf(am2, 0.f);
    hs[3][tid] = fmaxf(am3, 0.f);
  }
  __syncthreads();

  {
    float a = bb2[c];
    for (int k4 = 0; k4 < 64; ++k4) {
      float w0 = W2[(4 * k4 + 0) * 64 + c];
      float w1v = W2[(4 * k4 + 1) * 64 + c];
      float w2v = W2[(4 * k4 + 2) * 64 + c];
      float w3v = W2[(4 * k4 + 3) * 64 + c];
      float4 hv = *(const float4*)&hs[grp][4 * k4];
      a = fmaf(hv.x, w0, a); a = fmaf(hv.y, w1v, a);
      a = fmaf(hv.z, w2v, a); a = fmaf(hv.w, w3v, a);
    }
    float val = a + xs[grp][c];
    float mean = wave_sum(val) * (1.f / 64.f);
    float dv = val - mean;
    float var = wave_sum(dv * dv) * (1.f / 64.f);
    x2[grp][c] = dv * rsqrtf(var + 1e-5f) * g2[c] + be2[c];
  }
  __syncthreads();

  if (tid < 128) {
    int r = tid >> 5, mid = tid & 31;
    float a = db1[mid];
#pragma unroll 8
    for (int k = 0; k < 64; ++k) a = fmaf(x2[r][k], dW1[k * 32 + mid], a);
    h1s[r][mid] = fmaxf(a, 0.f);
  }
  __syncthreads();
  if (tid < 64) {
    int r = tid >> 4, low = tid & 15;
    float a = db2[low];
#pragma unroll
    for (int k = 0; k < 32; ++k) a = fmaf(h1s[r][k], dW2[k * 16 + low], a);
    h2s[r][low] = fmaxf(a, 0.f);
  }
  __syncthreads();
  if (tid < 4) {
    float a = db3[0];
#pragma unroll
    for (int k = 0; k < 16; ++k) a = fmaf(h2s[tid][k], dW3[k], a);
    out[bb * 256 + nbase + tid] = a;
  }
}

}  // namespace

extern "C" void kernel_launch(void* const* d_in, const int* in_sizes, int n_in,
                              void* d_out, int out_size, void* d_ws, size_t ws_size,
                              hipStream_t stream) {
  const float* x_seq = (const float*)d_in[0];
  // d_in[1] = edge_index (unused by reference)
  const float* Wi   = (const float*)d_in[2];
  const float* bi   = (const float*)d_in[3];
  const float* Wqkv = (const float*)d_in[4];
  const float* bqkv = (const float*)d_in[5];
  const float* Wo   = (const float*)d_in[6];
  const float* bo   = (const float*)d_in[7];
  const float* ln1g = (const float*)d_in[8];
  const float* ln1b = (const float*)d_in[9];
  const float* W1   = (const float*)d_in[10];
  const float* b1   = (const float*)d_in[11];
  const float* W2   = (const float*)d_in[12];
  const float* b2   = (const float*)d_in[13];
  const float* ln2g = (const float*)d_in[14];
  const float* ln2b = (const float*)d_in[15];
  const float* dW1  = (const float*)d_in[16];
  const float* db1  = (const float*)d_in[17];
  const float* dW2  = (const float*)d_in[18];
  const float* db2  = (const float*)d_in[19];
  const float* dW3  = (const float*)d_in[20];
  const float* db3  = (const float*)d_in[21];

  float* ws   = (float*)d_ws;  // needs >= 17.3 MB
  float* A    = ws + OFF_A;
  float* Bt   = ws + OFF_BT;
  float* Xb   = ws + OFF_XB;
  float* ALPH = ws + OFF_ALPH;
  float* BET  = ws + OFF_BET;
  float* GAM  = ws + OFF_GAM;
  float* DELT = ws + OFF_DELT;
  float* MN   = ws + OFF_MN;
  float* MX   = ws + OFF_MX;
  float* X    = ws + OFF_X;
  float* QKV  = ws + OFF_QKV;
  float* P0   = ws + OFF_P0;
  float* PM1  = ws + OFF_PM1;
  float* PL1  = ws + OFF_PL1;
  float* PA1  = ws + OFF_PA1;
  short* WT   = (short*)(ws + OFF_WT);

  k_setup<<<67, 256, 0, stream>>>(x_seq, Wi, bi, Wqkv, bqkv, Wo, W1, W2,
                                  A, Bt, Xb, ALPH, BET, GAM, DELT, MN, MX, WT);
  k_attn0<<<8 * PAIRS, 256, 0, stream>>>(x_seq, ALPH, BET, GAM, DELT, MN, MX, P0);
  k_fused0<<<512, 256, 0, stream>>>(P0, A, Bt, Xb, x_seq, Wi,
                                    bo, ln1g, ln1b, b1, b2, ln2g, ln2b,
                                    bqkv + 192, WT, X, QKV);
  k_attn1<<<128, 256, 0, stream>>>(QKV, PM1, PL1, PA1);
  k_fused1<<<128, 256, 0, stream>>>(PM1, PL1, PA1,
                                    Wo + 4096, bo + 64, ln1g + 64, ln1b + 64,
                                    W1 + 64 * 256, b1 + 256, W2 + 256 * 64, b2 + 64,
                                    ln2g + 64, ln2b + 64, X,
                                    dW1, db1, dW2, db2, dW3, db3, (float*)d_out);
}